// Round 15
// baseline (691.572 us; speedup 1.0000x reference)
//
#include <hip/hip_runtime.h>
#include <stdint.h>

#define DEVI __device__ __forceinline__

constexpr int N_   = 50000;
constexpr int ESC  = 600000;
constexpr int EBB  = 100000;
constexpr int NRES = 21;
constexpr float PI_F = 3.14159f;

// radix geometry
constexpr int RCH = 2048;
constexpr int RBS = (ESC + RCH - 1)/RCH;  // 293
constexpr int RBB = (EBB + RCH - 1)/RCH;  // 49

typedef __attribute__((ext_vector_type(8))) short short8v;
typedef __attribute__((ext_vector_type(4))) float f32x4;

// ---------- dtype helpers ----------
DEVI float bf2f(unsigned short u){ return __uint_as_float(((unsigned)u)<<16); }
DEVI unsigned short f2bf(float f){
  unsigned x = __float_as_uint(f);
  unsigned r = (x + 0x7FFFu + ((x>>16)&1u))>>16;
  return (unsigned short)r;
}
DEVI float ldin(const void* p, long i, int f32){
  return f32 ? ((const float*)p)[i] : bf2f(((const unsigned short*)p)[i]);
}
DEVI void stout(void* p, long i, float v, int f32){
  if(f32) ((float*)p)[i]=v; else ((unsigned short*)p)[i]=f2bf(v);
}
DEVI float wrapf(float a){
  float t = a + PI_F;
  const float TP = 2.f*PI_F;
  t -= floorf(t/TP)*TP;
  return t - PI_F;
}

// ---------- weight arena offsets ----------
constexpr int OW_SC_LN_G=0;
constexpr int OW_SC_LN_B=OW_SC_LN_G+19;
constexpr int OW_SC_W  = OW_SC_LN_B+19;
constexpr int OW_SC_B  = OW_SC_W+19*128;
constexpr int OW_BB_LN_G=OW_SC_B+128;
constexpr int OW_BB_LN_B=OW_BB_LN_G+38;
constexpr int OW_BB_W = OW_BB_LN_B+38;
constexpr int OW_BB_B = OW_BB_W+38*128;
constexpr int OW_E_LN_G=OW_BB_B+128;
constexpr int OW_E_LN_B=OW_E_LN_G+66;
constexpr int OW_EW1 = OW_E_LN_B+66;
constexpr int OW_EB1 = OW_EW1+66*128;
constexpr int OW_GW  = OW_EB1+128;
constexpr int OW_GB  = OW_GW+128*128;
constexpr int OW_BGW = OW_GB+128;
constexpr int OW_BGB = OW_BGW+128*128;
constexpr int OW_IW1 = OW_BGB+128;
constexpr int OW_IB1 = OW_IW1+256*128;
constexpr int OW_IW2 = OW_IB1+128;
constexpr int OW_IB2 = OW_IW2+128*128;
constexpr int OW_AW  = OW_IB2+128;
constexpr int OW_AB  = OW_AW+128;
constexpr int OW_BAW = OW_AB+1;
constexpr int OW_BAB = OW_BAW+128;
constexpr int OW_CW  = OW_BAB+1;
constexpr int OW_CB  = OW_CW+128*3;
constexpr int OW_XW  = OW_CB+3;
constexpr int OW_XB  = OW_XW+128*3;
constexpr int OW_RES = OW_XB+3;
constexpr int OW_TOT = OW_RES+21*32;

// ---------- basic kernels ----------
__global__ void k_detect(const void* vcom, int* flag){
  const unsigned short* u = (const unsigned short*)vcom;
  int insane=0;
  for(int i=0;i<64;i+=2){
    float f = bf2f(u[i]);
    float a = fabsf(f);
    if(!(a<1e5f) || (a!=0.0f && a<1e-5f)) insane++;
  }
  *flag = (insane>=8)?1:0;
}

struct CvtArgs { const void* src[29]; };

__global__ void k_cvtw(CvtArgs a, const int* flag, float* w){
  static constexpr int offs[30] = {
    OW_SC_LN_G,OW_SC_LN_B,OW_SC_W,OW_SC_B,OW_BB_LN_G,OW_BB_LN_B,OW_BB_W,OW_BB_B,
    OW_E_LN_G,OW_E_LN_B,OW_EW1,OW_EB1,OW_GW,OW_GB,OW_BGW,OW_BGB,OW_IW1,OW_IB1,
    OW_IW2,OW_IB2,OW_AW,OW_AB,OW_BAW,OW_BAB,OW_CW,OW_CB,OW_XW,OW_XB,OW_RES,OW_TOT};
  int f32=*flag;
  for(int t=blockIdx.x*blockDim.x+threadIdx.x; t<OW_TOT; t+=gridDim.x*blockDim.x){
    int s=0;
    while(t>=offs[s+1]) s++;
    w[t]=ldin(a.src[s], t-offs[s], f32);
  }
}

// W[K x 128] -> MFMA fragment order (zero-padded past Kreal), split hi/lo bf16.
DEVI void wprep_pad(const float* W, int Kreal, unsigned short* hi, unsigned short* lo, int idx){
  int lane=idx&63, nt=(idx>>6)&7, kt=idx>>9;
  int n = nt*16 + (lane&15);
  int kbase = kt*32 + (lane>>4)*8;
  #pragma unroll
  for(int i=0;i<8;i++){
    int k=kbase+i;
    float v = (k<Kreal) ? W[(long)k*128 + n] : 0.f;
    unsigned short h = f2bf(v);
    hi[(long)idx*8+i]=h;
    if(lo){ float r = v - bf2f(h); lo[(long)idx*8+i]=f2bf(r); }
  }
}

// ---------- mega prep kernel: wprep | prevec | preP | LN ----------
constexpr int PB_WP = 46;
constexpr int PB_PV = PB_WP+1;
constexpr int PB_PP = PB_PV+441;
constexpr int PB_LN = PB_PP + (2*N_+3)/4;

__global__ void k_prep(const float* w, const int* flag,
    unsigned short* g_hi, unsigned short* g_lo,
    unsigned short* bg_hi,
    unsigned short* i2_hi,
    unsigned short* i1_hi,
    unsigned short* sc_hi, unsigned short* sc_lo,
    unsigned short* bb_hi, unsigned short* bb_lo,
    const void* eW2, const void* eb2, const void* euW, const void* eub,
    float* dv, float* dvf, float* P, float* sp, float* qp,
    const void* vcom, const void* sbfchi,
    const void* xca, const void* vcb, const void* sphi, const void* spsi,
    float* xn_sc, float* xn_bb){
  __shared__ float pv[64];
  int b=blockIdx.x;
  if(b<PB_WP){
    int idx=b*256+threadIdx.x;
    if(idx<2048)       wprep_pad(w+OW_GW,  128, g_hi,  g_lo,  idx);
    else if(idx<4096)  wprep_pad(w+OW_BGW, 128, bg_hi, nullptr, idx-2048);
    else if(idx<6144)  wprep_pad(w+OW_IW2, 128, i2_hi, nullptr, idx-4096);
    else if(idx<10240) wprep_pad(w+OW_IW1, 256, i1_hi, nullptr, idx-6144);
    else if(idx<10752) wprep_pad(w+OW_SC_W, 19, sc_hi, sc_lo, idx-10240);
    else if(idx<11776) wprep_pad(w+OW_BB_W, 38, bb_hi, bb_lo, idx-10752);
  } else if(b<PB_PV){
    int j=threadIdx.x; int f32=*flag;
    if(j<128){
      const float* g=w+OW_E_LN_G; const float* bb=w+OW_E_LN_B; const float* W1=w+OW_EW1;
      float A=g[0]*W1[j], C=g[1]*W1[128+j];
      float G=0,B=0;
      for(int i=0;i<66;i++){ float wij=W1[i*128+j]; G+=g[i]*wij; B+=bb[i]*wij; }
      B += w[OW_EB1+j];
      float v2=0; for(int k=0;k<128;k++) v2+=ldin(eW2,(long)j*128+k,f32);
      float us=0,ud=0;
      for(int k=0;k<128;k++){ us+=ldin(euW,(long)j*128+k,f32); ud+=ldin(euW,(long)(128+j)*128+k,f32); }
      dv[640+j]=us*(1.f/128.f); dv[768+j]=ud*(1.f/128.f);
      dvf[j]=A; dvf[128+j]=C; dvf[256+j]=G; dvf[384+j]=B; dvf[512+j]=v2*(1.f/128.f);
      if(j==0){
        float s=0,t=0;
        for(int k=0;k<128;k++){ s+=ldin(eb2,k,f32); t+=ldin(eub,k,f32); }
        dv[896]=s*(1.f/128.f); dv[897]=t*(1.f/128.f);
        dvf[640]=s*(1.f/128.f);
      }
    }
  } else if(b<PB_PP){
    int c=b-PB_PV, j=threadIdx.x;
    const float* res=w+OW_RES;
    if(j<32) pv[j]=res[(c/NRES)*32+j];
    else if(j<64) pv[j]=res[(c%NRES)*32+(j-32)];
    __syncthreads();
    if(j<128){
      const float* g=w+OW_E_LN_G; const float* W1=w+OW_EW1;
      float s=0;
      for(int i=0;i<64;i++) s += pv[i]*g[2+i]*W1[(2+i)*128+j];
      P[c*128+j]=s;
      if(j==0){ float a=0,q=0; for(int i=0;i<64;i++){a+=pv[i]; q+=pv[i]*pv[i];} sp[c]=a; qp[c]=q; }
    }
  } else {
    int wv=threadIdx.x>>6, lane=threadIdx.x&63;
    long gw=(long)(b-PB_PP)*4+wv;
    int f32=*flag;
    if(gw<N_){
      int n=(int)gw;
      float x=0.f;
      if(lane<3) x=ldin(vcom,(long)n*3+lane,f32);
      else if(lane<19) x=ldin(sbfchi,(long)n*16+(lane-3),f32);
      float s=x, q=x*x;
      for(int m=1;m<64;m<<=1){ s+=__shfl_xor(s,m,64); q+=__shfl_xor(q,m,64); }
      float mean=s*(1.f/19.f);
      float istd=rsqrtf(fmaxf(q*(1.f/19.f)-mean*mean,0.f)+1e-5f);
      if(lane<32){
        float xn=(lane<19)? (x-mean)*istd*w[OW_SC_LN_G+lane]+w[OW_SC_LN_B+lane] : 0.f;
        xn_sc[(long)n*32+lane]=xn;
      }
    } else if(gw<2L*N_){
      int n=(int)(gw-N_);
      float x=0.f;
      if(lane<3) x=ldin(xca,(long)n*3+lane,f32);
      else if(lane<6) x=ldin(vcb,(long)n*3+(lane-3),f32);
      else if(lane<22) x=ldin(sphi,(long)n*16+(lane-6),f32);
      else if(lane<38) x=ldin(spsi,(long)n*16+(lane-22),f32);
      float s=x, q=x*x;
      for(int m=1;m<64;m<<=1){ s+=__shfl_xor(s,m,64); q+=__shfl_xor(q,m,64); }
      float mean=s*(1.f/38.f);
      float istd=rsqrtf(fmaxf(q*(1.f/38.f)-mean*mean,0.f)+1e-5f);
      float xn=(lane<38)? (x-mean)*istd*w[OW_BB_LN_G+lane]+w[OW_BB_LN_B+lane] : 0.f;
      xn_bb[(long)n*64+lane]=xn;
    }
  }
}

// ---------- stable 2-pass radix CSR build (RCH=2048, parallel scan) ----------
__global__ void k_rhist(const int* key_sc, const int* key_bb, int shift, int* hist){
  __shared__ int h[256];
  h[threadIdx.x]=0; __syncthreads();
  int g = blockIdx.x>=RBS;
  const int* key = g? key_bb : key_sc;
  int E = g? EBB : ESC;
  int b = g? blockIdx.x-RBS : blockIdx.x;
  int base=b*RCH;
  for(int r=0;r<RCH/256;r++){
    int idx=base+r*256+threadIdx.x;
    if(idx<E) atomicAdd(&h[(key[idx]>>shift)&255],1);
  }
  __syncthreads();
  hist[(long)blockIdx.x*256+threadIdx.x]=h[threadIdx.x];
}
__global__ void k_rscanA(int* hist, int* tot){
  __shared__ int sA[512], sB[512];
  int g = blockIdx.x>=256;
  int d = blockIdx.x&255;
  int NB = g? RBB : RBS;
  int* H = hist + (g? (long)RBS*256 : 0);
  int t=threadIdx.x;
  int i0=t, i1=t+256;
  int o0 = (i0<NB)? H[(long)i0*256+d] : 0;
  int o1 = (i1<NB)? H[(long)i1*256+d] : 0;
  sA[i0]=o0; sA[i1]=o1;
  __syncthreads();
  int* a=sA; int* b=sB;
  for(int off=1; off<512; off<<=1){
    b[i0] = a[i0] + ((i0>=off)? a[i0-off]:0);
    b[i1] = a[i1] + ((i1>=off)? a[i1-off]:0);
    __syncthreads();
    int* tmp=a; a=b; b=tmp;
  }
  if(i0<NB) H[(long)i0*256+d] = a[i0]-o0;
  if(i1<NB) H[(long)i1*256+d] = a[i1]-o1;
  if(t==255) tot[(g?256:0)+d] = a[511];
}
__global__ void k_rscanB(const int* tot, int* base){
  __shared__ int sA[256], sB[256];
  int t=threadIdx.x;
  for(int g=0;g<2;g++){
    int o=tot[g*256+t];
    sA[t]=o; __syncthreads();
    int* a=sA; int* b=sB;
    for(int off=1; off<256; off<<=1){
      b[t] = a[t] + ((t>=off)? a[t-off]:0);
      __syncthreads();
      int* tmp=a; a=b; b=tmp;
    }
    base[g*256+t] = a[t]-o;
    __syncthreads();
  }
}
__global__ void k_rscat(int shift, int first,
    const int* kin_sc, const int* srcv_sc, const int2* pin_sc,
    const int* kin_bb, const int* srcv_bb, const int2* pin_bb,
    const int* hist, const int* dbase,
    int* kout_sc, int2* pout_sc, int* kout_bb, int2* pout_bb){
  __shared__ int running[256];
  __shared__ int Hb[256];
  __shared__ int whist[4][256];
  __shared__ int pw[4][256];
  int tid=threadIdx.x, lane=tid&63, w=tid>>6;
  int g = blockIdx.x>=RBS;
  const int* kin  = g? kin_bb : kin_sc;
  const int* srcv = g? srcv_bb: srcv_sc;
  const int2* pin = g? pin_bb : pin_sc;
  int* kout  = g? kout_bb : kout_sc;
  int2* pout = g? pout_bb : pout_sc;
  int E = g? EBB : ESC;
  int b = g? blockIdx.x-RBS : blockIdx.x;
  running[tid]=0;
  Hb[tid]=hist[(long)blockIdx.x*256+tid] + dbase[(g?256:0)+tid];
  int base=b*RCH;
  for(int r=0;r<RCH/256;r++){
    __syncthreads();
    whist[0][tid]=0; whist[1][tid]=0; whist[2][tid]=0; whist[3][tid]=0;
    __syncthreads();
    int idx=base+r*256+tid;
    bool valid = idx<E;
    int key=0, digit=0; int2 pay; pay.x=0; pay.y=0;
    if(valid){
      key=kin[idx];
      digit=(key>>shift)&255;
      if(first){ pay.x=srcv[idx]; pay.y=idx; }
      else pay=pin[idx];
    }
    unsigned long long act=__ballot(valid);
    unsigned long long same=act;
    #pragma unroll
    for(int k=0;k<8;k++){
      unsigned long long m=__ballot(valid && ((digit>>k)&1));
      same &= ((digit>>k)&1)? m : ~m;
    }
    same &= act;
    unsigned long long below=(1ULL<<lane)-1ULL;
    int wrank=__popcll(same & below);
    if(valid && wrank==0) whist[w][digit]=__popcll(same);
    __syncthreads();
    int c0=whist[0][tid], c1=whist[1][tid], c2=whist[2][tid], c3=whist[3][tid];
    pw[0][tid]=0; pw[1][tid]=c0; pw[2][tid]=c0+c1; pw[3][tid]=c0+c1+c2;
    __syncthreads();
    if(valid){
      int pos=Hb[digit]+running[digit]+pw[w][digit]+wrank;
      kout[pos]=key; pout[pos]=pay;
    }
    __syncthreads();
    running[tid]+=c0+c1+c2+c3;
  }
}
__global__ void k_bounds(const int* dstS_sc, const int* dstS_bb, int* rp_sc, int* rp_bb){
  long i=(long)blockIdx.x*blockDim.x+threadIdx.x;
  if(i<=ESC){
    int cur = (i<ESC)? dstS_sc[i] : N_;
    int prev= (i>0)? dstS_sc[i-1] : -1;
    for(int d=prev+1; d<=cur; d++) rp_sc[d]=(int)i;
  } else if(i <= (long)ESC+1+EBB){
    long j=i-(ESC+1);
    int cur = (j<EBB)? dstS_bb[j] : N_;
    int prev= (j>0)? dstS_bb[j-1] : -1;
    for(int d=prev+1; d<=cur; d++) rp_bb[d]=(int)j;
  }
}
__global__ void k_degb(const int* rp, float* disb){
  int n=blockIdx.x*blockDim.x+threadIdx.x;
  if(n<N_) disb[n]=rsqrtf(1.f+(float)(rp[n+1]-rp[n]));
}

// ---------- edge MLP: 16-lane groups, 4 edges/group, dvf cached in registers ----------
constexpr int WBG = (ESC + 63)/64;  // 9375
__global__ __launch_bounds__(256,4) void k_w0(const void* dsc, const void* dmin,
    const int* ri_, const int* rj_, const int* flag, const float* dvf,
    const float* P, const float* sp, const float* qp, float* we){
  int wv=threadIdx.x>>6, lane=threadIdx.x&63;
  int g=lane>>4, l=lane&15;
  long ebase=(long)blockIdx.x*64 + wv*16 + g*4;
  int f32=*flag;
  int j0=l*8;
  float4 A0=*(const float4*)&dvf[j0],     A1=*(const float4*)&dvf[j0+4];
  float4 C0=*(const float4*)&dvf[128+j0], C1=*(const float4*)&dvf[128+j0+4];
  float4 G0=*(const float4*)&dvf[256+j0], G1=*(const float4*)&dvf[256+j0+4];
  float4 B0=*(const float4*)&dvf[384+j0], B1=*(const float4*)&dvf[384+j0+4];
  float4 V0=*(const float4*)&dvf[512+j0], V1=*(const float4*)&dvf[512+j0+4];
  float eb2=dvf[640];
  #pragma unroll
  for(int k=0;k<4;k++){
    long e=ebase+k;
    bool val = e<ESC;
    long ee = val? e : 0;
    float d1=ldin(dsc,ee,f32), d2=ldin(dmin,ee,f32);
    int c=ri_[ee]*NRES+rj_[ee];
    float m=(d1+d2+sp[c])*(1.f/66.f);
    float ms=(d1*d1+d2*d2+qp[c])*(1.f/66.f);
    float istd=rsqrtf(fmaxf(ms-m*m,0.f)+1e-5f);
    float nmi=-m*istd;
    float4 P0=*(const float4*)&P[(long)c*128+j0];
    float4 P1=*(const float4*)&P[(long)c*128+j0+4];
    float acc=0.f, t, hid;
    t=fmaf(d1,A0.x,fmaf(d2,C0.x,P0.x)); hid=fmaf(istd,t,fmaf(nmi,G0.x,B0.x)); acc=fmaf(fmaxf(hid,0.f),V0.x,acc);
    t=fmaf(d1,A0.y,fmaf(d2,C0.y,P0.y)); hid=fmaf(istd,t,fmaf(nmi,G0.y,B0.y)); acc=fmaf(fmaxf(hid,0.f),V0.y,acc);
    t=fmaf(d1,A0.z,fmaf(d2,C0.z,P0.z)); hid=fmaf(istd,t,fmaf(nmi,G0.z,B0.z)); acc=fmaf(fmaxf(hid,0.f),V0.z,acc);
    t=fmaf(d1,A0.w,fmaf(d2,C0.w,P0.w)); hid=fmaf(istd,t,fmaf(nmi,G0.w,B0.w)); acc=fmaf(fmaxf(hid,0.f),V0.w,acc);
    t=fmaf(d1,A1.x,fmaf(d2,C1.x,P1.x)); hid=fmaf(istd,t,fmaf(nmi,G1.x,B1.x)); acc=fmaf(fmaxf(hid,0.f),V1.x,acc);
    t=fmaf(d1,A1.y,fmaf(d2,C1.y,P1.y)); hid=fmaf(istd,t,fmaf(nmi,G1.y,B1.y)); acc=fmaf(fmaxf(hid,0.f),V1.y,acc);
    t=fmaf(d1,A1.z,fmaf(d2,C1.z,P1.z)); hid=fmaf(istd,t,fmaf(nmi,G1.z,B1.z)); acc=fmaf(fmaxf(hid,0.f),V1.z,acc);
    t=fmaf(d1,A1.w,fmaf(d2,C1.w,P1.w)); hid=fmaf(istd,t,fmaf(nmi,G1.w,B1.w)); acc=fmaf(fmaxf(hid,0.f),V1.w,acc);
    #pragma unroll
    for(int msk=1;msk<16;msk<<=1) acc+=__shfl_xor(acc,msk,64);
    if(l==0 && val) we[e]=acc+eb2;
  }
}

// ---------- split-bf16 MFMA GEMM core ----------
DEVI f32x4 MFMA(short8v a, short8v b, f32x4 c){
  return __builtin_amdgcn_mfma_f32_16x16x32_bf16(a,b,c,0,0,0);
}
DEVI void cvt8(float4 a0, float4 a1, short8v& hi, short8v& lo){
  float av[8]={a0.x,a0.y,a0.z,a0.w,a1.x,a1.y,a1.z,a1.w};
  union{short8v v; unsigned short u[8];} H,L;
  #pragma unroll
  for(int i=0;i<8;i++){
    unsigned short h=f2bf(av[i]);
    float r=av[i]-bf2f(h);
    H.u[i]=h; L.u[i]=f2bf(r);
  }
  hi=H.v; lo=L.v;
}
DEVI short8v cvt8hi(float4 a0, float4 a1){
  union{short8v v; unsigned short u[8];} H;
  H.u[0]=f2bf(a0.x); H.u[1]=f2bf(a0.y); H.u[2]=f2bf(a0.z); H.u[3]=f2bf(a0.w);
  H.u[4]=f2bf(a1.x); H.u[5]=f2bf(a1.y); H.u[6]=f2bf(a1.z); H.u[7]=f2bf(a1.w);
  return H.v;
}

template<int KT, int LDA>
DEVI void mgemm_body(int bid, const float* A1, const float* A2,
    const unsigned short* Whi, const unsigned short* Wlo,
    const float* bias, float* C, int relu, int accum, int M){
  const int lane = threadIdx.x & 63;
  const int wid  = threadIdx.x >> 6;
  const int r0   = bid*64 + wid*16;
  const int mrow = lane & 15;
  const int kg   = lane >> 4;
  long arow = (long)min(r0 + mrow, M-1);
  f32x4 acc[8];
  #pragma unroll
  for(int t=0;t<8;t++) acc[t]=(f32x4){0.f,0.f,0.f,0.f};

  #pragma unroll
  for(int kt=0; kt<KT; kt++){
    const float* A = (KT==8 && kt>=4) ? A2 : A1;
    int kb = (kt&3)*32 + kg*8;
    float4 a0 = *(const float4*)&A[arow*LDA + kb];
    float4 a1 = *(const float4*)&A[arow*LDA + kb + 4];
    short8v ah, al; cvt8(a0,a1,ah,al);
    #pragma unroll
    for(int nt=0;nt<8;nt++){
      long off = (((long)kt*8+nt)*64 + lane)*8;
      short8v wh = *(const short8v*)&Whi[off];
      short8v wl = *(const short8v*)&Wlo[off];
      acc[nt] = MFMA(ah, wh, acc[nt]);
      acc[nt] = MFMA(al, wh, acc[nt]);
      acc[nt] = MFMA(ah, wl, acc[nt]);
      acc[nt] = MFMA(al, wl, acc[nt]);
    }
  }

  #pragma unroll
  for(int nt=0;nt<8;nt++){
    int col = nt*16 + mrow;
    float bj = bias ? bias[col] : 0.f;
    #pragma unroll
    for(int r=0;r<4;r++){
      int row = r0 + kg*4 + r;
      if(row >= M) continue;
      long idx = (long)row*128 + col;
      float v = acc[nt][r] + bj;
      if(relu) v = fmaxf(v,0.f);
      if(accum) v += C[idx];
      C[idx] = v;
    }
  }
}

// sc layer: gW GEMM overlapped with degree pass (independent producers; round-7-proven)
__global__ __launch_bounds__(256,4) void k_gemmdeg(const float* hat_h,
    const unsigned short* Whi, const unsigned short* Wlo, float* C, int M,
    const int* rp, const int2* se, const float* we_edge,
    const float* an, const float* bn, const float* dv,
    float* we_csr, float* dis, int layer){
  int GBl=(M+63)/64;
  if((int)blockIdx.x < GBl){
    mgemm_body<4,128>(blockIdx.x, hat_h, nullptr, Whi, Wlo, nullptr, C, 0, 0, M);
  } else {
    int n=(blockIdx.x-GBl)*256+threadIdx.x;
    if(n>=N_) return;
    int e0=rp[n], e1=rp[n+1];
    float s=1.f;
    if(layer==0){
      for(int p=e0;p<e1;p++){ float ww=we_edge[se[p].y]; we_csr[p]=ww; s+=ww; }
    } else {
      float add_n = bn[n] + dv[897];
      for(int p=e0;p<e1;p++){
        float ww=we_csr[p] + an[se[p].x] + add_n;
        we_csr[p]=ww; s+=ww;
      }
    }
    dis[n]=rsqrtf(fmaxf(s,1e-6f));
  }
}

// wn[p] = dis[src]*wc[p]
__global__ void k_norm(const int2* se, const float* we_csr, const float* dis, float* wn){
  int p=blockIdx.x*blockDim.x+threadIdx.x;
  if(p<ESC) wn[p]=dis[se[p].x]*we_csr[p];
}

// featurizer: both small GEMMs in one launch
__global__ __launch_bounds__(256,4) void k_mfeat(const float* xn_sc, const float* xn_bb,
    const unsigned short* schi, const unsigned short* sclo,
    const unsigned short* bbhi, const unsigned short* bblo,
    const float* w, float* hat_h, float* hbuf, int M){
  int GBl=(M+63)/64;
  if((int)blockIdx.x < GBl)
    mgemm_body<1,32>(blockIdx.x, xn_sc, nullptr, schi, sclo, w+OW_SC_B, hat_h, 0,0,M);
  else
    mgemm_body<2,64>(blockIdx.x-GBl, xn_bb, nullptr, bbhi, bblo, w+OW_BB_B, hbuf, 0,0,M);
}

// fused bb layer (backbone branch is NOT chaotic -> plain bf16 suffices)
__global__ __launch_bounds__(256,4) void k_mbb(const float* h, const float* hh,
    const unsigned short* W1hi,
    const unsigned short* W2hi,
    const unsigned short* W3hi,
    const float* b1, const float* b2,
    unsigned short* xwout, unsigned short* mout, int M){
  __shared__ unsigned short hids[64*136];
  const int lane = threadIdx.x & 63;
  const int wid  = threadIdx.x >> 6;
  const int r0   = blockIdx.x*64 + wid*16;
  const int mrow = lane & 15;
  const int kg   = lane >> 4;
  long arow = (long)min(r0 + mrow, M-1);
  f32x4 acc1[8], acc2[8];
  #pragma unroll
  for(int t=0;t<8;t++){ acc1[t]=(f32x4){0,0,0,0}; acc2[t]=(f32x4){0,0,0,0}; }

  #pragma unroll
  for(int kt=0; kt<8; kt++){
    const float* A = (kt>=4) ? hh : h;
    int kb = (kt&3)*32 + kg*8;
    float4 a0 = *(const float4*)&A[arow*128 + kb];
    float4 a1 = *(const float4*)&A[arow*128 + kb + 4];
    short8v ah = cvt8hi(a0,a1);
    #pragma unroll
    for(int nt=0;nt<8;nt++){
      long off = (((long)kt*8+nt)*64 + lane)*8;
      acc1[nt] = MFMA(ah, *(const short8v*)&W1hi[off], acc1[nt]);
    }
    if(kt<4){
      #pragma unroll
      for(int nt=0;nt<8;nt++){
        long off = (((long)kt*8+nt)*64 + lane)*8;
        acc2[nt] = MFMA(ah, *(const short8v*)&W2hi[off], acc2[nt]);
      }
    }
  }

  #pragma unroll
  for(int nt=0;nt<8;nt++){
    int col = nt*16 + mrow;
    float bj = b1[col];
    #pragma unroll
    for(int r=0;r<4;r++){
      int rloc = wid*16 + kg*4 + r;
      int row = r0 + kg*4 + r;
      hids[rloc*136 + col] = f2bf(fmaxf(acc1[nt][r] + bj, 0.f));
      if(row < M) xwout[(long)row*128 + col] = f2bf(acc2[nt][r]);
    }
  }
  __syncthreads();

  f32x4 acc3[8];
  #pragma unroll
  for(int t=0;t<8;t++) acc3[t]=(f32x4){0,0,0,0};
  int rloc = wid*16 + mrow;
  #pragma unroll
  for(int kt=0; kt<4; kt++){
    int kb = kt*32 + kg*8;
    short8v ah = *(const short8v*)&hids[rloc*136 + kb];
    #pragma unroll
    for(int nt=0;nt<8;nt++){
      long off = (((long)kt*8+nt)*64 + lane)*8;
      acc3[nt] = MFMA(ah, *(const short8v*)&W3hi[off], acc3[nt]);
    }
  }
  #pragma unroll
  for(int nt=0;nt<8;nt++){
    int col = nt*16 + mrow;
    float bj = b2[col];
    #pragma unroll
    for(int r=0;r<4;r++){
      int row = r0 + kg*4 + r;
      if(row < M) mout[(long)row*128 + col] = f2bf(acc3[nt][r] + bj);
    }
  }
}

// ---------- aggregation: 8 lanes/edge, 8 groups, 2-edge unroll (16 rows in flight) ----------
__global__ void k_agg_sc(const int* rp, const int2* se, const float* wn,
                         const float* dis, const float* xw, const float* w,
                         float* hat_h, const float* dv, float* an, float* bn, int withdot){
  int wv=threadIdx.x>>6, lane=threadIdx.x&63;
  int n=blockIdx.x*4+wv;
  int g=lane>>3, l=lane&7, d0=l*16;
  float disn=dis[n];
  float4 a0={0,0,0,0},a1={0,0,0,0},a2={0,0,0,0},a3={0,0,0,0};
  float4 c0={0,0,0,0},c1={0,0,0,0},c2={0,0,0,0},c3={0,0,0,0};
  int e0=rp[n], e1=rp[n+1];
  int p=e0+g;
  for(; p+8<e1; p+=16){
    int s0=se[p].x, s1=se[p+8].x;
    float nw0=wn[p], nw1=wn[p+8];
    const float4* r0=(const float4*)&xw[(long)s0*128+d0];
    const float4* r1=(const float4*)&xw[(long)s1*128+d0];
    float4 x0=r0[0],x1=r0[1],x2=r0[2],x3=r0[3];
    float4 y0=r1[0],y1=r1[1],y2=r1[2],y3=r1[3];
    a0.x+=nw0*x0.x; a0.y+=nw0*x0.y; a0.z+=nw0*x0.z; a0.w+=nw0*x0.w;
    a1.x+=nw0*x1.x; a1.y+=nw0*x1.y; a1.z+=nw0*x1.z; a1.w+=nw0*x1.w;
    a2.x+=nw0*x2.x; a2.y+=nw0*x2.y; a2.z+=nw0*x2.z; a2.w+=nw0*x2.w;
    a3.x+=nw0*x3.x; a3.y+=nw0*x3.y; a3.z+=nw0*x3.z; a3.w+=nw0*x3.w;
    c0.x+=nw1*y0.x; c0.y+=nw1*y0.y; c0.z+=nw1*y0.z; c0.w+=nw1*y0.w;
    c1.x+=nw1*y1.x; c1.y+=nw1*y1.y; c1.z+=nw1*y1.z; c1.w+=nw1*y1.w;
    c2.x+=nw1*y2.x; c2.y+=nw1*y2.y; c2.z+=nw1*y2.z; c2.w+=nw1*y2.w;
    c3.x+=nw1*y3.x; c3.y+=nw1*y3.y; c3.z+=nw1*y3.z; c3.w+=nw1*y3.w;
  }
  if(p<e1){
    int s0=se[p].x;
    float nw0=wn[p];
    const float4* r0=(const float4*)&xw[(long)s0*128+d0];
    float4 x0=r0[0],x1=r0[1],x2=r0[2],x3=r0[3];
    a0.x+=nw0*x0.x; a0.y+=nw0*x0.y; a0.z+=nw0*x0.z; a0.w+=nw0*x0.w;
    a1.x+=nw0*x1.x; a1.y+=nw0*x1.y; a1.z+=nw0*x1.z; a1.w+=nw0*x1.w;
    a2.x+=nw0*x2.x; a2.y+=nw0*x2.y; a2.z+=nw0*x2.z; a2.w+=nw0*x2.w;
    a3.x+=nw0*x3.x; a3.y+=nw0*x3.y; a3.z+=nw0*x3.z; a3.w+=nw0*x3.w;
  }
  a0.x+=c0.x; a0.y+=c0.y; a0.z+=c0.z; a0.w+=c0.w;
  a1.x+=c1.x; a1.y+=c1.y; a1.z+=c1.z; a1.w+=c1.w;
  a2.x+=c2.x; a2.y+=c2.y; a2.z+=c2.z; a2.w+=c2.w;
  a3.x+=c3.x; a3.y+=c3.y; a3.z+=c3.z; a3.w+=c3.w;
  #pragma unroll
  for(int m=8;m<64;m<<=1){
    a0.x+=__shfl_xor(a0.x,m,64); a0.y+=__shfl_xor(a0.y,m,64);
    a0.z+=__shfl_xor(a0.z,m,64); a0.w+=__shfl_xor(a0.w,m,64);
    a1.x+=__shfl_xor(a1.x,m,64); a1.y+=__shfl_xor(a1.y,m,64);
    a1.z+=__shfl_xor(a1.z,m,64); a1.w+=__shfl_xor(a1.w,m,64);
    a2.x+=__shfl_xor(a2.x,m,64); a2.y+=__shfl_xor(a2.y,m,64);
    a2.z+=__shfl_xor(a2.z,m,64); a2.w+=__shfl_xor(a2.w,m,64);
    a3.x+=__shfl_xor(a3.x,m,64); a3.y+=__shfl_xor(a3.y,m,64);
    a3.z+=__shfl_xor(a3.z,m,64); a3.w+=__shfl_xor(a3.w,m,64);
  }
  float d2=disn*disn;
  const float4* xs=(const float4*)&xw[(long)n*128+d0];
  const float4* gb=(const float4*)&w[OW_GB+d0];
  float4* hp=(float4*)&hat_h[(long)n*128+d0];
  float4 hv[4];
  float4 av[4]={a0,a1,a2,a3};
  #pragma unroll
  for(int q=0;q<4;q++){
    float4 xq=xs[q], gq=gb[q], hq=hp[q];
    hv[q].x=hq.x+fmaxf(av[q].x*disn+d2*xq.x+gq.x,0.f);
    hv[q].y=hq.y+fmaxf(av[q].y*disn+d2*xq.y+gq.y,0.f);
    hv[q].z=hq.z+fmaxf(av[q].z*disn+d2*xq.z+gq.z,0.f);
    hv[q].w=hq.w+fmaxf(av[q].w*disn+d2*xq.w+gq.w,0.f);
  }
  if(g==0){
    #pragma unroll
    for(int q=0;q<4;q++) hp[q]=hv[q];
  }
  if(withdot){
    const float4* us=(const float4*)&dv[640+d0];
    const float4* ud=(const float4*)&dv[768+d0];
    float a=0.f, b=0.f;
    #pragma unroll
    for(int q=0;q<4;q++){
      float4 u=us[q], v=ud[q];
      a += hv[q].x*u.x+hv[q].y*u.y+hv[q].z*u.z+hv[q].w*u.w;
      b += hv[q].x*v.x+hv[q].y*v.y+hv[q].z*v.z+hv[q].w*v.w;
    }
    #pragma unroll
    for(int m=1;m<8;m<<=1){ a+=__shfl_xor(a,m,64); b+=__shfl_xor(b,m,64); }
    if(lane==0){ an[n]=a; bn[n]=b; }
  }
}

DEVI void bf8ld(const unsigned short* p, float4& lo, float4& hi){
  union{short8v v; unsigned short u[8];} t;
  t.v = *(const short8v*)p;
  lo.x=bf2f(t.u[0]); lo.y=bf2f(t.u[1]); lo.z=bf2f(t.u[2]); lo.w=bf2f(t.u[3]);
  hi.x=bf2f(t.u[4]); hi.y=bf2f(t.u[5]); hi.z=bf2f(t.u[6]); hi.w=bf2f(t.u[7]);
}

__global__ void k_agg_bb(const int* rp, const int2* se, const float* disb,
                         const unsigned short* xw, const unsigned short* mbuf,
                         const float* w, float* h){
  int wv=threadIdx.x>>6, lane=threadIdx.x&63;
  int n=blockIdx.x*4+wv;
  int g=lane>>3, l=lane&7, d0=l*16;
  int e0=rp[n], e1=rp[n+1];
  float disn=disb[n];
  float4 a0={0,0,0,0},a1={0,0,0,0},a2={0,0,0,0},a3={0,0,0,0};
  float4 c0={0,0,0,0},c1={0,0,0,0},c2={0,0,0,0},c3={0,0,0,0};
  int p=e0+g;
  for(; p+8<e1; p+=16){
    int s0=se[p].x, s1=se[p+8].x;
    float nw0=disb[s0], nw1=disb[s1];
    float4 x0,x1,x2,x3,y0,y1,y2,y3;
    bf8ld(&xw[(long)s0*128+d0], x0, x1);
    bf8ld(&xw[(long)s0*128+d0+8], x2, x3);
    bf8ld(&xw[(long)s1*128+d0], y0, y1);
    bf8ld(&xw[(long)s1*128+d0+8], y2, y3);
    a0.x+=nw0*x0.x; a0.y+=nw0*x0.y; a0.z+=nw0*x0.z; a0.w+=nw0*x0.w;
    a1.x+=nw0*x1.x; a1.y+=nw0*x1.y; a1.z+=nw0*x1.z; a1.w+=nw0*x1.w;
    a2.x+=nw0*x2.x; a2.y+=nw0*x2.y; a2.z+=nw0*x2.z; a2.w+=nw0*x2.w;
    a3.x+=nw0*x3.x; a3.y+=nw0*x3.y; a3.z+=nw0*x3.z; a3.w+=nw0*x3.w;
    c0.x+=nw1*y0.x; c0.y+=nw1*y0.y; c0.z+=nw1*y0.z; c0.w+=nw1*y0.w;
    c1.x+=nw1*y1.x; c1.y+=nw1*y1.y; c1.z+=nw1*y1.z; c1.w+=nw1*y1.w;
    c2.x+=nw1*y2.x; c2.y+=nw1*y2.y; c2.z+=nw1*y2.z; c2.w+=nw1*y2.w;
    c3.x+=nw1*y3.x; c3.y+=nw1*y3.y; c3.z+=nw1*y3.z; c3.w+=nw1*y3.w;
  }
  if(p<e1){
    int s0=se[p].x;
    float nw0=disb[s0];
    float4 x0,x1,x2,x3;
    bf8ld(&xw[(long)s0*128+d0], x0, x1);
    bf8ld(&xw[(long)s0*128+d0+8], x2, x3);
    a0.x+=nw0*x0.x; a0.y+=nw0*x0.y; a0.z+=nw0*x0.z; a0.w+=nw0*x0.w;
    a1.x+=nw0*x1.x; a1.y+=nw0*x1.y; a1.z+=nw0*x1.z; a1.w+=nw0*x1.w;
    a2.x+=nw0*x2.x; a2.y+=nw0*x2.y; a2.z+=nw0*x2.z; a2.w+=nw0*x2.w;
    a3.x+=nw0*x3.x; a3.y+=nw0*x3.y; a3.z+=nw0*x3.z; a3.w+=nw0*x3.w;
  }
  a0.x+=c0.x; a0.y+=c0.y; a0.z+=c0.z; a0.w+=c0.w;
  a1.x+=c1.x; a1.y+=c1.y; a1.z+=c1.z; a1.w+=c1.w;
  a2.x+=c2.x; a2.y+=c2.y; a2.z+=c2.z; a2.w+=c2.w;
  a3.x+=c3.x; a3.y+=c3.y; a3.z+=c3.z; a3.w+=c3.w;
  #pragma unroll
  for(int m=8;m<64;m<<=1){
    a0.x+=__shfl_xor(a0.x,m,64); a0.y+=__shfl_xor(a0.y,m,64);
    a0.z+=__shfl_xor(a0.z,m,64); a0.w+=__shfl_xor(a0.w,m,64);
    a1.x+=__shfl_xor(a1.x,m,64); a1.y+=__shfl_xor(a1.y,m,64);
    a1.z+=__shfl_xor(a1.z,m,64); a1.w+=__shfl_xor(a1.w,m,64);
    a2.x+=__shfl_xor(a2.x,m,64); a2.y+=__shfl_xor(a2.y,m,64);
    a2.z+=__shfl_xor(a2.z,m,64); a2.w+=__shfl_xor(a2.w,m,64);
    a3.x+=__shfl_xor(a3.x,m,64); a3.y+=__shfl_xor(a3.y,m,64);
    a3.z+=__shfl_xor(a3.z,m,64); a3.w+=__shfl_xor(a3.w,m,64);
  }
  if(g==0){
    float d2=disn*disn;
    float4 xs[4], mm[4];
    bf8ld(&xw[(long)n*128+d0], xs[0], xs[1]);
    bf8ld(&xw[(long)n*128+d0+8], xs[2], xs[3]);
    bf8ld(&mbuf[(long)n*128+d0], mm[0], mm[1]);
    bf8ld(&mbuf[(long)n*128+d0+8], mm[2], mm[3]);
    const float4* gb=(const float4*)&w[OW_BGB+d0];
    float4* hp=(float4*)&h[(long)n*128+d0];
    float4 av[4]={a0,a1,a2,a3};
    #pragma unroll
    for(int q=0;q<4;q++){
      float4 hq=hp[q], gq=gb[q];
      hq.x+=fmaxf(av[q].x*disn+d2*xs[q].x+gq.x,0.f)+mm[q].x;
      hq.y+=fmaxf(av[q].y*disn+d2*xs[q].y+gq.y,0.f)+mm[q].y;
      hq.z+=fmaxf(av[q].z*disn+d2*xs[q].z+gq.z,0.f)+mm[q].z;
      hq.w+=fmaxf(av[q].w*disn+d2*xs[q].w+gq.w,0.f)+mm[q].w;
      hp[q]=hq;
    }
  }
}

__global__ void k_heads(const float* hat_h, const float* h, const float* w,
                        const void* old_chi, const void* old_phi, const void* old_psi,
                        const void* old_cb, const void* old_ca, const int* flag, void* out){
  int wv=threadIdx.x>>6, lane=threadIdx.x&63;
  int n=blockIdx.x*4+wv;
  int f32=*flag;
  float s0=fmaxf(hat_h[(long)n*128+lane],0.f), s1=fmaxf(hat_h[(long)n*128+64+lane],0.f);
  float b0=fmaxf(h[(long)n*128+lane],0.f),    b1=fmaxf(h[(long)n*128+64+lane],0.f);
  float r[8];
  r[0]=s0*w[OW_AW+lane]+s1*w[OW_AW+64+lane];
  r[1]=s0*w[OW_CW+lane*3+0]+s1*w[OW_CW+(64+lane)*3+0];
  r[2]=s0*w[OW_CW+lane*3+1]+s1*w[OW_CW+(64+lane)*3+1];
  r[3]=s0*w[OW_CW+lane*3+2]+s1*w[OW_CW+(64+lane)*3+2];
  r[4]=b0*w[OW_BAW+lane]+b1*w[OW_BAW+64+lane];
  r[5]=b0*w[OW_XW+lane*3+0]+b1*w[OW_XW+(64+lane)*3+0];
  r[6]=b0*w[OW_XW+lane*3+1]+b1*w[OW_XW+(64+lane)*3+1];
  r[7]=b0*w[OW_XW+lane*3+2]+b1*w[OW_XW+(64+lane)*3+2];
  for(int m=1;m<64;m<<=1){
    #pragma unroll
    for(int t=0;t<8;t++) r[t]+=__shfl_xor(r[t],m,64);
  }
  if(lane==0){
    float dchi=r[0]+w[OW_AB];
    for(int k=0;k<4;k++)
      stout(out,(long)k*N_+n, wrapf(ldin(old_chi,(long)k*N_+n,f32)+dchi), f32);
    float dphi=r[4]+w[OW_BAB];
    stout(out,(long)4*N_+n, wrapf(ldin(old_phi,n,f32)+dphi), f32);
    stout(out,(long)5*N_+n, wrapf(ldin(old_psi,n,f32)+dphi), f32);
    for(int t=0;t<3;t++){
      stout(out,(long)6*N_+(long)n*3+t, ldin(old_cb,(long)n*3+t,f32)+r[1+t]+w[OW_CB+t], f32);
      stout(out,(long)9*N_+(long)n*3+t, ldin(old_ca,(long)n*3+t,f32)+r[5+t]+w[OW_XB+t], f32);
    }
  }
}

// ---------- host ----------
extern "C" void kernel_launch(void* const* d_in, const int* in_sizes, int n_in,
                              void* d_out, int out_size, void* d_ws, size_t ws_size,
                              hipStream_t stream) {
  (void)in_sizes; (void)n_in; (void)out_size; (void)ws_size;

  char* p=(char*)d_ws;
  auto alloc=[&](size_t bytes)->void*{ void* r=(void*)p; p+=((bytes+255)&~(size_t)255); return r; };
  int*   flag   =(int*)  alloc(16);
  float* warena =(float*)alloc((size_t)OW_TOT*4);
  float* dv     =(float*)alloc(1024*4);
  float* dvf    =(float*)alloc(1024*4);
  float* P      =(float*)alloc((size_t)441*128*4);
  float* sp     =(float*)alloc(441*4);
  float* qp     =(float*)alloc(441*4);
  float* hat_h  =(float*)alloc((size_t)N_*128*4);
  float* hbuf   =(float*)alloc((size_t)N_*128*4);
  float* bufX   =(float*)alloc((size_t)N_*128*4);
  unsigned short* bufXb=(unsigned short*)alloc((size_t)N_*128*2);
  unsigned short* bufMb=(unsigned short*)alloc((size_t)N_*128*2);
  float* xn_sc  =(float*)alloc((size_t)N_*32*4);
  float* xn_bb  =(float*)alloc((size_t)N_*64*4);
  float* we     =(float*)alloc((size_t)ESC*4);
  float* we_csr =(float*)alloc((size_t)ESC*4);
  float* wn     =(float*)alloc((size_t)ESC*4);
  float* an     =(float*)alloc((size_t)N_*4);
  float* bn     =(float*)alloc((size_t)N_*4);
  float* dis    =(float*)alloc((size_t)N_*4);
  float* disb   =(float*)alloc((size_t)N_*4);
  int* rp_sc    =(int*)  alloc((size_t)(N_+1)*4);
  int* rp_bb    =(int*)  alloc((size_t)(N_+1)*4);
  int*  key1_sc =(int*)  alloc((size_t)ESC*4);
  int2* pay1_sc =(int2*) alloc((size_t)ESC*8);
  int*  dstS_sc =(int*)  alloc((size_t)ESC*4);
  int2* csr_se_sc=(int2*)alloc((size_t)ESC*8);
  int*  key1_bb =(int*)  alloc((size_t)EBB*4);
  int2* pay1_bb =(int2*) alloc((size_t)EBB*8);
  int*  dstS_bb =(int*)  alloc((size_t)EBB*4);
  int2* csr_se_bb=(int2*)alloc((size_t)EBB*8);
  int*  hist    =(int*)  alloc((size_t)(RBS+RBB)*256*4);
  int*  tot     =(int*)  alloc(512*4);
  int*  dbase   =(int*)  alloc(512*4);
  unsigned short* wfg_hi =(unsigned short*)alloc(2048*8*2);
  unsigned short* wfg_lo =(unsigned short*)alloc(2048*8*2);
  unsigned short* wfbg_hi=(unsigned short*)alloc(2048*8*2);
  unsigned short* wfi2_hi=(unsigned short*)alloc(2048*8*2);
  unsigned short* wfi1_hi=(unsigned short*)alloc(4096*8*2);
  unsigned short* wfsc_hi=(unsigned short*)alloc(512*8*2);
  unsigned short* wfsc_lo=(unsigned short*)alloc(512*8*2);
  unsigned short* wfbb_hi=(unsigned short*)alloc(1024*8*2);
  unsigned short* wfbb_lo=(unsigned short*)alloc(1024*8*2);

  const int* src_sc=(const int*)d_in[48];
  const int* dst_sc=src_sc+ESC;
  const int* src_bb=(const int*)d_in[49];
  const int* dst_bb=src_bb+EBB;

  k_detect<<<1,1,0,stream>>>(d_in[0], flag);

  CvtArgs ca;
  {
    int map[29]={14,15,16,17,18,19,20,21,22,23,24,25,30,31,32,33,34,35,36,37,
                 38,39,40,41,42,43,44,45,13};
    for(int i=0;i<29;i++) ca.src[i]=d_in[map[i]];
  }
  k_cvtw<<<(OW_TOT+255)/256,256,0,stream>>>(ca, flag, warena);

  // mega prep: wprep | prevec | preP | LN
  k_prep<<<PB_LN,256,0,stream>>>(warena, flag,
      wfg_hi,wfg_lo, wfbg_hi, wfi2_hi, wfi1_hi,
      wfsc_hi,wfsc_lo, wfbb_hi,wfbb_lo,
      d_in[26], d_in[27], d_in[28], d_in[29], dv, dvf, P, sp, qp,
      d_in[0], d_in[1], d_in[2], d_in[3], d_in[4], d_in[5], xn_sc, xn_bb);

  // stable radix CSR build (parallel scan)
  k_rhist<<<RBS+RBB,256,0,stream>>>(dst_sc, dst_bb, 0, hist);
  k_rscanA<<<512,256,0,stream>>>(hist, tot);
  k_rscanB<<<1,256,0,stream>>>(tot, dbase);
  k_rscat<<<RBS+RBB,256,0,stream>>>(0, 1, dst_sc, src_sc, (const int2*)nullptr,
                                    dst_bb, src_bb, (const int2*)nullptr, hist, dbase,
                                    key1_sc, pay1_sc, key1_bb, pay1_bb);
  k_rhist<<<RBS+RBB,256,0,stream>>>(key1_sc, key1_bb, 8, hist);
  k_rscanA<<<512,256,0,stream>>>(hist, tot);
  k_rscanB<<<1,256,0,stream>>>(tot, dbase);
  k_rscat<<<RBS+RBB,256,0,stream>>>(8, 0, key1_sc, (const int*)nullptr, pay1_sc,
                                    key1_bb, (const int*)nullptr, pay1_bb, hist, dbase,
                                    dstS_sc, csr_se_sc, dstS_bb, csr_se_bb);
  k_bounds<<<(int)(((long)ESC+1+EBB+1+255)/256),256,0,stream>>>(dstS_sc, dstS_bb, rp_sc, rp_bb);
  k_degb<<<(N_+255)/256,256,0,stream>>>(rp_bb, disb);

  // featurizer GEMMs (merged)
  const int GB = (N_+63)/64;
  k_mfeat<<<2*GB,256,0,stream>>>(xn_sc, xn_bb, wfsc_hi, wfsc_lo, wfbb_hi, wfbb_lo,
                                 warena, hat_h, hbuf, N_);

  // edge MLP (16-lane groups, 4 edges/group, coalesced P)
  k_w0<<<WBG,256,0,stream>>>(d_in[6],d_in[7],(const int*)d_in[46],(const int*)d_in[47],
                             flag,dvf,P,sp,qp,we);

  // sidechain layers (GEMM || degree merged)
  const int DB = (N_+255)/256;
  const int NB = (ESC+255)/256;
  for(int l=0;l<3;l++){
    k_gemmdeg<<<GB+DB,256,0,stream>>>(hat_h, wfg_hi, wfg_lo, bufX, N_,
                                      rp_sc, csr_se_sc, we, an, bn, dv, we_csr, dis, l);
    k_norm<<<NB,256,0,stream>>>(csr_se_sc, we_csr, dis, wn);
    k_agg_sc<<<N_/4,256,0,stream>>>(rp_sc,csr_se_sc,wn,dis,bufX,warena,hat_h,dv,an,bn,(l<2)?1:0);
  }

  // backbone layers (fused GEMM trio + agg, bf16 path)
  for(int l=0;l<2;l++){
    k_mbb<<<GB,256,0,stream>>>(hbuf, hat_h, wfi1_hi, wfbg_hi, wfi2_hi,
                               warena+OW_IB1, warena+OW_IB2, bufXb, bufMb, N_);
    k_agg_bb<<<N_/4,256,0,stream>>>(rp_bb,csr_se_bb,disb,bufXb,bufMb,warena,hbuf);
  }

  k_heads<<<N_/4,256,0,stream>>>(hat_h,hbuf,warena,
                                 d_in[8],d_in[9],d_in[10],d_in[11],d_in[12],flag,d_out);
}

// Round 16
// 563.384 us; speedup vs baseline: 1.2275x; 1.2275x over previous
//
#include <hip/hip_runtime.h>
#include <stdint.h>

#define DEVI __device__ __forceinline__

constexpr int N_   = 50000;
constexpr int ESC  = 600000;
constexpr int EBB  = 100000;
constexpr int NRES = 21;
constexpr float PI_F = 3.14159f;

// radix geometry
constexpr int RCH = 2048;
constexpr int RBS = (ESC + RCH - 1)/RCH;  // 293
constexpr int RBB = (EBB + RCH - 1)/RCH;  // 49

typedef __attribute__((ext_vector_type(8))) short short8v;
typedef __attribute__((ext_vector_type(4))) float f32x4;

// ---------- dtype helpers ----------
DEVI float bf2f(unsigned short u){ return __uint_as_float(((unsigned)u)<<16); }
DEVI unsigned short f2bf(float f){
  unsigned x = __float_as_uint(f);
  unsigned r = (x + 0x7FFFu + ((x>>16)&1u))>>16;
  return (unsigned short)r;
}
DEVI float ldin(const void* p, long i, int f32){
  return f32 ? ((const float*)p)[i] : bf2f(((const unsigned short*)p)[i]);
}
DEVI void stout(void* p, long i, float v, int f32){
  if(f32) ((float*)p)[i]=v; else ((unsigned short*)p)[i]=f2bf(v);
}
DEVI float wrapf(float a){
  float t = a + PI_F;
  const float TP = 2.f*PI_F;
  t -= floorf(t/TP)*TP;
  return t - PI_F;
}

// ---------- weight arena offsets ----------
constexpr int OW_SC_LN_G=0;
constexpr int OW_SC_LN_B=OW_SC_LN_G+19;
constexpr int OW_SC_W  = OW_SC_LN_B+19;
constexpr int OW_SC_B  = OW_SC_W+19*128;
constexpr int OW_BB_LN_G=OW_SC_B+128;
constexpr int OW_BB_LN_B=OW_BB_LN_G+38;
constexpr int OW_BB_W = OW_BB_LN_B+38;
constexpr int OW_BB_B = OW_BB_W+38*128;
constexpr int OW_E_LN_G=OW_BB_B+128;
constexpr int OW_E_LN_B=OW_E_LN_G+66;
constexpr int OW_EW1 = OW_E_LN_B+66;
constexpr int OW_EB1 = OW_EW1+66*128;
constexpr int OW_GW  = OW_EB1+128;
constexpr int OW_GB  = OW_GW+128*128;
constexpr int OW_BGW = OW_GB+128;
constexpr int OW_BGB = OW_BGW+128*128;
constexpr int OW_IW1 = OW_BGB+128;
constexpr int OW_IB1 = OW_IW1+256*128;
constexpr int OW_IW2 = OW_IB1+128;
constexpr int OW_IB2 = OW_IW2+128*128;
constexpr int OW_AW  = OW_IB2+128;
constexpr int OW_AB  = OW_AW+128;
constexpr int OW_BAW = OW_AB+1;
constexpr int OW_BAB = OW_BAW+128;
constexpr int OW_CW  = OW_BAB+1;
constexpr int OW_CB  = OW_CW+128*3;
constexpr int OW_XW  = OW_CB+3;
constexpr int OW_XB  = OW_XW+128*3;
constexpr int OW_RES = OW_XB+3;
constexpr int OW_TOT = OW_RES+21*32;

// ---------- basic kernels ----------
__global__ void k_detect(const void* vcom, int* flag){
  const unsigned short* u = (const unsigned short*)vcom;
  int insane=0;
  for(int i=0;i<64;i+=2){
    float f = bf2f(u[i]);
    float a = fabsf(f);
    if(!(a<1e5f) || (a!=0.0f && a<1e-5f)) insane++;
  }
  *flag = (insane>=8)?1:0;
}

struct CvtArgs { const void* src[29]; };

__global__ void k_cvtw(CvtArgs a, const int* flag, float* w){
  static constexpr int offs[30] = {
    OW_SC_LN_G,OW_SC_LN_B,OW_SC_W,OW_SC_B,OW_BB_LN_G,OW_BB_LN_B,OW_BB_W,OW_BB_B,
    OW_E_LN_G,OW_E_LN_B,OW_EW1,OW_EB1,OW_GW,OW_GB,OW_BGW,OW_BGB,OW_IW1,OW_IB1,
    OW_IW2,OW_IB2,OW_AW,OW_AB,OW_BAW,OW_BAB,OW_CW,OW_CB,OW_XW,OW_XB,OW_RES,OW_TOT};
  int f32=*flag;
  for(int t=blockIdx.x*blockDim.x+threadIdx.x; t<OW_TOT; t+=gridDim.x*blockDim.x){
    int s=0;
    while(t>=offs[s+1]) s++;
    w[t]=ldin(a.src[s], t-offs[s], f32);
  }
}

// W[K x 128] -> MFMA fragment order (zero-padded past Kreal), split hi/lo bf16.
DEVI void wprep_pad(const float* W, int Kreal, unsigned short* hi, unsigned short* lo, int idx){
  int lane=idx&63, nt=(idx>>6)&7, kt=idx>>9;
  int n = nt*16 + (lane&15);
  int kbase = kt*32 + (lane>>4)*8;
  #pragma unroll
  for(int i=0;i<8;i++){
    int k=kbase+i;
    float v = (k<Kreal) ? W[(long)k*128 + n] : 0.f;
    unsigned short h = f2bf(v);
    hi[(long)idx*8+i]=h;
    if(lo){ float r = v - bf2f(h); lo[(long)idx*8+i]=f2bf(r); }
  }
}

// ---------- mega prep kernel: wprep | prevec | preP | LN ----------
constexpr int PB_WP = 46;
constexpr int PB_PV = PB_WP+1;
constexpr int PB_PP = PB_PV+441;
constexpr int PB_LN = PB_PP + (2*N_+3)/4;

__global__ void k_prep(const float* w, const int* flag,
    unsigned short* g_hi, unsigned short* g_lo,
    unsigned short* bg_hi,
    unsigned short* i2_hi,
    unsigned short* i1_hi,
    unsigned short* sc_hi, unsigned short* sc_lo,
    unsigned short* bb_hi, unsigned short* bb_lo,
    const void* eW2, const void* eb2, const void* euW, const void* eub,
    float* dv, float* dvf, float* P, float* sp, float* qp,
    const void* vcom, const void* sbfchi,
    const void* xca, const void* vcb, const void* sphi, const void* spsi,
    float* xn_sc, float* xn_bb){
  __shared__ float pv[64];
  int b=blockIdx.x;
  if(b<PB_WP){
    int idx=b*256+threadIdx.x;
    if(idx<2048)       wprep_pad(w+OW_GW,  128, g_hi,  g_lo,  idx);
    else if(idx<4096)  wprep_pad(w+OW_BGW, 128, bg_hi, nullptr, idx-2048);
    else if(idx<6144)  wprep_pad(w+OW_IW2, 128, i2_hi, nullptr, idx-4096);
    else if(idx<10240) wprep_pad(w+OW_IW1, 256, i1_hi, nullptr, idx-6144);
    else if(idx<10752) wprep_pad(w+OW_SC_W, 19, sc_hi, sc_lo, idx-10240);
    else if(idx<11776) wprep_pad(w+OW_BB_W, 38, bb_hi, bb_lo, idx-10752);
  } else if(b<PB_PV){
    int j=threadIdx.x; int f32=*flag;
    if(j<128){
      const float* g=w+OW_E_LN_G; const float* bb=w+OW_E_LN_B; const float* W1=w+OW_EW1;
      float A=g[0]*W1[j], C=g[1]*W1[128+j];
      float G=0,B=0;
      for(int i=0;i<66;i++){ float wij=W1[i*128+j]; G+=g[i]*wij; B+=bb[i]*wij; }
      B += w[OW_EB1+j];
      float v2=0; for(int k=0;k<128;k++) v2+=ldin(eW2,(long)j*128+k,f32);
      float us=0,ud=0;
      for(int k=0;k<128;k++){ us+=ldin(euW,(long)j*128+k,f32); ud+=ldin(euW,(long)(128+j)*128+k,f32); }
      dv[640+j]=us*(1.f/128.f); dv[768+j]=ud*(1.f/128.f);
      dvf[j]=A; dvf[128+j]=C; dvf[256+j]=G; dvf[384+j]=B; dvf[512+j]=v2*(1.f/128.f);
      if(j==0){
        float s=0,t=0;
        for(int k=0;k<128;k++){ s+=ldin(eb2,k,f32); t+=ldin(eub,k,f32); }
        dv[896]=s*(1.f/128.f); dv[897]=t*(1.f/128.f);
        dvf[640]=s*(1.f/128.f);
      }
    }
  } else if(b<PB_PP){
    int c=b-PB_PV, j=threadIdx.x;
    const float* res=w+OW_RES;
    if(j<32) pv[j]=res[(c/NRES)*32+j];
    else if(j<64) pv[j]=res[(c%NRES)*32+(j-32)];
    __syncthreads();
    if(j<128){
      const float* g=w+OW_E_LN_G; const float* W1=w+OW_EW1;
      float s=0;
      for(int i=0;i<64;i++) s += pv[i]*g[2+i]*W1[(2+i)*128+j];
      P[c*128+j]=s;
      if(j==0){ float a=0,q=0; for(int i=0;i<64;i++){a+=pv[i]; q+=pv[i]*pv[i];} sp[c]=a; qp[c]=q; }
    }
  } else {
    int wv=threadIdx.x>>6, lane=threadIdx.x&63;
    long gw=(long)(b-PB_PP)*4+wv;
    int f32=*flag;
    if(gw<N_){
      int n=(int)gw;
      float x=0.f;
      if(lane<3) x=ldin(vcom,(long)n*3+lane,f32);
      else if(lane<19) x=ldin(sbfchi,(long)n*16+(lane-3),f32);
      float s=x, q=x*x;
      for(int m=1;m<64;m<<=1){ s+=__shfl_xor(s,m,64); q+=__shfl_xor(q,m,64); }
      float mean=s*(1.f/19.f);
      float istd=rsqrtf(fmaxf(q*(1.f/19.f)-mean*mean,0.f)+1e-5f);
      if(lane<32){
        float xn=(lane<19)? (x-mean)*istd*w[OW_SC_LN_G+lane]+w[OW_SC_LN_B+lane] : 0.f;
        xn_sc[(long)n*32+lane]=xn;
      }
    } else if(gw<2L*N_){
      int n=(int)(gw-N_);
      float x=0.f;
      if(lane<3) x=ldin(xca,(long)n*3+lane,f32);
      else if(lane<6) x=ldin(vcb,(long)n*3+(lane-3),f32);
      else if(lane<22) x=ldin(sphi,(long)n*16+(lane-6),f32);
      else if(lane<38) x=ldin(spsi,(long)n*16+(lane-22),f32);
      float s=x, q=x*x;
      for(int m=1;m<64;m<<=1){ s+=__shfl_xor(s,m,64); q+=__shfl_xor(q,m,64); }
      float mean=s*(1.f/38.f);
      float istd=rsqrtf(fmaxf(q*(1.f/38.f)-mean*mean,0.f)+1e-5f);
      float xn=(lane<38)? (x-mean)*istd*w[OW_BB_LN_G+lane]+w[OW_BB_LN_B+lane] : 0.f;
      xn_bb[(long)n*64+lane]=xn;
    }
  }
}

// ---------- stable 2-pass radix CSR build (RCH=2048, parallel scan) ----------
__global__ void k_rhist(const int* key_sc, const int* key_bb, int shift, int* hist){
  __shared__ int h[256];
  h[threadIdx.x]=0; __syncthreads();
  int g = blockIdx.x>=RBS;
  const int* key = g? key_bb : key_sc;
  int E = g? EBB : ESC;
  int b = g? blockIdx.x-RBS : blockIdx.x;
  int base=b*RCH;
  for(int r=0;r<RCH/256;r++){
    int idx=base+r*256+threadIdx.x;
    if(idx<E) atomicAdd(&h[(key[idx]>>shift)&255],1);
  }
  __syncthreads();
  hist[(long)blockIdx.x*256+threadIdx.x]=h[threadIdx.x];
}
__global__ void k_rscanA(int* hist, int* tot){
  __shared__ int sA[512], sB[512];
  int g = blockIdx.x>=256;
  int d = blockIdx.x&255;
  int NB = g? RBB : RBS;
  int* H = hist + (g? (long)RBS*256 : 0);
  int t=threadIdx.x;
  int i0=t, i1=t+256;
  int o0 = (i0<NB)? H[(long)i0*256+d] : 0;
  int o1 = (i1<NB)? H[(long)i1*256+d] : 0;
  sA[i0]=o0; sA[i1]=o1;
  __syncthreads();
  int* a=sA; int* b=sB;
  for(int off=1; off<512; off<<=1){
    b[i0] = a[i0] + ((i0>=off)? a[i0-off]:0);
    b[i1] = a[i1] + ((i1>=off)? a[i1-off]:0);
    __syncthreads();
    int* tmp=a; a=b; b=tmp;
  }
  if(i0<NB) H[(long)i0*256+d] = a[i0]-o0;
  if(i1<NB) H[(long)i1*256+d] = a[i1]-o1;
  if(t==255) tot[(g?256:0)+d] = a[511];
}
__global__ void k_rscanB(const int* tot, int* base){
  __shared__ int sA[256], sB[256];
  int t=threadIdx.x;
  for(int g=0;g<2;g++){
    int o=tot[g*256+t];
    sA[t]=o; __syncthreads();
    int* a=sA; int* b=sB;
    for(int off=1; off<256; off<<=1){
      b[t] = a[t] + ((t>=off)? a[t-off]:0);
      __syncthreads();
      int* tmp=a; a=b; b=tmp;
    }
    base[g*256+t] = a[t]-o;
    __syncthreads();
  }
}
__global__ void k_rscat(int shift, int first,
    const int* kin_sc, const int* srcv_sc, const int2* pin_sc,
    const int* kin_bb, const int* srcv_bb, const int2* pin_bb,
    const int* hist, const int* dbase,
    int* kout_sc, int2* pout_sc, int* kout_bb, int2* pout_bb){
  __shared__ int running[256];
  __shared__ int Hb[256];
  __shared__ int whist[4][256];
  __shared__ int pw[4][256];
  int tid=threadIdx.x, lane=tid&63, w=tid>>6;
  int g = blockIdx.x>=RBS;
  const int* kin  = g? kin_bb : kin_sc;
  const int* srcv = g? srcv_bb: srcv_sc;
  const int2* pin = g? pin_bb : pin_sc;
  int* kout  = g? kout_bb : kout_sc;
  int2* pout = g? pout_bb : pout_sc;
  int E = g? EBB : ESC;
  int b = g? blockIdx.x-RBS : blockIdx.x;
  running[tid]=0;
  Hb[tid]=hist[(long)blockIdx.x*256+tid] + dbase[(g?256:0)+tid];
  int base=b*RCH;
  for(int r=0;r<RCH/256;r++){
    __syncthreads();
    whist[0][tid]=0; whist[1][tid]=0; whist[2][tid]=0; whist[3][tid]=0;
    __syncthreads();
    int idx=base+r*256+tid;
    bool valid = idx<E;
    int key=0, digit=0; int2 pay; pay.x=0; pay.y=0;
    if(valid){
      key=kin[idx];
      digit=(key>>shift)&255;
      if(first){ pay.x=srcv[idx]; pay.y=idx; }
      else pay=pin[idx];
    }
    unsigned long long act=__ballot(valid);
    unsigned long long same=act;
    #pragma unroll
    for(int k=0;k<8;k++){
      unsigned long long m=__ballot(valid && ((digit>>k)&1));
      same &= ((digit>>k)&1)? m : ~m;
    }
    same &= act;
    unsigned long long below=(1ULL<<lane)-1ULL;
    int wrank=__popcll(same & below);
    if(valid && wrank==0) whist[w][digit]=__popcll(same);
    __syncthreads();
    int c0=whist[0][tid], c1=whist[1][tid], c2=whist[2][tid], c3=whist[3][tid];
    pw[0][tid]=0; pw[1][tid]=c0; pw[2][tid]=c0+c1; pw[3][tid]=c0+c1+c2;
    __syncthreads();
    if(valid){
      int pos=Hb[digit]+running[digit]+pw[w][digit]+wrank;
      kout[pos]=key; pout[pos]=pay;
    }
    __syncthreads();
    running[tid]+=c0+c1+c2+c3;
  }
}
__global__ void k_bounds(const int* dstS_sc, const int* dstS_bb, int* rp_sc, int* rp_bb){
  long i=(long)blockIdx.x*blockDim.x+threadIdx.x;
  if(i<=ESC){
    int cur = (i<ESC)? dstS_sc[i] : N_;
    int prev= (i>0)? dstS_sc[i-1] : -1;
    for(int d=prev+1; d<=cur; d++) rp_sc[d]=(int)i;
  } else if(i <= (long)ESC+1+EBB){
    long j=i-(ESC+1);
    int cur = (j<EBB)? dstS_bb[j] : N_;
    int prev= (j>0)? dstS_bb[j-1] : -1;
    for(int d=prev+1; d<=cur; d++) rp_bb[d]=(int)j;
  }
}
__global__ void k_degb(const int* rp, float* disb){
  int n=blockIdx.x*blockDim.x+threadIdx.x;
  if(n<N_) disb[n]=rsqrtf(1.f+(float)(rp[n+1]-rp[n]));
}

// ---------- edge MLP: 16-lane groups, 4 edges/group, dvf cached in registers ----------
constexpr int WBG = (ESC + 63)/64;  // 9375
__global__ __launch_bounds__(256,4) void k_w0(const void* dsc, const void* dmin,
    const int* ri_, const int* rj_, const int* flag, const float* dvf,
    const float* P, const float* sp, const float* qp, float* we){
  int wv=threadIdx.x>>6, lane=threadIdx.x&63;
  int g=lane>>4, l=lane&15;
  long ebase=(long)blockIdx.x*64 + wv*16 + g*4;
  int f32=*flag;
  int j0=l*8;
  float4 A0=*(const float4*)&dvf[j0],     A1=*(const float4*)&dvf[j0+4];
  float4 C0=*(const float4*)&dvf[128+j0], C1=*(const float4*)&dvf[128+j0+4];
  float4 G0=*(const float4*)&dvf[256+j0], G1=*(const float4*)&dvf[256+j0+4];
  float4 B0=*(const float4*)&dvf[384+j0], B1=*(const float4*)&dvf[384+j0+4];
  float4 V0=*(const float4*)&dvf[512+j0], V1=*(const float4*)&dvf[512+j0+4];
  float eb2=dvf[640];
  #pragma unroll
  for(int k=0;k<4;k++){
    long e=ebase+k;
    bool val = e<ESC;
    long ee = val? e : 0;
    float d1=ldin(dsc,ee,f32), d2=ldin(dmin,ee,f32);
    int c=ri_[ee]*NRES+rj_[ee];
    float m=(d1+d2+sp[c])*(1.f/66.f);
    float ms=(d1*d1+d2*d2+qp[c])*(1.f/66.f);
    float istd=rsqrtf(fmaxf(ms-m*m,0.f)+1e-5f);
    float nmi=-m*istd;
    float4 P0=*(const float4*)&P[(long)c*128+j0];
    float4 P1=*(const float4*)&P[(long)c*128+j0+4];
    float acc=0.f, t, hid;
    t=fmaf(d1,A0.x,fmaf(d2,C0.x,P0.x)); hid=fmaf(istd,t,fmaf(nmi,G0.x,B0.x)); acc=fmaf(fmaxf(hid,0.f),V0.x,acc);
    t=fmaf(d1,A0.y,fmaf(d2,C0.y,P0.y)); hid=fmaf(istd,t,fmaf(nmi,G0.y,B0.y)); acc=fmaf(fmaxf(hid,0.f),V0.y,acc);
    t=fmaf(d1,A0.z,fmaf(d2,C0.z,P0.z)); hid=fmaf(istd,t,fmaf(nmi,G0.z,B0.z)); acc=fmaf(fmaxf(hid,0.f),V0.z,acc);
    t=fmaf(d1,A0.w,fmaf(d2,C0.w,P0.w)); hid=fmaf(istd,t,fmaf(nmi,G0.w,B0.w)); acc=fmaf(fmaxf(hid,0.f),V0.w,acc);
    t=fmaf(d1,A1.x,fmaf(d2,C1.x,P1.x)); hid=fmaf(istd,t,fmaf(nmi,G1.x,B1.x)); acc=fmaf(fmaxf(hid,0.f),V1.x,acc);
    t=fmaf(d1,A1.y,fmaf(d2,C1.y,P1.y)); hid=fmaf(istd,t,fmaf(nmi,G1.y,B1.y)); acc=fmaf(fmaxf(hid,0.f),V1.y,acc);
    t=fmaf(d1,A1.z,fmaf(d2,C1.z,P1.z)); hid=fmaf(istd,t,fmaf(nmi,G1.z,B1.z)); acc=fmaf(fmaxf(hid,0.f),V1.z,acc);
    t=fmaf(d1,A1.w,fmaf(d2,C1.w,P1.w)); hid=fmaf(istd,t,fmaf(nmi,G1.w,B1.w)); acc=fmaf(fmaxf(hid,0.f),V1.w,acc);
    #pragma unroll
    for(int msk=1;msk<16;msk<<=1) acc+=__shfl_xor(acc,msk,64);
    if(l==0 && val) we[e]=acc+eb2;
  }
}

// ---------- split-bf16 MFMA GEMM core ----------
DEVI f32x4 MFMA(short8v a, short8v b, f32x4 c){
  return __builtin_amdgcn_mfma_f32_16x16x32_bf16(a,b,c,0,0,0);
}
DEVI void cvt8(float4 a0, float4 a1, short8v& hi, short8v& lo){
  float av[8]={a0.x,a0.y,a0.z,a0.w,a1.x,a1.y,a1.z,a1.w};
  union{short8v v; unsigned short u[8];} H,L;
  #pragma unroll
  for(int i=0;i<8;i++){
    unsigned short h=f2bf(av[i]);
    float r=av[i]-bf2f(h);
    H.u[i]=h; L.u[i]=f2bf(r);
  }
  hi=H.v; lo=L.v;
}
DEVI short8v cvt8hi(float4 a0, float4 a1){
  union{short8v v; unsigned short u[8];} H;
  H.u[0]=f2bf(a0.x); H.u[1]=f2bf(a0.y); H.u[2]=f2bf(a0.z); H.u[3]=f2bf(a0.w);
  H.u[4]=f2bf(a1.x); H.u[5]=f2bf(a1.y); H.u[6]=f2bf(a1.z); H.u[7]=f2bf(a1.w);
  return H.v;
}

template<int KT, int LDA>
DEVI void mgemm_body(int bid, const float* A1, const float* A2,
    const unsigned short* Whi, const unsigned short* Wlo,
    const float* bias, float* C, int relu, int accum, int M){
  const int lane = threadIdx.x & 63;
  const int wid  = threadIdx.x >> 6;
  const int r0   = bid*64 + wid*16;
  const int mrow = lane & 15;
  const int kg   = lane >> 4;
  long arow = (long)min(r0 + mrow, M-1);
  f32x4 acc[8];
  #pragma unroll
  for(int t=0;t<8;t++) acc[t]=(f32x4){0.f,0.f,0.f,0.f};

  #pragma unroll
  for(int kt=0; kt<KT; kt++){
    const float* A = (KT==8 && kt>=4) ? A2 : A1;
    int kb = (kt&3)*32 + kg*8;
    float4 a0 = *(const float4*)&A[arow*LDA + kb];
    float4 a1 = *(const float4*)&A[arow*LDA + kb + 4];
    short8v ah, al; cvt8(a0,a1,ah,al);
    #pragma unroll
    for(int nt=0;nt<8;nt++){
      long off = (((long)kt*8+nt)*64 + lane)*8;
      short8v wh = *(const short8v*)&Whi[off];
      short8v wl = *(const short8v*)&Wlo[off];
      acc[nt] = MFMA(ah, wh, acc[nt]);
      acc[nt] = MFMA(al, wh, acc[nt]);
      acc[nt] = MFMA(ah, wl, acc[nt]);
      acc[nt] = MFMA(al, wl, acc[nt]);
    }
  }

  #pragma unroll
  for(int nt=0;nt<8;nt++){
    int col = nt*16 + mrow;
    float bj = bias ? bias[col] : 0.f;
    #pragma unroll
    for(int r=0;r<4;r++){
      int row = r0 + kg*4 + r;
      if(row >= M) continue;
      long idx = (long)row*128 + col;
      float v = acc[nt][r] + bj;
      if(relu) v = fmaxf(v,0.f);
      if(accum) v += C[idx];
      C[idx] = v;
    }
  }
}

// sc layer: gW GEMM overlapped with degree pass (independent producers)
__global__ __launch_bounds__(256,4) void k_gemmdeg(const float* hat_h,
    const unsigned short* Whi, const unsigned short* Wlo, float* C, int M,
    const int* rp, const int2* se, const float* we_edge,
    const float* an, const float* bn, const float* dv,
    float* we_csr, float* dis, int layer){
  int GBl=(M+63)/64;
  if((int)blockIdx.x < GBl){
    mgemm_body<4,128>(blockIdx.x, hat_h, nullptr, Whi, Wlo, nullptr, C, 0, 0, M);
  } else {
    int n=(blockIdx.x-GBl)*256+threadIdx.x;
    if(n>=N_) return;
    int e0=rp[n], e1=rp[n+1];
    float s=1.f;
    if(layer==0){
      for(int p=e0;p<e1;p++){ float ww=we_edge[se[p].y]; we_csr[p]=ww; s+=ww; }
    } else {
      float add_n = bn[n] + dv[897];
      for(int p=e0;p<e1;p++){
        float ww=we_csr[p] + an[se[p].x] + add_n;
        we_csr[p]=ww; s+=ww;
      }
    }
    dis[n]=rsqrtf(fmaxf(s,1e-6f));
  }
}

// wn[p] = dis[src]*wc[p]
__global__ void k_norm(const int2* se, const float* we_csr, const float* dis, float* wn){
  int p=blockIdx.x*blockDim.x+threadIdx.x;
  if(p<ESC) wn[p]=dis[se[p].x]*we_csr[p];
}

// featurizer: both small GEMMs in one launch
__global__ __launch_bounds__(256,4) void k_mfeat(const float* xn_sc, const float* xn_bb,
    const unsigned short* schi, const unsigned short* sclo,
    const unsigned short* bbhi, const unsigned short* bblo,
    const float* w, float* hat_h, float* hbuf, int M){
  int GBl=(M+63)/64;
  if((int)blockIdx.x < GBl)
    mgemm_body<1,32>(blockIdx.x, xn_sc, nullptr, schi, sclo, w+OW_SC_B, hat_h, 0,0,M);
  else
    mgemm_body<2,64>(blockIdx.x-GBl, xn_bb, nullptr, bbhi, bblo, w+OW_BB_B, hbuf, 0,0,M);
}

// fused bb layer (backbone branch is NOT chaotic -> plain bf16 suffices)
__global__ __launch_bounds__(256,4) void k_mbb(const float* h, const float* hh,
    const unsigned short* W1hi,
    const unsigned short* W2hi,
    const unsigned short* W3hi,
    const float* b1, const float* b2,
    unsigned short* xwout, unsigned short* mout, int M){
  __shared__ unsigned short hids[64*136];
  const int lane = threadIdx.x & 63;
  const int wid  = threadIdx.x >> 6;
  const int r0   = blockIdx.x*64 + wid*16;
  const int mrow = lane & 15;
  const int kg   = lane >> 4;
  long arow = (long)min(r0 + mrow, M-1);
  f32x4 acc1[8], acc2[8];
  #pragma unroll
  for(int t=0;t<8;t++){ acc1[t]=(f32x4){0,0,0,0}; acc2[t]=(f32x4){0,0,0,0}; }

  #pragma unroll
  for(int kt=0; kt<8; kt++){
    const float* A = (kt>=4) ? hh : h;
    int kb = (kt&3)*32 + kg*8;
    float4 a0 = *(const float4*)&A[arow*128 + kb];
    float4 a1 = *(const float4*)&A[arow*128 + kb + 4];
    short8v ah = cvt8hi(a0,a1);
    #pragma unroll
    for(int nt=0;nt<8;nt++){
      long off = (((long)kt*8+nt)*64 + lane)*8;
      acc1[nt] = MFMA(ah, *(const short8v*)&W1hi[off], acc1[nt]);
    }
    if(kt<4){
      #pragma unroll
      for(int nt=0;nt<8;nt++){
        long off = (((long)kt*8+nt)*64 + lane)*8;
        acc2[nt] = MFMA(ah, *(const short8v*)&W2hi[off], acc2[nt]);
      }
    }
  }

  #pragma unroll
  for(int nt=0;nt<8;nt++){
    int col = nt*16 + mrow;
    float bj = b1[col];
    #pragma unroll
    for(int r=0;r<4;r++){
      int rloc = wid*16 + kg*4 + r;
      int row = r0 + kg*4 + r;
      hids[rloc*136 + col] = f2bf(fmaxf(acc1[nt][r] + bj, 0.f));
      if(row < M) xwout[(long)row*128 + col] = f2bf(acc2[nt][r]);
    }
  }
  __syncthreads();

  f32x4 acc3[8];
  #pragma unroll
  for(int t=0;t<8;t++) acc3[t]=(f32x4){0,0,0,0};
  int rloc = wid*16 + mrow;
  #pragma unroll
  for(int kt=0; kt<4; kt++){
    int kb = kt*32 + kg*8;
    short8v ah = *(const short8v*)&hids[rloc*136 + kb];
    #pragma unroll
    for(int nt=0;nt<8;nt++){
      long off = (((long)kt*8+nt)*64 + lane)*8;
      acc3[nt] = MFMA(ah, *(const short8v*)&W3hi[off], acc3[nt]);
    }
  }
  #pragma unroll
  for(int nt=0;nt<8;nt++){
    int col = nt*16 + mrow;
    float bj = b2[col];
    #pragma unroll
    for(int r=0;r<4;r++){
      int row = r0 + kg*4 + r;
      if(row < M) mout[(long)row*128 + col] = f2bf(acc3[nt][r] + bj);
    }
  }
}

// ---------- aggregation: 16 lanes/edge, 2-edge unroll per group (round-14 shape) ----------
__global__ void k_agg_sc(const int* rp, const int2* se, const float* wn,
                         const float* dis, const float* xw, const float* w,
                         float* hat_h, const float* dv, float* an, float* bn, int withdot){
  int wv=threadIdx.x>>6, lane=threadIdx.x&63;
  int n=blockIdx.x*4+wv;
  int g=lane>>4, l=lane&15, d0=l*8;
  float disn=dis[n];
  float4 aA={0,0,0,0}, aB={0,0,0,0}, cA={0,0,0,0}, cB={0,0,0,0};
  int e0=rp[n], e1=rp[n+1];
  int p=e0+g;
  for(; p+4<e1; p+=8){
    int s0=se[p].x, s1=se[p+4].x;
    float nw0=wn[p], nw1=wn[p+4];
    float4 xa0=*(const float4*)&xw[(long)s0*128+d0];
    float4 xb0=*(const float4*)&xw[(long)s0*128+d0+4];
    float4 xa1=*(const float4*)&xw[(long)s1*128+d0];
    float4 xb1=*(const float4*)&xw[(long)s1*128+d0+4];
    aA.x+=nw0*xa0.x; aA.y+=nw0*xa0.y; aA.z+=nw0*xa0.z; aA.w+=nw0*xa0.w;
    aB.x+=nw0*xb0.x; aB.y+=nw0*xb0.y; aB.z+=nw0*xb0.z; aB.w+=nw0*xb0.w;
    cA.x+=nw1*xa1.x; cA.y+=nw1*xa1.y; cA.z+=nw1*xa1.z; cA.w+=nw1*xa1.w;
    cB.x+=nw1*xb1.x; cB.y+=nw1*xb1.y; cB.z+=nw1*xb1.z; cB.w+=nw1*xb1.w;
  }
  if(p<e1){
    int s0=se[p].x;
    float nw0=wn[p];
    float4 xa0=*(const float4*)&xw[(long)s0*128+d0];
    float4 xb0=*(const float4*)&xw[(long)s0*128+d0+4];
    aA.x+=nw0*xa0.x; aA.y+=nw0*xa0.y; aA.z+=nw0*xa0.z; aA.w+=nw0*xa0.w;
    aB.x+=nw0*xb0.x; aB.y+=nw0*xb0.y; aB.z+=nw0*xb0.z; aB.w+=nw0*xb0.w;
  }
  aA.x+=cA.x; aA.y+=cA.y; aA.z+=cA.z; aA.w+=cA.w;
  aB.x+=cB.x; aB.y+=cB.y; aB.z+=cB.z; aB.w+=cB.w;
  #pragma unroll
  for(int m=16;m<64;m<<=1){
    aA.x+=__shfl_xor(aA.x,m,64); aA.y+=__shfl_xor(aA.y,m,64);
    aA.z+=__shfl_xor(aA.z,m,64); aA.w+=__shfl_xor(aA.w,m,64);
    aB.x+=__shfl_xor(aB.x,m,64); aB.y+=__shfl_xor(aB.y,m,64);
    aB.z+=__shfl_xor(aB.z,m,64); aB.w+=__shfl_xor(aB.w,m,64);
  }
  float d2=disn*disn;
  float4 xsA=*(const float4*)&xw[(long)n*128+d0];
  float4 xsB=*(const float4*)&xw[(long)n*128+d0+4];
  float4 gbA=*(const float4*)&w[OW_GB+d0];
  float4 gbB=*(const float4*)&w[OW_GB+d0+4];
  float4 hoA=*(const float4*)&hat_h[(long)n*128+d0];
  float4 hoB=*(const float4*)&hat_h[(long)n*128+d0+4];
  float4 hA, hB;
  hA.x=hoA.x+fmaxf(aA.x*disn+d2*xsA.x+gbA.x,0.f);
  hA.y=hoA.y+fmaxf(aA.y*disn+d2*xsA.y+gbA.y,0.f);
  hA.z=hoA.z+fmaxf(aA.z*disn+d2*xsA.z+gbA.z,0.f);
  hA.w=hoA.w+fmaxf(aA.w*disn+d2*xsA.w+gbA.w,0.f);
  hB.x=hoB.x+fmaxf(aB.x*disn+d2*xsB.x+gbB.x,0.f);
  hB.y=hoB.y+fmaxf(aB.y*disn+d2*xsB.y+gbB.y,0.f);
  hB.z=hoB.z+fmaxf(aB.z*disn+d2*xsB.z+gbB.z,0.f);
  hB.w=hoB.w+fmaxf(aB.w*disn+d2*xsB.w+gbB.w,0.f);
  if(g==0){
    *(float4*)&hat_h[(long)n*128+d0]=hA;
    *(float4*)&hat_h[(long)n*128+d0+4]=hB;
  }
  if(withdot){
    float4 usA=*(const float4*)&dv[640+d0], usB=*(const float4*)&dv[640+d0+4];
    float4 udA=*(const float4*)&dv[768+d0], udB=*(const float4*)&dv[768+d0+4];
    float a = hA.x*usA.x+hA.y*usA.y+hA.z*usA.z+hA.w*usA.w
            + hB.x*usB.x+hB.y*usB.y+hB.z*usB.z+hB.w*usB.w;
    float b = hA.x*udA.x+hA.y*udA.y+hA.z*udA.z+hA.w*udA.w
            + hB.x*udB.x+hB.y*udB.y+hB.z*udB.z+hB.w*udB.w;
    #pragma unroll
    for(int m=1;m<16;m<<=1){ a+=__shfl_xor(a,m,64); b+=__shfl_xor(b,m,64); }
    if(lane==0){ an[n]=a; bn[n]=b; }
  }
}

DEVI void bf8ld(const unsigned short* p, float4& lo, float4& hi){
  union{short8v v; unsigned short u[8];} t;
  t.v = *(const short8v*)p;
  lo.x=bf2f(t.u[0]); lo.y=bf2f(t.u[1]); lo.z=bf2f(t.u[2]); lo.w=bf2f(t.u[3]);
  hi.x=bf2f(t.u[4]); hi.y=bf2f(t.u[5]); hi.z=bf2f(t.u[6]); hi.w=bf2f(t.u[7]);
}

__global__ void k_agg_bb(const int* rp, const int2* se, const float* disb,
                         const unsigned short* xw, const unsigned short* mbuf,
                         const float* w, float* h){
  int wv=threadIdx.x>>6, lane=threadIdx.x&63;
  int n=blockIdx.x*4+wv;
  int g=lane>>4, l=lane&15, d0=l*8;
  int e0=rp[n], e1=rp[n+1];
  float disn=disb[n];
  float4 aA={0,0,0,0}, aB={0,0,0,0}, cA={0,0,0,0}, cB={0,0,0,0};
  int p=e0+g;
  for(; p+4<e1; p+=8){
    int s0=se[p].x, s1=se[p+4].x;
    float nw0=disb[s0], nw1=disb[s1];
    float4 xa0,xb0,xa1,xb1;
    bf8ld(&xw[(long)s0*128+d0], xa0, xb0);
    bf8ld(&xw[(long)s1*128+d0], xa1, xb1);
    aA.x+=nw0*xa0.x; aA.y+=nw0*xa0.y; aA.z+=nw0*xa0.z; aA.w+=nw0*xa0.w;
    aB.x+=nw0*xb0.x; aB.y+=nw0*xb0.y; aB.z+=nw0*xb0.z; aB.w+=nw0*xb0.w;
    cA.x+=nw1*xa1.x; cA.y+=nw1*xa1.y; cA.z+=nw1*xa1.z; cA.w+=nw1*xa1.w;
    cB.x+=nw1*xb1.x; cB.y+=nw1*xb1.y; cB.z+=nw1*xb1.z; cB.w+=nw1*xb1.w;
  }
  if(p<e1){
    int s0=se[p].x;
    float nw0=disb[s0];
    float4 xa0,xb0;
    bf8ld(&xw[(long)s0*128+d0], xa0, xb0);
    aA.x+=nw0*xa0.x; aA.y+=nw0*xa0.y; aA.z+=nw0*xa0.z; aA.w+=nw0*xa0.w;
    aB.x+=nw0*xb0.x; aB.y+=nw0*xb0.y; aB.z+=nw0*xb0.z; aB.w+=nw0*xb0.w;
  }
  aA.x+=cA.x; aA.y+=cA.y; aA.z+=cA.z; aA.w+=cA.w;
  aB.x+=cB.x; aB.y+=cB.y; aB.z+=cB.z; aB.w+=cB.w;
  #pragma unroll
  for(int m=16;m<64;m<<=1){
    aA.x+=__shfl_xor(aA.x,m,64); aA.y+=__shfl_xor(aA.y,m,64);
    aA.z+=__shfl_xor(aA.z,m,64); aA.w+=__shfl_xor(aA.w,m,64);
    aB.x+=__shfl_xor(aB.x,m,64); aB.y+=__shfl_xor(aB.y,m,64);
    aB.z+=__shfl_xor(aB.z,m,64); aB.w+=__shfl_xor(aB.w,m,64);
  }
  if(g==0){
    float d2=disn*disn;
    float4 xsA,xsB,mA,mB;
    bf8ld(&xw[(long)n*128+d0], xsA, xsB);
    bf8ld(&mbuf[(long)n*128+d0], mA, mB);
    float4 gbA=*(const float4*)&w[OW_BGB+d0];
    float4 gbB=*(const float4*)&w[OW_BGB+d0+4];
    float4 hA=*(float4*)&h[(long)n*128+d0];
    float4 hB=*(float4*)&h[(long)n*128+d0+4];
    hA.x+=fmaxf(aA.x*disn+d2*xsA.x+gbA.x,0.f)+mA.x;
    hA.y+=fmaxf(aA.y*disn+d2*xsA.y+gbA.y,0.f)+mA.y;
    hA.z+=fmaxf(aA.z*disn+d2*xsA.z+gbA.z,0.f)+mA.z;
    hA.w+=fmaxf(aA.w*disn+d2*xsA.w+gbA.w,0.f)+mA.w;
    hB.x+=fmaxf(aB.x*disn+d2*xsB.x+gbB.x,0.f)+mB.x;
    hB.y+=fmaxf(aB.y*disn+d2*xsB.y+gbB.y,0.f)+mB.y;
    hB.z+=fmaxf(aB.z*disn+d2*xsB.z+gbB.z,0.f)+mB.z;
    hB.w+=fmaxf(aB.w*disn+d2*xsB.w+gbB.w,0.f)+mB.w;
    *(float4*)&h[(long)n*128+d0]=hA;
    *(float4*)&h[(long)n*128+d0+4]=hB;
  }
}

__global__ void k_heads(const float* hat_h, const float* h, const float* w,
                        const void* old_chi, const void* old_phi, const void* old_psi,
                        const void* old_cb, const void* old_ca, const int* flag, void* out){
  int wv=threadIdx.x>>6, lane=threadIdx.x&63;
  int n=blockIdx.x*4+wv;
  int f32=*flag;
  float s0=fmaxf(hat_h[(long)n*128+lane],0.f), s1=fmaxf(hat_h[(long)n*128+64+lane],0.f);
  float b0=fmaxf(h[(long)n*128+lane],0.f),    b1=fmaxf(h[(long)n*128+64+lane],0.f);
  float r[8];
  r[0]=s0*w[OW_AW+lane]+s1*w[OW_AW+64+lane];
  r[1]=s0*w[OW_CW+lane*3+0]+s1*w[OW_CW+(64+lane)*3+0];
  r[2]=s0*w[OW_CW+lane*3+1]+s1*w[OW_CW+(64+lane)*3+1];
  r[3]=s0*w[OW_CW+lane*3+2]+s1*w[OW_CW+(64+lane)*3+2];
  r[4]=b0*w[OW_BAW+lane]+b1*w[OW_BAW+64+lane];
  r[5]=b0*w[OW_XW+lane*3+0]+b1*w[OW_XW+(64+lane)*3+0];
  r[6]=b0*w[OW_XW+lane*3+1]+b1*w[OW_XW+(64+lane)*3+1];
  r[7]=b0*w[OW_XW+lane*3+2]+b1*w[OW_XW+(64+lane)*3+2];
  for(int m=1;m<64;m<<=1){
    #pragma unroll
    for(int t=0;t<8;t++) r[t]+=__shfl_xor(r[t],m,64);
  }
  if(lane==0){
    float dchi=r[0]+w[OW_AB];
    for(int k=0;k<4;k++)
      stout(out,(long)k*N_+n, wrapf(ldin(old_chi,(long)k*N_+n,f32)+dchi), f32);
    float dphi=r[4]+w[OW_BAB];
    stout(out,(long)4*N_+n, wrapf(ldin(old_phi,n,f32)+dphi), f32);
    stout(out,(long)5*N_+n, wrapf(ldin(old_psi,n,f32)+dphi), f32);
    for(int t=0;t<3;t++){
      stout(out,(long)6*N_+(long)n*3+t, ldin(old_cb,(long)n*3+t,f32)+r[1+t]+w[OW_CB+t], f32);
      stout(out,(long)9*N_+(long)n*3+t, ldin(old_ca,(long)n*3+t,f32)+r[5+t]+w[OW_XB+t], f32);
    }
  }
}

// ---------- host ----------
extern "C" void kernel_launch(void* const* d_in, const int* in_sizes, int n_in,
                              void* d_out, int out_size, void* d_ws, size_t ws_size,
                              hipStream_t stream) {
  (void)in_sizes; (void)n_in; (void)out_size; (void)ws_size;

  char* p=(char*)d_ws;
  auto alloc=[&](size_t bytes)->void*{ void* r=(void*)p; p+=((bytes+255)&~(size_t)255); return r; };
  int*   flag   =(int*)  alloc(16);
  float* warena =(float*)alloc((size_t)OW_TOT*4);
  float* dv     =(float*)alloc(1024*4);
  float* dvf    =(float*)alloc(1024*4);
  float* P      =(float*)alloc((size_t)441*128*4);
  float* sp     =(float*)alloc(441*4);
  float* qp     =(float*)alloc(441*4);
  float* hat_h  =(float*)alloc((size_t)N_*128*4);
  float* hbuf   =(float*)alloc((size_t)N_*128*4);
  float* bufX   =(float*)alloc((size_t)N_*128*4);
  unsigned short* bufXb=(unsigned short*)alloc((size_t)N_*128*2);
  unsigned short* bufMb=(unsigned short*)alloc((size_t)N_*128*2);
  float* xn_sc  =(float*)alloc((size_t)N_*32*4);
  float* xn_bb  =(float*)alloc((size_t)N_*64*4);
  float* we     =(float*)alloc((size_t)ESC*4);
  float* we_csr =(float*)alloc((size_t)ESC*4);
  float* wn     =(float*)alloc((size_t)ESC*4);
  float* an     =(float*)alloc((size_t)N_*4);
  float* bn     =(float*)alloc((size_t)N_*4);
  float* dis    =(float*)alloc((size_t)N_*4);
  float* disb   =(float*)alloc((size_t)N_*4);
  int* rp_sc    =(int*)  alloc((size_t)(N_+1)*4);
  int* rp_bb    =(int*)  alloc((size_t)(N_+1)*4);
  int*  key1_sc =(int*)  alloc((size_t)ESC*4);
  int2* pay1_sc =(int2*) alloc((size_t)ESC*8);
  int*  dstS_sc =(int*)  alloc((size_t)ESC*4);
  int2* csr_se_sc=(int2*)alloc((size_t)ESC*8);
  int*  key1_bb =(int*)  alloc((size_t)EBB*4);
  int2* pay1_bb =(int2*) alloc((size_t)EBB*8);
  int*  dstS_bb =(int*)  alloc((size_t)EBB*4);
  int2* csr_se_bb=(int2*)alloc((size_t)EBB*8);
  int*  hist    =(int*)  alloc((size_t)(RBS+RBB)*256*4);
  int*  tot     =(int*)  alloc(512*4);
  int*  dbase   =(int*)  alloc(512*4);
  unsigned short* wfg_hi =(unsigned short*)alloc(2048*8*2);
  unsigned short* wfg_lo =(unsigned short*)alloc(2048*8*2);
  unsigned short* wfbg_hi=(unsigned short*)alloc(2048*8*2);
  unsigned short* wfi2_hi=(unsigned short*)alloc(2048*8*2);
  unsigned short* wfi1_hi=(unsigned short*)alloc(4096*8*2);
  unsigned short* wfsc_hi=(unsigned short*)alloc(512*8*2);
  unsigned short* wfsc_lo=(unsigned short*)alloc(512*8*2);
  unsigned short* wfbb_hi=(unsigned short*)alloc(1024*8*2);
  unsigned short* wfbb_lo=(unsigned short*)alloc(1024*8*2);

  const int* src_sc=(const int*)d_in[48];
  const int* dst_sc=src_sc+ESC;
  const int* src_bb=(const int*)d_in[49];
  const int* dst_bb=src_bb+EBB;

  k_detect<<<1,1,0,stream>>>(d_in[0], flag);

  CvtArgs ca;
  {
    int map[29]={14,15,16,17,18,19,20,21,22,23,24,25,30,31,32,33,34,35,36,37,
                 38,39,40,41,42,43,44,45,13};
    for(int i=0;i<29;i++) ca.src[i]=d_in[map[i]];
  }
  k_cvtw<<<(OW_TOT+255)/256,256,0,stream>>>(ca, flag, warena);

  // mega prep: wprep | prevec | preP | LN
  k_prep<<<PB_LN,256,0,stream>>>(warena, flag,
      wfg_hi,wfg_lo, wfbg_hi, wfi2_hi, wfi1_hi,
      wfsc_hi,wfsc_lo, wfbb_hi,wfbb_lo,
      d_in[26], d_in[27], d_in[28], d_in[29], dv, dvf, P, sp, qp,
      d_in[0], d_in[1], d_in[2], d_in[3], d_in[4], d_in[5], xn_sc, xn_bb);

  // stable radix CSR build (parallel scan)
  k_rhist<<<RBS+RBB,256,0,stream>>>(dst_sc, dst_bb, 0, hist);
  k_rscanA<<<512,256,0,stream>>>(hist, tot);
  k_rscanB<<<1,256,0,stream>>>(tot, dbase);
  k_rscat<<<RBS+RBB,256,0,stream>>>(0, 1, dst_sc, src_sc, (const int2*)nullptr,
                                    dst_bb, src_bb, (const int2*)nullptr, hist, dbase,
                                    key1_sc, pay1_sc, key1_bb, pay1_bb);
  k_rhist<<<RBS+RBB,256,0,stream>>>(key1_sc, key1_bb, 8, hist);
  k_rscanA<<<512,256,0,stream>>>(hist, tot);
  k_rscanB<<<1,256,0,stream>>>(tot, dbase);
  k_rscat<<<RBS+RBB,256,0,stream>>>(8, 0, key1_sc, (const int*)nullptr, pay1_sc,
                                    key1_bb, (const int*)nullptr, pay1_bb, hist, dbase,
                                    dstS_sc, csr_se_sc, dstS_bb, csr_se_bb);
  k_bounds<<<(int)(((long)ESC+1+EBB+1+255)/256),256,0,stream>>>(dstS_sc, dstS_bb, rp_sc, rp_bb);
  k_degb<<<(N_+255)/256,256,0,stream>>>(rp_bb, disb);

  // featurizer GEMMs (merged)
  const int GB = (N_+63)/64;
  k_mfeat<<<2*GB,256,0,stream>>>(xn_sc, xn_bb, wfsc_hi, wfsc_lo, wfbb_hi, wfbb_lo,
                                 warena, hat_h, hbuf, N_);

  // edge MLP (16-lane groups, 4 edges/group, coalesced P)
  k_w0<<<WBG,256,0,stream>>>(d_in[6],d_in[7],(const int*)d_in[46],(const int*)d_in[47],
                             flag,dvf,P,sp,qp,we);

  // sidechain layers (GEMM || degree merged)
  const int DB = (N_+255)/256;
  const int NB = (ESC+255)/256;
  for(int l=0;l<3;l++){
    k_gemmdeg<<<GB+DB,256,0,stream>>>(hat_h, wfg_hi, wfg_lo, bufX, N_,
                                      rp_sc, csr_se_sc, we, an, bn, dv, we_csr, dis, l);
    k_norm<<<NB,256,0,stream>>>(csr_se_sc, we_csr, dis, wn);
    k_agg_sc<<<N_/4,256,0,stream>>>(rp_sc,csr_se_sc,wn,dis,bufX,warena,hat_h,dv,an,bn,(l<2)?1:0);
  }

  // backbone layers (fused GEMM trio + agg, bf16 path)
  for(int l=0;l<2;l++){
    k_mbb<<<GB,256,0,stream>>>(hbuf, hat_h, wfi1_hi, wfbg_hi, wfi2_hi,
                               warena+OW_IB1, warena+OW_IB2, bufXb, bufMb, N_);
    k_agg_bb<<<N_/4,256,0,stream>>>(rp_bb,csr_se_bb,disb,bufXb,bufMb,warena,hbuf);
  }

  k_heads<<<N_/4,256,0,stream>>>(hat_h,hbuf,warena,
                                 d_in[8],d_in[9],d_in[10],d_in[11],d_in[12],flag,d_out);
}

// Round 17
// 558.993 us; speedup vs baseline: 1.2372x; 1.0079x over previous
//
#include <hip/hip_runtime.h>
#include <stdint.h>

#define DEVI __device__ __forceinline__

constexpr int N_   = 50000;
constexpr int ESC  = 600000;
constexpr int EBB  = 100000;
constexpr int NRES = 21;
constexpr float PI_F = 3.14159f;

// radix geometry
constexpr int RCH = 2048;
constexpr int RBS = (ESC + RCH - 1)/RCH;  // 293
constexpr int RBB = (EBB + RCH - 1)/RCH;  // 49

typedef __attribute__((ext_vector_type(8))) short short8v;
typedef __attribute__((ext_vector_type(4))) float f32x4;

// ---------- dtype helpers ----------
DEVI float bf2f(unsigned short u){ return __uint_as_float(((unsigned)u)<<16); }
DEVI unsigned short f2bf(float f){
  unsigned x = __float_as_uint(f);
  unsigned r = (x + 0x7FFFu + ((x>>16)&1u))>>16;
  return (unsigned short)r;
}
DEVI float ldin(const void* p, long i, int f32){
  return f32 ? ((const float*)p)[i] : bf2f(((const unsigned short*)p)[i]);
}
DEVI void stout(void* p, long i, float v, int f32){
  if(f32) ((float*)p)[i]=v; else ((unsigned short*)p)[i]=f2bf(v);
}
DEVI float wrapf(float a){
  float t = a + PI_F;
  const float TP = 2.f*PI_F;
  t -= floorf(t/TP)*TP;
  return t - PI_F;
}

// ---------- weight arena offsets ----------
constexpr int OW_SC_LN_G=0;
constexpr int OW_SC_LN_B=OW_SC_LN_G+19;
constexpr int OW_SC_W  = OW_SC_LN_B+19;
constexpr int OW_SC_B  = OW_SC_W+19*128;
constexpr int OW_BB_LN_G=OW_SC_B+128;
constexpr int OW_BB_LN_B=OW_BB_LN_G+38;
constexpr int OW_BB_W = OW_BB_LN_B+38;
constexpr int OW_BB_B = OW_BB_W+38*128;
constexpr int OW_E_LN_G=OW_BB_B+128;
constexpr int OW_E_LN_B=OW_E_LN_G+66;
constexpr int OW_EW1 = OW_E_LN_B+66;
constexpr int OW_EB1 = OW_EW1+66*128;
constexpr int OW_GW  = OW_EB1+128;
constexpr int OW_GB  = OW_GW+128*128;
constexpr int OW_BGW = OW_GB+128;
constexpr int OW_BGB = OW_BGW+128*128;
constexpr int OW_IW1 = OW_BGB+128;
constexpr int OW_IB1 = OW_IW1+256*128;
constexpr int OW_IW2 = OW_IB1+128;
constexpr int OW_IB2 = OW_IW2+128*128;
constexpr int OW_AW  = OW_IB2+128;
constexpr int OW_AB  = OW_AW+128;
constexpr int OW_BAW = OW_AB+1;
constexpr int OW_BAB = OW_BAW+128;
constexpr int OW_CW  = OW_BAB+1;
constexpr int OW_CB  = OW_CW+128*3;
constexpr int OW_XW  = OW_CB+3;
constexpr int OW_XB  = OW_XW+128*3;
constexpr int OW_RES = OW_XB+3;
constexpr int OW_TOT = OW_RES+21*32;

// ---------- basic kernels ----------
__global__ void k_detect(const void* vcom, int* flag){
  const unsigned short* u = (const unsigned short*)vcom;
  int insane=0;
  for(int i=0;i<64;i+=2){
    float f = bf2f(u[i]);
    float a = fabsf(f);
    if(!(a<1e5f) || (a!=0.0f && a<1e-5f)) insane++;
  }
  *flag = (insane>=8)?1:0;
}

struct CvtArgs { const void* src[29]; };

__global__ void k_cvtw(CvtArgs a, const int* flag, float* w){
  static constexpr int offs[30] = {
    OW_SC_LN_G,OW_SC_LN_B,OW_SC_W,OW_SC_B,OW_BB_LN_G,OW_BB_LN_B,OW_BB_W,OW_BB_B,
    OW_E_LN_G,OW_E_LN_B,OW_EW1,OW_EB1,OW_GW,OW_GB,OW_BGW,OW_BGB,OW_IW1,OW_IB1,
    OW_IW2,OW_IB2,OW_AW,OW_AB,OW_BAW,OW_BAB,OW_CW,OW_CB,OW_XW,OW_XB,OW_RES,OW_TOT};
  int f32=*flag;
  for(int t=blockIdx.x*blockDim.x+threadIdx.x; t<OW_TOT; t+=gridDim.x*blockDim.x){
    int s=0;
    while(t>=offs[s+1]) s++;
    w[t]=ldin(a.src[s], t-offs[s], f32);
  }
}

// W[K x 128] -> MFMA fragment order (zero-padded past Kreal), split hi/lo bf16.
DEVI void wprep_pad(const float* W, int Kreal, unsigned short* hi, unsigned short* lo, int idx){
  int lane=idx&63, nt=(idx>>6)&7, kt=idx>>9;
  int n = nt*16 + (lane&15);
  int kbase = kt*32 + (lane>>4)*8;
  #pragma unroll
  for(int i=0;i<8;i++){
    int k=kbase+i;
    float v = (k<Kreal) ? W[(long)k*128 + n] : 0.f;
    unsigned short h = f2bf(v);
    hi[(long)idx*8+i]=h;
    if(lo){ float r = v - bf2f(h); lo[(long)idx*8+i]=f2bf(r); }
  }
}

// ---------- mega prep kernel: wprep | prevec | preP | LN ----------
constexpr int PB_WP = 46;
constexpr int PB_PV = PB_WP+1;
constexpr int PB_PP = PB_PV+441;
constexpr int PB_LN = PB_PP + (2*N_+3)/4;

__global__ void k_prep(const float* w, const int* flag,
    unsigned short* g_hi, unsigned short* g_lo,
    unsigned short* bg_hi,
    unsigned short* i2_hi,
    unsigned short* i1_hi,
    unsigned short* sc_hi, unsigned short* sc_lo,
    unsigned short* bb_hi, unsigned short* bb_lo,
    const void* eW2, const void* eb2, const void* euW, const void* eub,
    float* dv, float* dvf, float* P, float* sp, float* qp,
    const void* vcom, const void* sbfchi,
    const void* xca, const void* vcb, const void* sphi, const void* spsi,
    float* xn_sc, float* xn_bb){
  __shared__ float pv[64];
  int b=blockIdx.x;
  if(b<PB_WP){
    int idx=b*256+threadIdx.x;
    if(idx<2048)       wprep_pad(w+OW_GW,  128, g_hi,  g_lo,  idx);
    else if(idx<4096)  wprep_pad(w+OW_BGW, 128, bg_hi, nullptr, idx-2048);
    else if(idx<6144)  wprep_pad(w+OW_IW2, 128, i2_hi, nullptr, idx-4096);
    else if(idx<10240) wprep_pad(w+OW_IW1, 256, i1_hi, nullptr, idx-6144);
    else if(idx<10752) wprep_pad(w+OW_SC_W, 19, sc_hi, sc_lo, idx-10240);
    else if(idx<11776) wprep_pad(w+OW_BB_W, 38, bb_hi, bb_lo, idx-10752);
  } else if(b<PB_PV){
    int j=threadIdx.x; int f32=*flag;
    if(j<128){
      const float* g=w+OW_E_LN_G; const float* bb=w+OW_E_LN_B; const float* W1=w+OW_EW1;
      float A=g[0]*W1[j], C=g[1]*W1[128+j];
      float G=0,B=0;
      for(int i=0;i<66;i++){ float wij=W1[i*128+j]; G+=g[i]*wij; B+=bb[i]*wij; }
      B += w[OW_EB1+j];
      float v2=0; for(int k=0;k<128;k++) v2+=ldin(eW2,(long)j*128+k,f32);
      float us=0,ud=0;
      for(int k=0;k<128;k++){ us+=ldin(euW,(long)j*128+k,f32); ud+=ldin(euW,(long)(128+j)*128+k,f32); }
      dv[640+j]=us*(1.f/128.f); dv[768+j]=ud*(1.f/128.f);
      dvf[j]=A; dvf[128+j]=C; dvf[256+j]=G; dvf[384+j]=B; dvf[512+j]=v2*(1.f/128.f);
      if(j==0){
        float s=0,t=0;
        for(int k=0;k<128;k++){ s+=ldin(eb2,k,f32); t+=ldin(eub,k,f32); }
        dv[896]=s*(1.f/128.f); dv[897]=t*(1.f/128.f);
        dvf[640]=s*(1.f/128.f);
      }
    }
  } else if(b<PB_PP){
    int c=b-PB_PV, j=threadIdx.x;
    const float* res=w+OW_RES;
    if(j<32) pv[j]=res[(c/NRES)*32+j];
    else if(j<64) pv[j]=res[(c%NRES)*32+(j-32)];
    __syncthreads();
    if(j<128){
      const float* g=w+OW_E_LN_G; const float* W1=w+OW_EW1;
      float s=0;
      for(int i=0;i<64;i++) s += pv[i]*g[2+i]*W1[(2+i)*128+j];
      P[c*128+j]=s;
      if(j==0){ float a=0,q=0; for(int i=0;i<64;i++){a+=pv[i]; q+=pv[i]*pv[i];} sp[c]=a; qp[c]=q; }
    }
  } else {
    int wv=threadIdx.x>>6, lane=threadIdx.x&63;
    long gw=(long)(b-PB_PP)*4+wv;
    int f32=*flag;
    if(gw<N_){
      int n=(int)gw;
      float x=0.f;
      if(lane<3) x=ldin(vcom,(long)n*3+lane,f32);
      else if(lane<19) x=ldin(sbfchi,(long)n*16+(lane-3),f32);
      float s=x, q=x*x;
      for(int m=1;m<64;m<<=1){ s+=__shfl_xor(s,m,64); q+=__shfl_xor(q,m,64); }
      float mean=s*(1.f/19.f);
      float istd=rsqrtf(fmaxf(q*(1.f/19.f)-mean*mean,0.f)+1e-5f);
      if(lane<32){
        float xn=(lane<19)? (x-mean)*istd*w[OW_SC_LN_G+lane]+w[OW_SC_LN_B+lane] : 0.f;
        xn_sc[(long)n*32+lane]=xn;
      }
    } else if(gw<2L*N_){
      int n=(int)(gw-N_);
      float x=0.f;
      if(lane<3) x=ldin(xca,(long)n*3+lane,f32);
      else if(lane<6) x=ldin(vcb,(long)n*3+(lane-3),f32);
      else if(lane<22) x=ldin(sphi,(long)n*16+(lane-6),f32);
      else if(lane<38) x=ldin(spsi,(long)n*16+(lane-22),f32);
      float s=x, q=x*x;
      for(int m=1;m<64;m<<=1){ s+=__shfl_xor(s,m,64); q+=__shfl_xor(q,m,64); }
      float mean=s*(1.f/38.f);
      float istd=rsqrtf(fmaxf(q*(1.f/38.f)-mean*mean,0.f)+1e-5f);
      float xn=(lane<38)? (x-mean)*istd*w[OW_BB_LN_G+lane]+w[OW_BB_LN_B+lane] : 0.f;
      xn_bb[(long)n*64+lane]=xn;
    }
  }
}

// ---------- stable 2-pass radix CSR build (RCH=2048, parallel scan) ----------
__global__ void k_rhist(const int* key_sc, const int* key_bb, int shift, int* hist){
  __shared__ int h[256];
  h[threadIdx.x]=0; __syncthreads();
  int g = blockIdx.x>=RBS;
  const int* key = g? key_bb : key_sc;
  int E = g? EBB : ESC;
  int b = g? blockIdx.x-RBS : blockIdx.x;
  int base=b*RCH;
  for(int r=0;r<RCH/256;r++){
    int idx=base+r*256+threadIdx.x;
    if(idx<E) atomicAdd(&h[(key[idx]>>shift)&255],1);
  }
  __syncthreads();
  hist[(long)blockIdx.x*256+threadIdx.x]=h[threadIdx.x];
}
__global__ void k_rscanA(int* hist, int* tot){
  __shared__ int sA[512], sB[512];
  int g = blockIdx.x>=256;
  int d = blockIdx.x&255;
  int NB = g? RBB : RBS;
  int* H = hist + (g? (long)RBS*256 : 0);
  int t=threadIdx.x;
  int i0=t, i1=t+256;
  int o0 = (i0<NB)? H[(long)i0*256+d] : 0;
  int o1 = (i1<NB)? H[(long)i1*256+d] : 0;
  sA[i0]=o0; sA[i1]=o1;
  __syncthreads();
  int* a=sA; int* b=sB;
  for(int off=1; off<512; off<<=1){
    b[i0] = a[i0] + ((i0>=off)? a[i0-off]:0);
    b[i1] = a[i1] + ((i1>=off)? a[i1-off]:0);
    __syncthreads();
    int* tmp=a; a=b; b=tmp;
  }
  if(i0<NB) H[(long)i0*256+d] = a[i0]-o0;
  if(i1<NB) H[(long)i1*256+d] = a[i1]-o1;
  if(t==255) tot[(g?256:0)+d] = a[511];
}
__global__ void k_rscanB(const int* tot, int* base){
  __shared__ int sA[256], sB[256];
  int t=threadIdx.x;
  for(int g=0;g<2;g++){
    int o=tot[g*256+t];
    sA[t]=o; __syncthreads();
    int* a=sA; int* b=sB;
    for(int off=1; off<256; off<<=1){
      b[t] = a[t] + ((t>=off)? a[t-off]:0);
      __syncthreads();
      int* tmp=a; a=b; b=tmp;
    }
    base[g*256+t] = a[t]-o;
    __syncthreads();
  }
}
__global__ void k_rscat(int shift, int first,
    const int* kin_sc, const int* srcv_sc, const int2* pin_sc,
    const int* kin_bb, const int* srcv_bb, const int2* pin_bb,
    const int* hist, const int* dbase,
    int* kout_sc, int2* pout_sc, int* kout_bb, int2* pout_bb){
  __shared__ int running[256];
  __shared__ int Hb[256];
  __shared__ int whist[4][256];
  __shared__ int pw[4][256];
  int tid=threadIdx.x, lane=tid&63, w=tid>>6;
  int g = blockIdx.x>=RBS;
  const int* kin  = g? kin_bb : kin_sc;
  const int* srcv = g? srcv_bb: srcv_sc;
  const int2* pin = g? pin_bb : pin_sc;
  int* kout  = g? kout_bb : kout_sc;
  int2* pout = g? pout_bb : pout_sc;
  int E = g? EBB : ESC;
  int b = g? blockIdx.x-RBS : blockIdx.x;
  running[tid]=0;
  Hb[tid]=hist[(long)blockIdx.x*256+tid] + dbase[(g?256:0)+tid];
  int base=b*RCH;
  for(int r=0;r<RCH/256;r++){
    __syncthreads();
    whist[0][tid]=0; whist[1][tid]=0; whist[2][tid]=0; whist[3][tid]=0;
    __syncthreads();
    int idx=base+r*256+tid;
    bool valid = idx<E;
    int key=0, digit=0; int2 pay; pay.x=0; pay.y=0;
    if(valid){
      key=kin[idx];
      digit=(key>>shift)&255;
      if(first){ pay.x=srcv[idx]; pay.y=idx; }
      else pay=pin[idx];
    }
    unsigned long long act=__ballot(valid);
    unsigned long long same=act;
    #pragma unroll
    for(int k=0;k<8;k++){
      unsigned long long m=__ballot(valid && ((digit>>k)&1));
      same &= ((digit>>k)&1)? m : ~m;
    }
    same &= act;
    unsigned long long below=(1ULL<<lane)-1ULL;
    int wrank=__popcll(same & below);
    if(valid && wrank==0) whist[w][digit]=__popcll(same);
    __syncthreads();
    int c0=whist[0][tid], c1=whist[1][tid], c2=whist[2][tid], c3=whist[3][tid];
    pw[0][tid]=0; pw[1][tid]=c0; pw[2][tid]=c0+c1; pw[3][tid]=c0+c1+c2;
    __syncthreads();
    if(valid){
      int pos=Hb[digit]+running[digit]+pw[w][digit]+wrank;
      kout[pos]=key; pout[pos]=pay;
    }
    __syncthreads();
    running[tid]+=c0+c1+c2+c3;
  }
}
__global__ void k_bounds(const int* dstS_sc, const int* dstS_bb, int* rp_sc, int* rp_bb){
  long i=(long)blockIdx.x*blockDim.x+threadIdx.x;
  if(i<=ESC){
    int cur = (i<ESC)? dstS_sc[i] : N_;
    int prev= (i>0)? dstS_sc[i-1] : -1;
    for(int d=prev+1; d<=cur; d++) rp_sc[d]=(int)i;
  } else if(i <= (long)ESC+1+EBB){
    long j=i-(ESC+1);
    int cur = (j<EBB)? dstS_bb[j] : N_;
    int prev= (j>0)? dstS_bb[j-1] : -1;
    for(int d=prev+1; d<=cur; d++) rp_bb[d]=(int)j;
  }
}
__global__ void k_degb(const int* rp, float* disb){
  int n=blockIdx.x*blockDim.x+threadIdx.x;
  if(n<N_) disb[n]=rsqrtf(1.f+(float)(rp[n+1]-rp[n]));
}

// ---------- edge MLP: 16-lane groups, 4 edges/group, dvf cached in registers ----------
constexpr int WBG = (ESC + 63)/64;  // 9375
__global__ __launch_bounds__(256,4) void k_w0(const void* dsc, const void* dmin,
    const int* ri_, const int* rj_, const int* flag, const float* dvf,
    const float* P, const float* sp, const float* qp, float* we){
  int wv=threadIdx.x>>6, lane=threadIdx.x&63;
  int g=lane>>4, l=lane&15;
  long ebase=(long)blockIdx.x*64 + wv*16 + g*4;
  int f32=*flag;
  int j0=l*8;
  float4 A0=*(const float4*)&dvf[j0],     A1=*(const float4*)&dvf[j0+4];
  float4 C0=*(const float4*)&dvf[128+j0], C1=*(const float4*)&dvf[128+j0+4];
  float4 G0=*(const float4*)&dvf[256+j0], G1=*(const float4*)&dvf[256+j0+4];
  float4 B0=*(const float4*)&dvf[384+j0], B1=*(const float4*)&dvf[384+j0+4];
  float4 V0=*(const float4*)&dvf[512+j0], V1=*(const float4*)&dvf[512+j0+4];
  float eb2=dvf[640];
  #pragma unroll
  for(int k=0;k<4;k++){
    long e=ebase+k;
    bool val = e<ESC;
    long ee = val? e : 0;
    float d1=ldin(dsc,ee,f32), d2=ldin(dmin,ee,f32);
    int c=ri_[ee]*NRES+rj_[ee];
    float m=(d1+d2+sp[c])*(1.f/66.f);
    float ms=(d1*d1+d2*d2+qp[c])*(1.f/66.f);
    float istd=rsqrtf(fmaxf(ms-m*m,0.f)+1e-5f);
    float nmi=-m*istd;
    float4 P0=*(const float4*)&P[(long)c*128+j0];
    float4 P1=*(const float4*)&P[(long)c*128+j0+4];
    float acc=0.f, t, hid;
    t=fmaf(d1,A0.x,fmaf(d2,C0.x,P0.x)); hid=fmaf(istd,t,fmaf(nmi,G0.x,B0.x)); acc=fmaf(fmaxf(hid,0.f),V0.x,acc);
    t=fmaf(d1,A0.y,fmaf(d2,C0.y,P0.y)); hid=fmaf(istd,t,fmaf(nmi,G0.y,B0.y)); acc=fmaf(fmaxf(hid,0.f),V0.y,acc);
    t=fmaf(d1,A0.z,fmaf(d2,C0.z,P0.z)); hid=fmaf(istd,t,fmaf(nmi,G0.z,B0.z)); acc=fmaf(fmaxf(hid,0.f),V0.z,acc);
    t=fmaf(d1,A0.w,fmaf(d2,C0.w,P0.w)); hid=fmaf(istd,t,fmaf(nmi,G0.w,B0.w)); acc=fmaf(fmaxf(hid,0.f),V0.w,acc);
    t=fmaf(d1,A1.x,fmaf(d2,C1.x,P1.x)); hid=fmaf(istd,t,fmaf(nmi,G1.x,B1.x)); acc=fmaf(fmaxf(hid,0.f),V1.x,acc);
    t=fmaf(d1,A1.y,fmaf(d2,C1.y,P1.y)); hid=fmaf(istd,t,fmaf(nmi,G1.y,B1.y)); acc=fmaf(fmaxf(hid,0.f),V1.y,acc);
    t=fmaf(d1,A1.z,fmaf(d2,C1.z,P1.z)); hid=fmaf(istd,t,fmaf(nmi,G1.z,B1.z)); acc=fmaf(fmaxf(hid,0.f),V1.z,acc);
    t=fmaf(d1,A1.w,fmaf(d2,C1.w,P1.w)); hid=fmaf(istd,t,fmaf(nmi,G1.w,B1.w)); acc=fmaf(fmaxf(hid,0.f),V1.w,acc);
    #pragma unroll
    for(int msk=1;msk<16;msk<<=1) acc+=__shfl_xor(acc,msk,64);
    if(l==0 && val) we[e]=acc+eb2;
  }
}

// ---------- split-bf16 MFMA GEMM core ----------
DEVI f32x4 MFMA(short8v a, short8v b, f32x4 c){
  return __builtin_amdgcn_mfma_f32_16x16x32_bf16(a,b,c,0,0,0);
}
DEVI void cvt8(float4 a0, float4 a1, short8v& hi, short8v& lo){
  float av[8]={a0.x,a0.y,a0.z,a0.w,a1.x,a1.y,a1.z,a1.w};
  union{short8v v; unsigned short u[8];} H,L;
  #pragma unroll
  for(int i=0;i<8;i++){
    unsigned short h=f2bf(av[i]);
    float r=av[i]-bf2f(h);
    H.u[i]=h; L.u[i]=f2bf(r);
  }
  hi=H.v; lo=L.v;
}
DEVI short8v cvt8hi(float4 a0, float4 a1){
  union{short8v v; unsigned short u[8];} H;
  H.u[0]=f2bf(a0.x); H.u[1]=f2bf(a0.y); H.u[2]=f2bf(a0.z); H.u[3]=f2bf(a0.w);
  H.u[4]=f2bf(a1.x); H.u[5]=f2bf(a1.y); H.u[6]=f2bf(a1.z); H.u[7]=f2bf(a1.w);
  return H.v;
}

template<int KT, int LDA>
DEVI void mgemm_body(int bid, const float* A1, const float* A2,
    const unsigned short* Whi, const unsigned short* Wlo,
    const float* bias, float* C, int relu, int accum, int M){
  const int lane = threadIdx.x & 63;
  const int wid  = threadIdx.x >> 6;
  const int r0   = bid*64 + wid*16;
  const int mrow = lane & 15;
  const int kg   = lane >> 4;
  long arow = (long)min(r0 + mrow, M-1);
  f32x4 acc[8];
  #pragma unroll
  for(int t=0;t<8;t++) acc[t]=(f32x4){0.f,0.f,0.f,0.f};

  #pragma unroll
  for(int kt=0; kt<KT; kt++){
    const float* A = (KT==8 && kt>=4) ? A2 : A1;
    int kb = (kt&3)*32 + kg*8;
    float4 a0 = *(const float4*)&A[arow*LDA + kb];
    float4 a1 = *(const float4*)&A[arow*LDA + kb + 4];
    short8v ah, al; cvt8(a0,a1,ah,al);
    #pragma unroll
    for(int nt=0;nt<8;nt++){
      long off = (((long)kt*8+nt)*64 + lane)*8;
      short8v wh = *(const short8v*)&Whi[off];
      short8v wl = *(const short8v*)&Wlo[off];
      acc[nt] = MFMA(ah, wh, acc[nt]);
      acc[nt] = MFMA(al, wh, acc[nt]);
      acc[nt] = MFMA(ah, wl, acc[nt]);
      acc[nt] = MFMA(al, wl, acc[nt]);
    }
  }

  #pragma unroll
  for(int nt=0;nt<8;nt++){
    int col = nt*16 + mrow;
    float bj = bias ? bias[col] : 0.f;
    #pragma unroll
    for(int r=0;r<4;r++){
      int row = r0 + kg*4 + r;
      if(row >= M) continue;
      long idx = (long)row*128 + col;
      float v = acc[nt][r] + bj;
      if(relu) v = fmaxf(v,0.f);
      if(accum) v += C[idx];
      C[idx] = v;
    }
  }
}

// sc layer: gW GEMM overlapped with degree pass
__global__ __launch_bounds__(256,4) void k_gemmdeg(const float* hat_h,
    const unsigned short* Whi, const unsigned short* Wlo, float* C, int M,
    const int* rp, const int2* se, const float* we_edge,
    const float* an, const float* bn, const float* dv,
    float* we_csr, float* dis, int layer){
  int GBl=(M+63)/64;
  if((int)blockIdx.x < GBl){
    mgemm_body<4,128>(blockIdx.x, hat_h, nullptr, Whi, Wlo, nullptr, C, 0, 0, M);
  } else {
    int n=(blockIdx.x-GBl)*256+threadIdx.x;
    if(n>=N_) return;
    int e0=rp[n], e1=rp[n+1];
    float s=1.f;
    if(layer==0){
      for(int p=e0;p<e1;p++){ float ww=we_edge[se[p].y]; we_csr[p]=ww; s+=ww; }
    } else {
      float add_n = bn[n] + dv[897];
      for(int p=e0;p<e1;p++){
        float ww=we_csr[p] + an[se[p].x] + add_n;
        we_csr[p]=ww; s+=ww;
      }
    }
    dis[n]=rsqrtf(fmaxf(s,1e-6f));
  }
}

// featurizer: both small GEMMs in one launch
__global__ __launch_bounds__(256,4) void k_mfeat(const float* xn_sc, const float* xn_bb,
    const unsigned short* schi, const unsigned short* sclo,
    const unsigned short* bbhi, const unsigned short* bblo,
    const float* w, float* hat_h, float* hbuf, int M){
  int GBl=(M+63)/64;
  if((int)blockIdx.x < GBl)
    mgemm_body<1,32>(blockIdx.x, xn_sc, nullptr, schi, sclo, w+OW_SC_B, hat_h, 0,0,M);
  else
    mgemm_body<2,64>(blockIdx.x-GBl, xn_bb, nullptr, bbhi, bblo, w+OW_BB_B, hbuf, 0,0,M);
}

// fused bb layer (backbone branch is NOT chaotic -> plain bf16 suffices)
__global__ __launch_bounds__(256,4) void k_mbb(const float* h, const float* hh,
    const unsigned short* W1hi,
    const unsigned short* W2hi,
    const unsigned short* W3hi,
    const float* b1, const float* b2,
    unsigned short* xwout, unsigned short* mout, int M){
  __shared__ unsigned short hids[64*136];
  const int lane = threadIdx.x & 63;
  const int wid  = threadIdx.x >> 6;
  const int r0   = blockIdx.x*64 + wid*16;
  const int mrow = lane & 15;
  const int kg   = lane >> 4;
  long arow = (long)min(r0 + mrow, M-1);
  f32x4 acc1[8], acc2[8];
  #pragma unroll
  for(int t=0;t<8;t++){ acc1[t]=(f32x4){0,0,0,0}; acc2[t]=(f32x4){0,0,0,0}; }

  #pragma unroll
  for(int kt=0; kt<8; kt++){
    const float* A = (kt>=4) ? hh : h;
    int kb = (kt&3)*32 + kg*8;
    float4 a0 = *(const float4*)&A[arow*128 + kb];
    float4 a1 = *(const float4*)&A[arow*128 + kb + 4];
    short8v ah = cvt8hi(a0,a1);
    #pragma unroll
    for(int nt=0;nt<8;nt++){
      long off = (((long)kt*8+nt)*64 + lane)*8;
      acc1[nt] = MFMA(ah, *(const short8v*)&W1hi[off], acc1[nt]);
    }
    if(kt<4){
      #pragma unroll
      for(int nt=0;nt<8;nt++){
        long off = (((long)kt*8+nt)*64 + lane)*8;
        acc2[nt] = MFMA(ah, *(const short8v*)&W2hi[off], acc2[nt]);
      }
    }
  }

  #pragma unroll
  for(int nt=0;nt<8;nt++){
    int col = nt*16 + mrow;
    float bj = b1[col];
    #pragma unroll
    for(int r=0;r<4;r++){
      int rloc = wid*16 + kg*4 + r;
      int row = r0 + kg*4 + r;
      hids[rloc*136 + col] = f2bf(fmaxf(acc1[nt][r] + bj, 0.f));
      if(row < M) xwout[(long)row*128 + col] = f2bf(acc2[nt][r]);
    }
  }
  __syncthreads();

  f32x4 acc3[8];
  #pragma unroll
  for(int t=0;t<8;t++) acc3[t]=(f32x4){0,0,0,0};
  int rloc = wid*16 + mrow;
  #pragma unroll
  for(int kt=0; kt<4; kt++){
    int kb = kt*32 + kg*8;
    short8v ah = *(const short8v*)&hids[rloc*136 + kb];
    #pragma unroll
    for(int nt=0;nt<8;nt++){
      long off = (((long)kt*8+nt)*64 + lane)*8;
      acc3[nt] = MFMA(ah, *(const short8v*)&W3hi[off], acc3[nt]);
    }
  }
  #pragma unroll
  for(int nt=0;nt<8;nt++){
    int col = nt*16 + mrow;
    float bj = b2[col];
    #pragma unroll
    for(int r=0;r<4;r++){
      int row = r0 + kg*4 + r;
      if(row < M) mout[(long)row*128 + col] = f2bf(acc3[nt][r] + bj);
    }
  }
}

// ---------- aggregation: 16 lanes/edge, 2-edge unroll, inline dis[src] ----------
__global__ void k_agg_sc(const int* rp, const int2* se, const float* wc,
                         const float* dis, const float* xw, const float* w,
                         float* hat_h, const float* dv, float* an, float* bn, int withdot){
  int wv=threadIdx.x>>6, lane=threadIdx.x&63;
  int n=blockIdx.x*4+wv;
  int g=lane>>4, l=lane&15, d0=l*8;
  float disn=dis[n];
  float4 aA={0,0,0,0}, aB={0,0,0,0}, cA={0,0,0,0}, cB={0,0,0,0};
  int e0=rp[n], e1=rp[n+1];
  int p=e0+g;
  for(; p+4<e1; p+=8){
    int s0=se[p].x, s1=se[p+4].x;
    float nw0=dis[s0]*wc[p], nw1=dis[s1]*wc[p+4];
    float4 xa0=*(const float4*)&xw[(long)s0*128+d0];
    float4 xb0=*(const float4*)&xw[(long)s0*128+d0+4];
    float4 xa1=*(const float4*)&xw[(long)s1*128+d0];
    float4 xb1=*(const float4*)&xw[(long)s1*128+d0+4];
    aA.x+=nw0*xa0.x; aA.y+=nw0*xa0.y; aA.z+=nw0*xa0.z; aA.w+=nw0*xa0.w;
    aB.x+=nw0*xb0.x; aB.y+=nw0*xb0.y; aB.z+=nw0*xb0.z; aB.w+=nw0*xb0.w;
    cA.x+=nw1*xa1.x; cA.y+=nw1*xa1.y; cA.z+=nw1*xa1.z; cA.w+=nw1*xa1.w;
    cB.x+=nw1*xb1.x; cB.y+=nw1*xb1.y; cB.z+=nw1*xb1.z; cB.w+=nw1*xb1.w;
  }
  if(p<e1){
    int s0=se[p].x;
    float nw0=dis[s0]*wc[p];
    float4 xa0=*(const float4*)&xw[(long)s0*128+d0];
    float4 xb0=*(const float4*)&xw[(long)s0*128+d0+4];
    aA.x+=nw0*xa0.x; aA.y+=nw0*xa0.y; aA.z+=nw0*xa0.z; aA.w+=nw0*xa0.w;
    aB.x+=nw0*xb0.x; aB.y+=nw0*xb0.y; aB.z+=nw0*xb0.z; aB.w+=nw0*xb0.w;
  }
  aA.x+=cA.x; aA.y+=cA.y; aA.z+=cA.z; aA.w+=cA.w;
  aB.x+=cB.x; aB.y+=cB.y; aB.z+=cB.z; aB.w+=cB.w;
  #pragma unroll
  for(int m=16;m<64;m<<=1){
    aA.x+=__shfl_xor(aA.x,m,64); aA.y+=__shfl_xor(aA.y,m,64);
    aA.z+=__shfl_xor(aA.z,m,64); aA.w+=__shfl_xor(aA.w,m,64);
    aB.x+=__shfl_xor(aB.x,m,64); aB.y+=__shfl_xor(aB.y,m,64);
    aB.z+=__shfl_xor(aB.z,m,64); aB.w+=__shfl_xor(aB.w,m,64);
  }
  float d2=disn*disn;
  float4 xsA=*(const float4*)&xw[(long)n*128+d0];
  float4 xsB=*(const float4*)&xw[(long)n*128+d0+4];
  float4 gbA=*(const float4*)&w[OW_GB+d0];
  float4 gbB=*(const float4*)&w[OW_GB+d0+4];
  float4 hoA=*(const float4*)&hat_h[(long)n*128+d0];
  float4 hoB=*(const float4*)&hat_h[(long)n*128+d0+4];
  float4 hA, hB;
  hA.x=hoA.x+fmaxf(aA.x*disn+d2*xsA.x+gbA.x,0.f);
  hA.y=hoA.y+fmaxf(aA.y*disn+d2*xsA.y+gbA.y,0.f);
  hA.z=hoA.z+fmaxf(aA.z*disn+d2*xsA.z+gbA.z,0.f);
  hA.w=hoA.w+fmaxf(aA.w*disn+d2*xsA.w+gbA.w,0.f);
  hB.x=hoB.x+fmaxf(aB.x*disn+d2*xsB.x+gbB.x,0.f);
  hB.y=hoB.y+fmaxf(aB.y*disn+d2*xsB.y+gbB.y,0.f);
  hB.z=hoB.z+fmaxf(aB.z*disn+d2*xsB.z+gbB.z,0.f);
  hB.w=hoB.w+fmaxf(aB.w*disn+d2*xsB.w+gbB.w,0.f);
  if(g==0){
    *(float4*)&hat_h[(long)n*128+d0]=hA;
    *(float4*)&hat_h[(long)n*128+d0+4]=hB;
  }
  if(withdot){
    float4 usA=*(const float4*)&dv[640+d0], usB=*(const float4*)&dv[640+d0+4];
    float4 udA=*(const float4*)&dv[768+d0], udB=*(const float4*)&dv[768+d0+4];
    float a = hA.x*usA.x+hA.y*usA.y+hA.z*usA.z+hA.w*usA.w
            + hB.x*usB.x+hB.y*usB.y+hB.z*usB.z+hB.w*usB.w;
    float b = hA.x*udA.x+hA.y*udA.y+hA.z*udA.z+hA.w*udA.w
            + hB.x*udB.x+hB.y*udB.y+hB.z*udB.z+hB.w*udB.w;
    #pragma unroll
    for(int m=1;m<16;m<<=1){ a+=__shfl_xor(a,m,64); b+=__shfl_xor(b,m,64); }
    if(lane==0){ an[n]=a; bn[n]=b; }
  }
}

DEVI void bf8ld(const unsigned short* p, float4& lo, float4& hi){
  union{short8v v; unsigned short u[8];} t;
  t.v = *(const short8v*)p;
  lo.x=bf2f(t.u[0]); lo.y=bf2f(t.u[1]); lo.z=bf2f(t.u[2]); lo.w=bf2f(t.u[3]);
  hi.x=bf2f(t.u[4]); hi.y=bf2f(t.u[5]); hi.z=bf2f(t.u[6]); hi.w=bf2f(t.u[7]);
}

// bb aggregation + (optional) fused output heads on the last layer
__global__ void k_agg_bb(const int* rp, const int2* se, const float* disb,
                         const unsigned short* xw, const unsigned short* mbuf,
                         const float* w, float* h,
                         const float* hat_h, const void* old_chi, const void* old_phi,
                         const void* old_psi, const void* old_cb, const void* old_ca,
                         const int* flag, void* out, int dohead){
  int wv=threadIdx.x>>6, lane=threadIdx.x&63;
  int n=blockIdx.x*4+wv;
  int g=lane>>4, l=lane&15, d0=l*8;
  int e0=rp[n], e1=rp[n+1];
  float disn=disb[n];
  float4 aA={0,0,0,0}, aB={0,0,0,0}, cA={0,0,0,0}, cB={0,0,0,0};
  int p=e0+g;
  for(; p+4<e1; p+=8){
    int s0=se[p].x, s1=se[p+4].x;
    float nw0=disb[s0], nw1=disb[s1];
    float4 xa0,xb0,xa1,xb1;
    bf8ld(&xw[(long)s0*128+d0], xa0, xb0);
    bf8ld(&xw[(long)s1*128+d0], xa1, xb1);
    aA.x+=nw0*xa0.x; aA.y+=nw0*xa0.y; aA.z+=nw0*xa0.z; aA.w+=nw0*xa0.w;
    aB.x+=nw0*xb0.x; aB.y+=nw0*xb0.y; aB.z+=nw0*xb0.z; aB.w+=nw0*xb0.w;
    cA.x+=nw1*xa1.x; cA.y+=nw1*xa1.y; cA.z+=nw1*xa1.z; cA.w+=nw1*xa1.w;
    cB.x+=nw1*xb1.x; cB.y+=nw1*xb1.y; cB.z+=nw1*xb1.z; cB.w+=nw1*xb1.w;
  }
  if(p<e1){
    int s0=se[p].x;
    float nw0=disb[s0];
    float4 xa0,xb0;
    bf8ld(&xw[(long)s0*128+d0], xa0, xb0);
    aA.x+=nw0*xa0.x; aA.y+=nw0*xa0.y; aA.z+=nw0*xa0.z; aA.w+=nw0*xa0.w;
    aB.x+=nw0*xb0.x; aB.y+=nw0*xb0.y; aB.z+=nw0*xb0.z; aB.w+=nw0*xb0.w;
  }
  aA.x+=cA.x; aA.y+=cA.y; aA.z+=cA.z; aA.w+=cA.w;
  aB.x+=cB.x; aB.y+=cB.y; aB.z+=cB.z; aB.w+=cB.w;
  #pragma unroll
  for(int m=16;m<64;m<<=1){
    aA.x+=__shfl_xor(aA.x,m,64); aA.y+=__shfl_xor(aA.y,m,64);
    aA.z+=__shfl_xor(aA.z,m,64); aA.w+=__shfl_xor(aA.w,m,64);
    aB.x+=__shfl_xor(aB.x,m,64); aB.y+=__shfl_xor(aB.y,m,64);
    aB.z+=__shfl_xor(aB.z,m,64); aB.w+=__shfl_xor(aB.w,m,64);
  }
  if(g==0){
    float d2=disn*disn;
    float4 xsA,xsB,mA,mB;
    bf8ld(&xw[(long)n*128+d0], xsA, xsB);
    bf8ld(&mbuf[(long)n*128+d0], mA, mB);
    float4 gbA=*(const float4*)&w[OW_BGB+d0];
    float4 gbB=*(const float4*)&w[OW_BGB+d0+4];
    float4 hA=*(float4*)&h[(long)n*128+d0];
    float4 hB=*(float4*)&h[(long)n*128+d0+4];
    hA.x+=fmaxf(aA.x*disn+d2*xsA.x+gbA.x,0.f)+mA.x;
    hA.y+=fmaxf(aA.y*disn+d2*xsA.y+gbA.y,0.f)+mA.y;
    hA.z+=fmaxf(aA.z*disn+d2*xsA.z+gbA.z,0.f)+mA.z;
    hA.w+=fmaxf(aA.w*disn+d2*xsA.w+gbA.w,0.f)+mA.w;
    hB.x+=fmaxf(aB.x*disn+d2*xsB.x+gbB.x,0.f)+mB.x;
    hB.y+=fmaxf(aB.y*disn+d2*xsB.y+gbB.y,0.f)+mB.y;
    hB.z+=fmaxf(aB.z*disn+d2*xsB.z+gbB.z,0.f)+mB.z;
    hB.w+=fmaxf(aB.w*disn+d2*xsB.w+gbB.w,0.f)+mB.w;
    *(float4*)&h[(long)n*128+d0]=hA;
    *(float4*)&h[(long)n*128+d0+4]=hB;

    if(dohead){
      int f32=*flag;
      // lanes 0-15 each own dims d0..d0+7 of the full row
      float4 shA=*(const float4*)&hat_h[(long)n*128+d0];
      float4 shB=*(const float4*)&hat_h[(long)n*128+d0+4];
      float sv[8]={fmaxf(shA.x,0.f),fmaxf(shA.y,0.f),fmaxf(shA.z,0.f),fmaxf(shA.w,0.f),
                   fmaxf(shB.x,0.f),fmaxf(shB.y,0.f),fmaxf(shB.z,0.f),fmaxf(shB.w,0.f)};
      float bv[8]={fmaxf(hA.x,0.f),fmaxf(hA.y,0.f),fmaxf(hA.z,0.f),fmaxf(hA.w,0.f),
                   fmaxf(hB.x,0.f),fmaxf(hB.y,0.f),fmaxf(hB.z,0.f),fmaxf(hB.w,0.f)};
      float r[8]={0,0,0,0,0,0,0,0};
      #pragma unroll
      for(int i=0;i<8;i++){
        int col=d0+i;
        r[0]+=sv[i]*w[OW_AW+col];
        r[1]+=sv[i]*w[OW_CW+col*3+0];
        r[2]+=sv[i]*w[OW_CW+col*3+1];
        r[3]+=sv[i]*w[OW_CW+col*3+2];
        r[4]+=bv[i]*w[OW_BAW+col];
        r[5]+=bv[i]*w[OW_XW+col*3+0];
        r[6]+=bv[i]*w[OW_XW+col*3+1];
        r[7]+=bv[i]*w[OW_XW+col*3+2];
      }
      #pragma unroll
      for(int m=1;m<16;m<<=1){
        #pragma unroll
        for(int t=0;t<8;t++) r[t]+=__shfl_xor(r[t],m,64);
      }
      if(l==0){
        float dchi=r[0]+w[OW_AB];
        for(int k=0;k<4;k++)
          stout(out,(long)k*N_+n, wrapf(ldin(old_chi,(long)k*N_+n,f32)+dchi), f32);
        float dphi=r[4]+w[OW_BAB];
        stout(out,(long)4*N_+n, wrapf(ldin(old_phi,n,f32)+dphi), f32);
        stout(out,(long)5*N_+n, wrapf(ldin(old_psi,n,f32)+dphi), f32);
        for(int t=0;t<3;t++){
          stout(out,(long)6*N_+(long)n*3+t, ldin(old_cb,(long)n*3+t,f32)+r[1+t]+w[OW_CB+t], f32);
          stout(out,(long)9*N_+(long)n*3+t, ldin(old_ca,(long)n*3+t,f32)+r[5+t]+w[OW_XB+t], f32);
        }
      }
    }
  }
}

// ---------- host ----------
extern "C" void kernel_launch(void* const* d_in, const int* in_sizes, int n_in,
                              void* d_out, int out_size, void* d_ws, size_t ws_size,
                              hipStream_t stream) {
  (void)in_sizes; (void)n_in; (void)out_size; (void)ws_size;

  char* p=(char*)d_ws;
  auto alloc=[&](size_t bytes)->void*{ void* r=(void*)p; p+=((bytes+255)&~(size_t)255); return r; };
  int*   flag   =(int*)  alloc(16);
  float* warena =(float*)alloc((size_t)OW_TOT*4);
  float* dv     =(float*)alloc(1024*4);
  float* dvf    =(float*)alloc(1024*4);
  float* P      =(float*)alloc((size_t)441*128*4);
  float* sp     =(float*)alloc(441*4);
  float* qp     =(float*)alloc(441*4);
  float* hat_h  =(float*)alloc((size_t)N_*128*4);
  float* hbuf   =(float*)alloc((size_t)N_*128*4);
  float* bufX   =(float*)alloc((size_t)N_*128*4);
  unsigned short* bufXb=(unsigned short*)alloc((size_t)N_*128*2);
  unsigned short* bufMb=(unsigned short*)alloc((size_t)N_*128*2);
  float* xn_sc  =(float*)alloc((size_t)N_*32*4);
  float* xn_bb  =(float*)alloc((size_t)N_*64*4);
  float* we     =(float*)alloc((size_t)ESC*4);
  float* we_csr =(float*)alloc((size_t)ESC*4);
  float* an     =(float*)alloc((size_t)N_*4);
  float* bn     =(float*)alloc((size_t)N_*4);
  float* dis    =(float*)alloc((size_t)N_*4);
  float* disb   =(float*)alloc((size_t)N_*4);
  int* rp_sc    =(int*)  alloc((size_t)(N_+1)*4);
  int* rp_bb    =(int*)  alloc((size_t)(N_+1)*4);
  int*  key1_sc =(int*)  alloc((size_t)ESC*4);
  int2* pay1_sc =(int2*) alloc((size_t)ESC*8);
  int*  dstS_sc =(int*)  alloc((size_t)ESC*4);
  int2* csr_se_sc=(int2*)alloc((size_t)ESC*8);
  int*  key1_bb =(int*)  alloc((size_t)EBB*4);
  int2* pay1_bb =(int2*) alloc((size_t)EBB*8);
  int*  dstS_bb =(int*)  alloc((size_t)EBB*4);
  int2* csr_se_bb=(int2*)alloc((size_t)EBB*8);
  int*  hist    =(int*)  alloc((size_t)(RBS+RBB)*256*4);
  int*  tot     =(int*)  alloc(512*4);
  int*  dbase   =(int*)  alloc(512*4);
  unsigned short* wfg_hi =(unsigned short*)alloc(2048*8*2);
  unsigned short* wfg_lo =(unsigned short*)alloc(2048*8*2);
  unsigned short* wfbg_hi=(unsigned short*)alloc(2048*8*2);
  unsigned short* wfi2_hi=(unsigned short*)alloc(2048*8*2);
  unsigned short* wfi1_hi=(unsigned short*)alloc(4096*8*2);
  unsigned short* wfsc_hi=(unsigned short*)alloc(512*8*2);
  unsigned short* wfsc_lo=(unsigned short*)alloc(512*8*2);
  unsigned short* wfbb_hi=(unsigned short*)alloc(1024*8*2);
  unsigned short* wfbb_lo=(unsigned short*)alloc(1024*8*2);

  const int* src_sc=(const int*)d_in[48];
  const int* dst_sc=src_sc+ESC;
  const int* src_bb=(const int*)d_in[49];
  const int* dst_bb=src_bb+EBB;

  k_detect<<<1,1,0,stream>>>(d_in[0], flag);

  CvtArgs ca;
  {
    int map[29]={14,15,16,17,18,19,20,21,22,23,24,25,30,31,32,33,34,35,36,37,
                 38,39,40,41,42,43,44,45,13};
    for(int i=0;i<29;i++) ca.src[i]=d_in[map[i]];
  }
  k_cvtw<<<(OW_TOT+255)/256,256,0,stream>>>(ca, flag, warena);

  // mega prep: wprep | prevec | preP | LN
  k_prep<<<PB_LN,256,0,stream>>>(warena, flag,
      wfg_hi,wfg_lo, wfbg_hi, wfi2_hi, wfi1_hi,
      wfsc_hi,wfsc_lo, wfbb_hi,wfbb_lo,
      d_in[26], d_in[27], d_in[28], d_in[29], dv, dvf, P, sp, qp,
      d_in[0], d_in[1], d_in[2], d_in[3], d_in[4], d_in[5], xn_sc, xn_bb);

  // stable radix CSR build (parallel scan)
  k_rhist<<<RBS+RBB,256,0,stream>>>(dst_sc, dst_bb, 0, hist);
  k_rscanA<<<512,256,0,stream>>>(hist, tot);
  k_rscanB<<<1,256,0,stream>>>(tot, dbase);
  k_rscat<<<RBS+RBB,256,0,stream>>>(0, 1, dst_sc, src_sc, (const int2*)nullptr,
                                    dst_bb, src_bb, (const int2*)nullptr, hist, dbase,
                                    key1_sc, pay1_sc, key1_bb, pay1_bb);
  k_rhist<<<RBS+RBB,256,0,stream>>>(key1_sc, key1_bb, 8, hist);
  k_rscanA<<<512,256,0,stream>>>(hist, tot);
  k_rscanB<<<1,256,0,stream>>>(tot, dbase);
  k_rscat<<<RBS+RBB,256,0,stream>>>(8, 0, key1_sc, (const int*)nullptr, pay1_sc,
                                    key1_bb, (const int*)nullptr, pay1_bb, hist, dbase,
                                    dstS_sc, csr_se_sc, dstS_bb, csr_se_bb);
  k_bounds<<<(int)(((long)ESC+1+EBB+1+255)/256),256,0,stream>>>(dstS_sc, dstS_bb, rp_sc, rp_bb);
  k_degb<<<(N_+255)/256,256,0,stream>>>(rp_bb, disb);

  // featurizer GEMMs (merged)
  const int GB = (N_+63)/64;
  k_mfeat<<<2*GB,256,0,stream>>>(xn_sc, xn_bb, wfsc_hi, wfsc_lo, wfbb_hi, wfbb_lo,
                                 warena, hat_h, hbuf, N_);

  // edge MLP (16-lane groups, 4 edges/group, coalesced P)
  k_w0<<<WBG,256,0,stream>>>(d_in[6],d_in[7],(const int*)d_in[46],(const int*)d_in[47],
                             flag,dvf,P,sp,qp,we);

  // sidechain layers (GEMM || degree merged; dis[src] inlined in agg)
  const int DB = (N_+255)/256;
  for(int l=0;l<3;l++){
    k_gemmdeg<<<GB+DB,256,0,stream>>>(hat_h, wfg_hi, wfg_lo, bufX, N_,
                                      rp_sc, csr_se_sc, we, an, bn, dv, we_csr, dis, l);
    k_agg_sc<<<N_/4,256,0,stream>>>(rp_sc,csr_se_sc,we_csr,dis,bufX,warena,hat_h,dv,an,bn,(l<2)?1:0);
  }

  // backbone layers (fused GEMM trio + agg; heads fused into last agg)
  for(int l=0;l<2;l++){
    k_mbb<<<GB,256,0,stream>>>(hbuf, hat_h, wfi1_hi, wfbg_hi, wfi2_hi,
                               warena+OW_IB1, warena+OW_IB2, bufXb, bufMb, N_);
    k_agg_bb<<<N_/4,256,0,stream>>>(rp_bb,csr_se_bb,disb,bufXb,bufMb,warena,hbuf,
                                    hat_h, d_in[8],d_in[9],d_in[10],d_in[11],d_in[12],
                                    flag, d_out, (l==1)?1:0);
  }
}

// Round 18
// 555.277 us; speedup vs baseline: 1.2455x; 1.0067x over previous
//
#include <hip/hip_runtime.h>
#include <stdint.h>

#define DEVI __device__ __forceinline__

constexpr int N_   = 50000;
constexpr int ESC  = 600000;
constexpr int EBB  = 100000;
constexpr int NRES = 21;
constexpr float PI_F = 3.14159f;

// radix geometry
constexpr int RCH = 2048;
constexpr int RBS = (ESC + RCH - 1)/RCH;  // 293
constexpr int RBB = (EBB + RCH - 1)/RCH;  // 49

typedef __attribute__((ext_vector_type(8))) short short8v;
typedef __attribute__((ext_vector_type(4))) float f32x4;

// ---------- dtype helpers ----------
DEVI float bf2f(unsigned short u){ return __uint_as_float(((unsigned)u)<<16); }
DEVI unsigned short f2bf(float f){
  unsigned x = __float_as_uint(f);
  unsigned r = (x + 0x7FFFu + ((x>>16)&1u))>>16;
  return (unsigned short)r;
}
DEVI float ldin(const void* p, long i, int f32){
  return f32 ? ((const float*)p)[i] : bf2f(((const unsigned short*)p)[i]);
}
DEVI void stout(void* p, long i, float v, int f32){
  if(f32) ((float*)p)[i]=v; else ((unsigned short*)p)[i]=f2bf(v);
}
DEVI float wrapf(float a){
  float t = a + PI_F;
  const float TP = 2.f*PI_F;
  t -= floorf(t/TP)*TP;
  return t - PI_F;
}

// ---------- weight arena offsets ----------
constexpr int OW_SC_LN_G=0;
constexpr int OW_SC_LN_B=OW_SC_LN_G+19;
constexpr int OW_SC_W  = OW_SC_LN_B+19;
constexpr int OW_SC_B  = OW_SC_W+19*128;
constexpr int OW_BB_LN_G=OW_SC_B+128;
constexpr int OW_BB_LN_B=OW_BB_LN_G+38;
constexpr int OW_BB_W = OW_BB_LN_B+38;
constexpr int OW_BB_B = OW_BB_W+38*128;
constexpr int OW_E_LN_G=OW_BB_B+128;
constexpr int OW_E_LN_B=OW_E_LN_G+66;
constexpr int OW_EW1 = OW_E_LN_B+66;
constexpr int OW_EB1 = OW_EW1+66*128;
constexpr int OW_GW  = OW_EB1+128;
constexpr int OW_GB  = OW_GW+128*128;
constexpr int OW_BGW = OW_GB+128;
constexpr int OW_BGB = OW_BGW+128*128;
constexpr int OW_IW1 = OW_BGB+128;
constexpr int OW_IB1 = OW_IW1+256*128;
constexpr int OW_IW2 = OW_IB1+128;
constexpr int OW_IB2 = OW_IW2+128*128;
constexpr int OW_AW  = OW_IB2+128;
constexpr int OW_AB  = OW_AW+128;
constexpr int OW_BAW = OW_AB+1;
constexpr int OW_BAB = OW_BAW+128;
constexpr int OW_CW  = OW_BAB+1;
constexpr int OW_CB  = OW_CW+128*3;
constexpr int OW_XW  = OW_CB+3;
constexpr int OW_XB  = OW_XW+128*3;
constexpr int OW_RES = OW_XB+3;
constexpr int OW_TOT = OW_RES+21*32;

// ---------- basic kernels ----------
__global__ void k_detect(const void* vcom, int* flag){
  const unsigned short* u = (const unsigned short*)vcom;
  int insane=0;
  for(int i=0;i<64;i+=2){
    float f = bf2f(u[i]);
    float a = fabsf(f);
    if(!(a<1e5f) || (a!=0.0f && a<1e-5f)) insane++;
  }
  *flag = (insane>=8)?1:0;
}

struct CvtArgs { const void* src[29]; };

__global__ void k_cvtw(CvtArgs a, const int* flag, float* w){
  static constexpr int offs[30] = {
    OW_SC_LN_G,OW_SC_LN_B,OW_SC_W,OW_SC_B,OW_BB_LN_G,OW_BB_LN_B,OW_BB_W,OW_BB_B,
    OW_E_LN_G,OW_E_LN_B,OW_EW1,OW_EB1,OW_GW,OW_GB,OW_BGW,OW_BGB,OW_IW1,OW_IB1,
    OW_IW2,OW_IB2,OW_AW,OW_AB,OW_BAW,OW_BAB,OW_CW,OW_CB,OW_XW,OW_XB,OW_RES,OW_TOT};
  int f32=*flag;
  for(int t=blockIdx.x*blockDim.x+threadIdx.x; t<OW_TOT; t+=gridDim.x*blockDim.x){
    int s=0;
    while(t>=offs[s+1]) s++;
    w[t]=ldin(a.src[s], t-offs[s], f32);
  }
}

// W[K x 128] -> MFMA fragment order (zero-padded past Kreal), split hi/lo bf16.
DEVI void wprep_pad(const float* W, int Kreal, unsigned short* hi, unsigned short* lo, int idx){
  int lane=idx&63, nt=(idx>>6)&7, kt=idx>>9;
  int n = nt*16 + (lane&15);
  int kbase = kt*32 + (lane>>4)*8;
  #pragma unroll
  for(int i=0;i<8;i++){
    int k=kbase+i;
    float v = (k<Kreal) ? W[(long)k*128 + n] : 0.f;
    unsigned short h = f2bf(v);
    hi[(long)idx*8+i]=h;
    if(lo){ float r = v - bf2f(h); lo[(long)idx*8+i]=f2bf(r); }
  }
}

// ---------- mega prep kernel: wprep | prevec | preP | LN ----------
constexpr int PB_WP = 46;
constexpr int PB_PV = PB_WP+1;
constexpr int PB_PP = PB_PV+441;
constexpr int PB_LN = PB_PP + (2*N_+3)/4;

__global__ void k_prep(const float* w, const int* flag,
    unsigned short* g_hi, unsigned short* g_lo,
    unsigned short* bg_hi,
    unsigned short* i2_hi,
    unsigned short* i1_hi,
    unsigned short* sc_hi, unsigned short* sc_lo,
    unsigned short* bb_hi, unsigned short* bb_lo,
    const void* eW2, const void* eb2, const void* euW, const void* eub,
    float* dv, float* dvf, float* P, float* sp, float* qp,
    const void* vcom, const void* sbfchi,
    const void* xca, const void* vcb, const void* sphi, const void* spsi,
    float* xn_sc, float* xn_bb){
  __shared__ float pv[64];
  int b=blockIdx.x;
  if(b<PB_WP){
    int idx=b*256+threadIdx.x;
    if(idx<2048)       wprep_pad(w+OW_GW,  128, g_hi,  g_lo,  idx);
    else if(idx<4096)  wprep_pad(w+OW_BGW, 128, bg_hi, nullptr, idx-2048);
    else if(idx<6144)  wprep_pad(w+OW_IW2, 128, i2_hi, nullptr, idx-4096);
    else if(idx<10240) wprep_pad(w+OW_IW1, 256, i1_hi, nullptr, idx-6144);
    else if(idx<10752) wprep_pad(w+OW_SC_W, 19, sc_hi, sc_lo, idx-10240);
    else if(idx<11776) wprep_pad(w+OW_BB_W, 38, bb_hi, bb_lo, idx-10752);
  } else if(b<PB_PV){
    int j=threadIdx.x; int f32=*flag;
    if(j<128){
      const float* g=w+OW_E_LN_G; const float* bb=w+OW_E_LN_B; const float* W1=w+OW_EW1;
      float A=g[0]*W1[j], C=g[1]*W1[128+j];
      float G=0,B=0;
      for(int i=0;i<66;i++){ float wij=W1[i*128+j]; G+=g[i]*wij; B+=bb[i]*wij; }
      B += w[OW_EB1+j];
      float v2=0; for(int k=0;k<128;k++) v2+=ldin(eW2,(long)j*128+k,f32);
      float us=0,ud=0;
      for(int k=0;k<128;k++){ us+=ldin(euW,(long)j*128+k,f32); ud+=ldin(euW,(long)(128+j)*128+k,f32); }
      dv[640+j]=us*(1.f/128.f); dv[768+j]=ud*(1.f/128.f);
      dvf[j]=A; dvf[128+j]=C; dvf[256+j]=G; dvf[384+j]=B; dvf[512+j]=v2*(1.f/128.f);
      if(j==0){
        float s=0,t=0;
        for(int k=0;k<128;k++){ s+=ldin(eb2,k,f32); t+=ldin(eub,k,f32); }
        dv[896]=s*(1.f/128.f); dv[897]=t*(1.f/128.f);
        dvf[640]=s*(1.f/128.f);
      }
    }
  } else if(b<PB_PP){
    int c=b-PB_PV, j=threadIdx.x;
    const float* res=w+OW_RES;
    if(j<32) pv[j]=res[(c/NRES)*32+j];
    else if(j<64) pv[j]=res[(c%NRES)*32+(j-32)];
    __syncthreads();
    if(j<128){
      const float* g=w+OW_E_LN_G; const float* W1=w+OW_EW1;
      float s=0;
      for(int i=0;i<64;i++) s += pv[i]*g[2+i]*W1[(2+i)*128+j];
      P[c*128+j]=s;
      if(j==0){ float a=0,q=0; for(int i=0;i<64;i++){a+=pv[i]; q+=pv[i]*pv[i];} sp[c]=a; qp[c]=q; }
    }
  } else {
    int wv=threadIdx.x>>6, lane=threadIdx.x&63;
    long gw=(long)(b-PB_PP)*4+wv;
    int f32=*flag;
    if(gw<N_){
      int n=(int)gw;
      float x=0.f;
      if(lane<3) x=ldin(vcom,(long)n*3+lane,f32);
      else if(lane<19) x=ldin(sbfchi,(long)n*16+(lane-3),f32);
      float s=x, q=x*x;
      for(int m=1;m<64;m<<=1){ s+=__shfl_xor(s,m,64); q+=__shfl_xor(q,m,64); }
      float mean=s*(1.f/19.f);
      float istd=rsqrtf(fmaxf(q*(1.f/19.f)-mean*mean,0.f)+1e-5f);
      if(lane<32){
        float xn=(lane<19)? (x-mean)*istd*w[OW_SC_LN_G+lane]+w[OW_SC_LN_B+lane] : 0.f;
        xn_sc[(long)n*32+lane]=xn;
      }
    } else if(gw<2L*N_){
      int n=(int)(gw-N_);
      float x=0.f;
      if(lane<3) x=ldin(xca,(long)n*3+lane,f32);
      else if(lane<6) x=ldin(vcb,(long)n*3+(lane-3),f32);
      else if(lane<22) x=ldin(sphi,(long)n*16+(lane-6),f32);
      else if(lane<38) x=ldin(spsi,(long)n*16+(lane-22),f32);
      float s=x, q=x*x;
      for(int m=1;m<64;m<<=1){ s+=__shfl_xor(s,m,64); q+=__shfl_xor(q,m,64); }
      float mean=s*(1.f/38.f);
      float istd=rsqrtf(fmaxf(q*(1.f/38.f)-mean*mean,0.f)+1e-5f);
      float xn=(lane<38)? (x-mean)*istd*w[OW_BB_LN_G+lane]+w[OW_BB_LN_B+lane] : 0.f;
      xn_bb[(long)n*64+lane]=xn;
    }
  }
}

// ---------- stable 2-pass radix CSR build (RCH=2048, parallel scan) ----------
__global__ void k_rhist(const int* key_sc, const int* key_bb, int shift, int* hist){
  __shared__ int h[256];
  h[threadIdx.x]=0; __syncthreads();
  int g = blockIdx.x>=RBS;
  const int* key = g? key_bb : key_sc;
  int E = g? EBB : ESC;
  int b = g? blockIdx.x-RBS : blockIdx.x;
  int base=b*RCH;
  for(int r=0;r<RCH/256;r++){
    int idx=base+r*256+threadIdx.x;
    if(idx<E) atomicAdd(&h[(key[idx]>>shift)&255],1);
  }
  __syncthreads();
  hist[(long)blockIdx.x*256+threadIdx.x]=h[threadIdx.x];
}
__global__ void k_rscanA(int* hist, int* tot){
  __shared__ int sA[512], sB[512];
  int g = blockIdx.x>=256;
  int d = blockIdx.x&255;
  int NB = g? RBB : RBS;
  int* H = hist + (g? (long)RBS*256 : 0);
  int t=threadIdx.x;
  int i0=t, i1=t+256;
  int o0 = (i0<NB)? H[(long)i0*256+d] : 0;
  int o1 = (i1<NB)? H[(long)i1*256+d] : 0;
  sA[i0]=o0; sA[i1]=o1;
  __syncthreads();
  int* a=sA; int* b=sB;
  for(int off=1; off<512; off<<=1){
    b[i0] = a[i0] + ((i0>=off)? a[i0-off]:0);
    b[i1] = a[i1] + ((i1>=off)? a[i1-off]:0);
    __syncthreads();
    int* tmp=a; a=b; b=tmp;
  }
  if(i0<NB) H[(long)i0*256+d] = a[i0]-o0;
  if(i1<NB) H[(long)i1*256+d] = a[i1]-o1;
  if(t==255) tot[(g?256:0)+d] = a[511];
}
__global__ void k_rscanB(const int* tot, int* base){
  __shared__ int sA[256], sB[256];
  int t=threadIdx.x;
  for(int g=0;g<2;g++){
    int o=tot[g*256+t];
    sA[t]=o; __syncthreads();
    int* a=sA; int* b=sB;
    for(int off=1; off<256; off<<=1){
      b[t] = a[t] + ((t>=off)? a[t-off]:0);
      __syncthreads();
      int* tmp=a; a=b; b=tmp;
    }
    base[g*256+t] = a[t]-o;
    __syncthreads();
  }
}
__global__ void k_rscat(int shift, int first,
    const int* kin_sc, const int* srcv_sc, const int2* pin_sc,
    const int* kin_bb, const int* srcv_bb, const int2* pin_bb,
    const int* hist, const int* dbase,
    int* kout_sc, int2* pout_sc, int* kout_bb, int2* pout_bb){
  __shared__ int running[256];
  __shared__ int Hb[256];
  __shared__ int whist[4][256];
  __shared__ int pw[4][256];
  int tid=threadIdx.x, lane=tid&63, w=tid>>6;
  int g = blockIdx.x>=RBS;
  const int* kin  = g? kin_bb : kin_sc;
  const int* srcv = g? srcv_bb: srcv_sc;
  const int2* pin = g? pin_bb : pin_sc;
  int* kout  = g? kout_bb : kout_sc;
  int2* pout = g? pout_bb : pout_sc;
  int E = g? EBB : ESC;
  int b = g? blockIdx.x-RBS : blockIdx.x;
  running[tid]=0;
  Hb[tid]=hist[(long)blockIdx.x*256+tid] + dbase[(g?256:0)+tid];
  int base=b*RCH;
  for(int r=0;r<RCH/256;r++){
    __syncthreads();
    whist[0][tid]=0; whist[1][tid]=0; whist[2][tid]=0; whist[3][tid]=0;
    __syncthreads();
    int idx=base+r*256+tid;
    bool valid = idx<E;
    int key=0, digit=0; int2 pay; pay.x=0; pay.y=0;
    if(valid){
      key=kin[idx];
      digit=(key>>shift)&255;
      if(first){ pay.x=srcv[idx]; pay.y=idx; }
      else pay=pin[idx];
    }
    unsigned long long act=__ballot(valid);
    unsigned long long same=act;
    #pragma unroll
    for(int k=0;k<8;k++){
      unsigned long long m=__ballot(valid && ((digit>>k)&1));
      same &= ((digit>>k)&1)? m : ~m;
    }
    same &= act;
    unsigned long long below=(1ULL<<lane)-1ULL;
    int wrank=__popcll(same & below);
    if(valid && wrank==0) whist[w][digit]=__popcll(same);
    __syncthreads();
    int c0=whist[0][tid], c1=whist[1][tid], c2=whist[2][tid], c3=whist[3][tid];
    pw[0][tid]=0; pw[1][tid]=c0; pw[2][tid]=c0+c1; pw[3][tid]=c0+c1+c2;
    __syncthreads();
    if(valid){
      int pos=Hb[digit]+running[digit]+pw[w][digit]+wrank;
      kout[pos]=key; pout[pos]=pay;
    }
    __syncthreads();
    running[tid]+=c0+c1+c2+c3;
  }
}
__global__ void k_bounds(const int* dstS_sc, const int* dstS_bb, int* rp_sc, int* rp_bb){
  long i=(long)blockIdx.x*blockDim.x+threadIdx.x;
  if(i<=ESC){
    int cur = (i<ESC)? dstS_sc[i] : N_;
    int prev= (i>0)? dstS_sc[i-1] : -1;
    for(int d=prev+1; d<=cur; d++) rp_sc[d]=(int)i;
  } else if(i <= (long)ESC+1+EBB){
    long j=i-(ESC+1);
    int cur = (j<EBB)? dstS_bb[j] : N_;
    int prev= (j>0)? dstS_bb[j-1] : -1;
    for(int d=prev+1; d<=cur; d++) rp_bb[d]=(int)j;
  }
}
__global__ void k_degb(const int* rp, float* disb){
  int n=blockIdx.x*blockDim.x+threadIdx.x;
  if(n<N_) disb[n]=rsqrtf(1.f+(float)(rp[n+1]-rp[n]));
}

// ---------- edge MLP: 16-lane groups, 4 edges/group, dvf cached in registers ----------
constexpr int WBG = (ESC + 63)/64;  // 9375
__global__ __launch_bounds__(256,4) void k_w0(const void* dsc, const void* dmin,
    const int* ri_, const int* rj_, const int* flag, const float* dvf,
    const float* P, const float* sp, const float* qp, float* we){
  int wv=threadIdx.x>>6, lane=threadIdx.x&63;
  int g=lane>>4, l=lane&15;
  long ebase=(long)blockIdx.x*64 + wv*16 + g*4;
  int f32=*flag;
  int j0=l*8;
  float4 A0=*(const float4*)&dvf[j0],     A1=*(const float4*)&dvf[j0+4];
  float4 C0=*(const float4*)&dvf[128+j0], C1=*(const float4*)&dvf[128+j0+4];
  float4 G0=*(const float4*)&dvf[256+j0], G1=*(const float4*)&dvf[256+j0+4];
  float4 B0=*(const float4*)&dvf[384+j0], B1=*(const float4*)&dvf[384+j0+4];
  float4 V0=*(const float4*)&dvf[512+j0], V1=*(const float4*)&dvf[512+j0+4];
  float eb2=dvf[640];
  #pragma unroll
  for(int k=0;k<4;k++){
    long e=ebase+k;
    bool val = e<ESC;
    long ee = val? e : 0;
    float d1=ldin(dsc,ee,f32), d2=ldin(dmin,ee,f32);
    int c=ri_[ee]*NRES+rj_[ee];
    float m=(d1+d2+sp[c])*(1.f/66.f);
    float ms=(d1*d1+d2*d2+qp[c])*(1.f/66.f);
    float istd=rsqrtf(fmaxf(ms-m*m,0.f)+1e-5f);
    float nmi=-m*istd;
    float4 P0=*(const float4*)&P[(long)c*128+j0];
    float4 P1=*(const float4*)&P[(long)c*128+j0+4];
    float acc=0.f, t, hid;
    t=fmaf(d1,A0.x,fmaf(d2,C0.x,P0.x)); hid=fmaf(istd,t,fmaf(nmi,G0.x,B0.x)); acc=fmaf(fmaxf(hid,0.f),V0.x,acc);
    t=fmaf(d1,A0.y,fmaf(d2,C0.y,P0.y)); hid=fmaf(istd,t,fmaf(nmi,G0.y,B0.y)); acc=fmaf(fmaxf(hid,0.f),V0.y,acc);
    t=fmaf(d1,A0.z,fmaf(d2,C0.z,P0.z)); hid=fmaf(istd,t,fmaf(nmi,G0.z,B0.z)); acc=fmaf(fmaxf(hid,0.f),V0.z,acc);
    t=fmaf(d1,A0.w,fmaf(d2,C0.w,P0.w)); hid=fmaf(istd,t,fmaf(nmi,G0.w,B0.w)); acc=fmaf(fmaxf(hid,0.f),V0.w,acc);
    t=fmaf(d1,A1.x,fmaf(d2,C1.x,P1.x)); hid=fmaf(istd,t,fmaf(nmi,G1.x,B1.x)); acc=fmaf(fmaxf(hid,0.f),V1.x,acc);
    t=fmaf(d1,A1.y,fmaf(d2,C1.y,P1.y)); hid=fmaf(istd,t,fmaf(nmi,G1.y,B1.y)); acc=fmaf(fmaxf(hid,0.f),V1.y,acc);
    t=fmaf(d1,A1.z,fmaf(d2,C1.z,P1.z)); hid=fmaf(istd,t,fmaf(nmi,G1.z,B1.z)); acc=fmaf(fmaxf(hid,0.f),V1.z,acc);
    t=fmaf(d1,A1.w,fmaf(d2,C1.w,P1.w)); hid=fmaf(istd,t,fmaf(nmi,G1.w,B1.w)); acc=fmaf(fmaxf(hid,0.f),V1.w,acc);
    #pragma unroll
    for(int msk=1;msk<16;msk<<=1) acc+=__shfl_xor(acc,msk,64);
    if(l==0 && val) we[e]=acc+eb2;
  }
}

// ---------- split-bf16 MFMA GEMM core ----------
DEVI f32x4 MFMA(short8v a, short8v b, f32x4 c){
  return __builtin_amdgcn_mfma_f32_16x16x32_bf16(a,b,c,0,0,0);
}
DEVI void cvt8(float4 a0, float4 a1, short8v& hi, short8v& lo){
  float av[8]={a0.x,a0.y,a0.z,a0.w,a1.x,a1.y,a1.z,a1.w};
  union{short8v v; unsigned short u[8];} H,L;
  #pragma unroll
  for(int i=0;i<8;i++){
    unsigned short h=f2bf(av[i]);
    float r=av[i]-bf2f(h);
    H.u[i]=h; L.u[i]=f2bf(r);
  }
  hi=H.v; lo=L.v;
}
DEVI short8v cvt8hi(float4 a0, float4 a1){
  union{short8v v; unsigned short u[8];} H;
  H.u[0]=f2bf(a0.x); H.u[1]=f2bf(a0.y); H.u[2]=f2bf(a0.z); H.u[3]=f2bf(a0.w);
  H.u[4]=f2bf(a1.x); H.u[5]=f2bf(a1.y); H.u[6]=f2bf(a1.z); H.u[7]=f2bf(a1.w);
  return H.v;
}

template<int KT, int LDA>
DEVI void mgemm_body(int bid, const float* A1, const float* A2,
    const unsigned short* Whi, const unsigned short* Wlo,
    const float* bias, float* C, int relu, int accum, int M){
  const int lane = threadIdx.x & 63;
  const int wid  = threadIdx.x >> 6;
  const int r0   = bid*64 + wid*16;
  const int mrow = lane & 15;
  const int kg   = lane >> 4;
  long arow = (long)min(r0 + mrow, M-1);
  f32x4 acc[8];
  #pragma unroll
  for(int t=0;t<8;t++) acc[t]=(f32x4){0.f,0.f,0.f,0.f};

  #pragma unroll
  for(int kt=0; kt<KT; kt++){
    const float* A = (KT==8 && kt>=4) ? A2 : A1;
    int kb = (kt&3)*32 + kg*8;
    float4 a0 = *(const float4*)&A[arow*LDA + kb];
    float4 a1 = *(const float4*)&A[arow*LDA + kb + 4];
    short8v ah, al; cvt8(a0,a1,ah,al);
    #pragma unroll
    for(int nt=0;nt<8;nt++){
      long off = (((long)kt*8+nt)*64 + lane)*8;
      short8v wh = *(const short8v*)&Whi[off];
      short8v wl = *(const short8v*)&Wlo[off];
      acc[nt] = MFMA(ah, wh, acc[nt]);
      acc[nt] = MFMA(al, wh, acc[nt]);
      acc[nt] = MFMA(ah, wl, acc[nt]);
      acc[nt] = MFMA(al, wl, acc[nt]);
    }
  }

  #pragma unroll
  for(int nt=0;nt<8;nt++){
    int col = nt*16 + mrow;
    float bj = bias ? bias[col] : 0.f;
    #pragma unroll
    for(int r=0;r<4;r++){
      int row = r0 + kg*4 + r;
      if(row >= M) continue;
      long idx = (long)row*128 + col;
      float v = acc[nt][r] + bj;
      if(relu) v = fmaxf(v,0.f);
      if(accum) v += C[idx];
      C[idx] = v;
    }
  }
}

// sc layer: gW GEMM overlapped with degree pass
__global__ __launch_bounds__(256,4) void k_gemmdeg(const float* hat_h,
    const unsigned short* Whi, const unsigned short* Wlo, float* C, int M,
    const int* rp, const int2* se, const float* we_edge,
    const float* an, const float* bn, const float* dv,
    float* we_csr, float* dis, int layer){
  int GBl=(M+63)/64;
  if((int)blockIdx.x < GBl){
    mgemm_body<4,128>(blockIdx.x, hat_h, nullptr, Whi, Wlo, nullptr, C, 0, 0, M);
  } else {
    int n=(blockIdx.x-GBl)*256+threadIdx.x;
    if(n>=N_) return;
    int e0=rp[n], e1=rp[n+1];
    float s=1.f;
    if(layer==0){
      for(int p=e0;p<e1;p++){ float ww=we_edge[se[p].y]; we_csr[p]=ww; s+=ww; }
    } else {
      float add_n = bn[n] + dv[897];
      for(int p=e0;p<e1;p++){
        float ww=we_csr[p] + an[se[p].x] + add_n;
        we_csr[p]=ww; s+=ww;
      }
    }
    dis[n]=rsqrtf(fmaxf(s,1e-6f));
  }
}

// featurizer: both small GEMMs in one launch
__global__ __launch_bounds__(256,4) void k_mfeat(const float* xn_sc, const float* xn_bb,
    const unsigned short* schi, const unsigned short* sclo,
    const unsigned short* bbhi, const unsigned short* bblo,
    const float* w, float* hat_h, float* hbuf, int M){
  int GBl=(M+63)/64;
  if((int)blockIdx.x < GBl)
    mgemm_body<1,32>(blockIdx.x, xn_sc, nullptr, schi, sclo, w+OW_SC_B, hat_h, 0,0,M);
  else
    mgemm_body<2,64>(blockIdx.x-GBl, xn_bb, nullptr, bbhi, bblo, w+OW_BB_B, hbuf, 0,0,M);
}

// fused bb layer (backbone branch is NOT chaotic -> plain bf16 suffices)
__global__ __launch_bounds__(256,4) void k_mbb(const float* h, const float* hh,
    const unsigned short* W1hi,
    const unsigned short* W2hi,
    const unsigned short* W3hi,
    const float* b1, const float* b2,
    unsigned short* xwout, unsigned short* mout, int M){
  __shared__ unsigned short hids[64*136];
  const int lane = threadIdx.x & 63;
  const int wid  = threadIdx.x >> 6;
  const int r0   = blockIdx.x*64 + wid*16;
  const int mrow = lane & 15;
  const int kg   = lane >> 4;
  long arow = (long)min(r0 + mrow, M-1);
  f32x4 acc1[8], acc2[8];
  #pragma unroll
  for(int t=0;t<8;t++){ acc1[t]=(f32x4){0,0,0,0}; acc2[t]=(f32x4){0,0,0,0}; }

  #pragma unroll
  for(int kt=0; kt<8; kt++){
    const float* A = (kt>=4) ? hh : h;
    int kb = (kt&3)*32 + kg*8;
    float4 a0 = *(const float4*)&A[arow*128 + kb];
    float4 a1 = *(const float4*)&A[arow*128 + kb + 4];
    short8v ah = cvt8hi(a0,a1);
    #pragma unroll
    for(int nt=0;nt<8;nt++){
      long off = (((long)kt*8+nt)*64 + lane)*8;
      acc1[nt] = MFMA(ah, *(const short8v*)&W1hi[off], acc1[nt]);
    }
    if(kt<4){
      #pragma unroll
      for(int nt=0;nt<8;nt++){
        long off = (((long)kt*8+nt)*64 + lane)*8;
        acc2[nt] = MFMA(ah, *(const short8v*)&W2hi[off], acc2[nt]);
      }
    }
  }

  #pragma unroll
  for(int nt=0;nt<8;nt++){
    int col = nt*16 + mrow;
    float bj = b1[col];
    #pragma unroll
    for(int r=0;r<4;r++){
      int rloc = wid*16 + kg*4 + r;
      int row = r0 + kg*4 + r;
      hids[rloc*136 + col] = f2bf(fmaxf(acc1[nt][r] + bj, 0.f));
      if(row < M) xwout[(long)row*128 + col] = f2bf(acc2[nt][r]);
    }
  }
  __syncthreads();

  f32x4 acc3[8];
  #pragma unroll
  for(int t=0;t<8;t++) acc3[t]=(f32x4){0,0,0,0};
  int rloc = wid*16 + mrow;
  #pragma unroll
  for(int kt=0; kt<4; kt++){
    int kb = kt*32 + kg*8;
    short8v ah = *(const short8v*)&hids[rloc*136 + kb];
    #pragma unroll
    for(int nt=0;nt<8;nt++){
      long off = (((long)kt*8+nt)*64 + lane)*8;
      acc3[nt] = MFMA(ah, *(const short8v*)&W3hi[off], acc3[nt]);
    }
  }
  #pragma unroll
  for(int nt=0;nt<8;nt++){
    int col = nt*16 + mrow;
    float bj = b2[col];
    #pragma unroll
    for(int r=0;r<4;r++){
      int row = r0 + kg*4 + r;
      if(row < M) mout[(long)row*128 + col] = f2bf(acc3[nt][r] + bj);
    }
  }
}

// ---------- aggregation: 16 lanes/edge, 2-edge unroll, inline dis[src] ----------
__global__ void k_agg_sc(const int* __restrict__ rp, const int2* __restrict__ se,
                         const float* __restrict__ wc, const float* __restrict__ dis,
                         const float* __restrict__ xw, const float* __restrict__ w,
                         float* __restrict__ hat_h, const float* __restrict__ dv,
                         float* __restrict__ an, float* __restrict__ bn, int withdot){
  int wv=threadIdx.x>>6, lane=threadIdx.x&63;
  int n=blockIdx.x*4+wv;
  int g=lane>>4, l=lane&15, d0=l*8;
  float disn=dis[n];
  float4 aA={0,0,0,0}, aB={0,0,0,0}, cA={0,0,0,0}, cB={0,0,0,0};
  int e0=rp[n], e1=rp[n+1];
  int p=e0+g;
  for(; p+4<e1; p+=8){
    int s0=se[p].x, s1=se[p+4].x;
    float nw0=dis[s0]*wc[p], nw1=dis[s1]*wc[p+4];
    float4 xa0=*(const float4*)&xw[(long)s0*128+d0];
    float4 xb0=*(const float4*)&xw[(long)s0*128+d0+4];
    float4 xa1=*(const float4*)&xw[(long)s1*128+d0];
    float4 xb1=*(const float4*)&xw[(long)s1*128+d0+4];
    aA.x+=nw0*xa0.x; aA.y+=nw0*xa0.y; aA.z+=nw0*xa0.z; aA.w+=nw0*xa0.w;
    aB.x+=nw0*xb0.x; aB.y+=nw0*xb0.y; aB.z+=nw0*xb0.z; aB.w+=nw0*xb0.w;
    cA.x+=nw1*xa1.x; cA.y+=nw1*xa1.y; cA.z+=nw1*xa1.z; cA.w+=nw1*xa1.w;
    cB.x+=nw1*xb1.x; cB.y+=nw1*xb1.y; cB.z+=nw1*xb1.z; cB.w+=nw1*xb1.w;
  }
  if(p<e1){
    int s0=se[p].x;
    float nw0=dis[s0]*wc[p];
    float4 xa0=*(const float4*)&xw[(long)s0*128+d0];
    float4 xb0=*(const float4*)&xw[(long)s0*128+d0+4];
    aA.x+=nw0*xa0.x; aA.y+=nw0*xa0.y; aA.z+=nw0*xa0.z; aA.w+=nw0*xa0.w;
    aB.x+=nw0*xb0.x; aB.y+=nw0*xb0.y; aB.z+=nw0*xb0.z; aB.w+=nw0*xb0.w;
  }
  aA.x+=cA.x; aA.y+=cA.y; aA.z+=cA.z; aA.w+=cA.w;
  aB.x+=cB.x; aB.y+=cB.y; aB.z+=cB.z; aB.w+=cB.w;
  #pragma unroll
  for(int m=16;m<64;m<<=1){
    aA.x+=__shfl_xor(aA.x,m,64); aA.y+=__shfl_xor(aA.y,m,64);
    aA.z+=__shfl_xor(aA.z,m,64); aA.w+=__shfl_xor(aA.w,m,64);
    aB.x+=__shfl_xor(aB.x,m,64); aB.y+=__shfl_xor(aB.y,m,64);
    aB.z+=__shfl_xor(aB.z,m,64); aB.w+=__shfl_xor(aB.w,m,64);
  }
  float d2=disn*disn;
  float4 xsA=*(const float4*)&xw[(long)n*128+d0];
  float4 xsB=*(const float4*)&xw[(long)n*128+d0+4];
  float4 gbA=*(const float4*)&w[OW_GB+d0];
  float4 gbB=*(const float4*)&w[OW_GB+d0+4];
  float4 hoA=*(const float4*)&hat_h[(long)n*128+d0];
  float4 hoB=*(const float4*)&hat_h[(long)n*128+d0+4];
  float4 hA, hB;
  hA.x=hoA.x+fmaxf(aA.x*disn+d2*xsA.x+gbA.x,0.f);
  hA.y=hoA.y+fmaxf(aA.y*disn+d2*xsA.y+gbA.y,0.f);
  hA.z=hoA.z+fmaxf(aA.z*disn+d2*xsA.z+gbA.z,0.f);
  hA.w=hoA.w+fmaxf(aA.w*disn+d2*xsA.w+gbA.w,0.f);
  hB.x=hoB.x+fmaxf(aB.x*disn+d2*xsB.x+gbB.x,0.f);
  hB.y=hoB.y+fmaxf(aB.y*disn+d2*xsB.y+gbB.y,0.f);
  hB.z=hoB.z+fmaxf(aB.z*disn+d2*xsB.z+gbB.z,0.f);
  hB.w=hoB.w+fmaxf(aB.w*disn+d2*xsB.w+gbB.w,0.f);
  if(g==0){
    *(float4*)&hat_h[(long)n*128+d0]=hA;
    *(float4*)&hat_h[(long)n*128+d0+4]=hB;
  }
  if(withdot){
    float4 usA=*(const float4*)&dv[640+d0], usB=*(const float4*)&dv[640+d0+4];
    float4 udA=*(const float4*)&dv[768+d0], udB=*(const float4*)&dv[768+d0+4];
    float a = hA.x*usA.x+hA.y*usA.y+hA.z*usA.z+hA.w*usA.w
            + hB.x*usB.x+hB.y*usB.y+hB.z*usB.z+hB.w*usB.w;
    float b = hA.x*udA.x+hA.y*udA.y+hA.z*udA.z+hA.w*udA.w
            + hB.x*udB.x+hB.y*udB.y+hB.z*udB.z+hB.w*udB.w;
    #pragma unroll
    for(int m=1;m<16;m<<=1){ a+=__shfl_xor(a,m,64); b+=__shfl_xor(b,m,64); }
    if(lane==0){ an[n]=a; bn[n]=b; }
  }
}

DEVI void bf8ld(const unsigned short* p, float4& lo, float4& hi){
  union{short8v v; unsigned short u[8];} t;
  t.v = *(const short8v*)p;
  lo.x=bf2f(t.u[0]); lo.y=bf2f(t.u[1]); lo.z=bf2f(t.u[2]); lo.w=bf2f(t.u[3]);
  hi.x=bf2f(t.u[4]); hi.y=bf2f(t.u[5]); hi.z=bf2f(t.u[6]); hi.w=bf2f(t.u[7]);
}

// bb aggregation core (shared by plain and head-fused kernels)
DEVI void agg_bb_core(int n, int g, int d0,
    const int* __restrict__ rp, const int2* __restrict__ se,
    const float* __restrict__ disb, const unsigned short* __restrict__ xw,
    float4& aA, float4& aB, float& disn){
  int e0=rp[n], e1=rp[n+1];
  disn=disb[n];
  float4 cA={0,0,0,0}, cB={0,0,0,0};
  aA=(float4){0,0,0,0}; aB=(float4){0,0,0,0};
  int p=e0+g;
  for(; p+4<e1; p+=8){
    int s0=se[p].x, s1=se[p+4].x;
    float nw0=disb[s0], nw1=disb[s1];
    float4 xa0,xb0,xa1,xb1;
    bf8ld(&xw[(long)s0*128+d0], xa0, xb0);
    bf8ld(&xw[(long)s1*128+d0], xa1, xb1);
    aA.x+=nw0*xa0.x; aA.y+=nw0*xa0.y; aA.z+=nw0*xa0.z; aA.w+=nw0*xa0.w;
    aB.x+=nw0*xb0.x; aB.y+=nw0*xb0.y; aB.z+=nw0*xb0.z; aB.w+=nw0*xb0.w;
    cA.x+=nw1*xa1.x; cA.y+=nw1*xa1.y; cA.z+=nw1*xa1.z; cA.w+=nw1*xa1.w;
    cB.x+=nw1*xb1.x; cB.y+=nw1*xb1.y; cB.z+=nw1*xb1.z; cB.w+=nw1*xb1.w;
  }
  if(p<e1){
    int s0=se[p].x;
    float nw0=disb[s0];
    float4 xa0,xb0;
    bf8ld(&xw[(long)s0*128+d0], xa0, xb0);
    aA.x+=nw0*xa0.x; aA.y+=nw0*xa0.y; aA.z+=nw0*xa0.z; aA.w+=nw0*xa0.w;
    aB.x+=nw0*xb0.x; aB.y+=nw0*xb0.y; aB.z+=nw0*xb0.z; aB.w+=nw0*xb0.w;
  }
  aA.x+=cA.x; aA.y+=cA.y; aA.z+=cA.z; aA.w+=cA.w;
  aB.x+=cB.x; aB.y+=cB.y; aB.z+=cB.z; aB.w+=cB.w;
  #pragma unroll
  for(int m=16;m<64;m<<=1){
    aA.x+=__shfl_xor(aA.x,m,64); aA.y+=__shfl_xor(aA.y,m,64);
    aA.z+=__shfl_xor(aA.z,m,64); aA.w+=__shfl_xor(aA.w,m,64);
    aB.x+=__shfl_xor(aB.x,m,64); aB.y+=__shfl_xor(aB.y,m,64);
    aB.z+=__shfl_xor(aB.z,m,64); aB.w+=__shfl_xor(aB.w,m,64);
  }
}

// plain bb aggregation (layer 0) — lean signature, round-14 codegen
__global__ void k_agg_bb(const int* __restrict__ rp, const int2* __restrict__ se,
                         const float* __restrict__ disb,
                         const unsigned short* __restrict__ xw,
                         const unsigned short* __restrict__ mbuf,
                         const float* __restrict__ w, float* __restrict__ h){
  int wv=threadIdx.x>>6, lane=threadIdx.x&63;
  int n=blockIdx.x*4+wv;
  int g=lane>>4, l=lane&15, d0=l*8;
  float4 aA, aB; float disn;
  agg_bb_core(n, g, d0, rp, se, disb, xw, aA, aB, disn);
  if(g==0){
    float d2=disn*disn;
    float4 xsA,xsB,mA,mB;
    bf8ld(&xw[(long)n*128+d0], xsA, xsB);
    bf8ld(&mbuf[(long)n*128+d0], mA, mB);
    float4 gbA=*(const float4*)&w[OW_BGB+d0];
    float4 gbB=*(const float4*)&w[OW_BGB+d0+4];
    float4 hA=*(float4*)&h[(long)n*128+d0];
    float4 hB=*(float4*)&h[(long)n*128+d0+4];
    hA.x+=fmaxf(aA.x*disn+d2*xsA.x+gbA.x,0.f)+mA.x;
    hA.y+=fmaxf(aA.y*disn+d2*xsA.y+gbA.y,0.f)+mA.y;
    hA.z+=fmaxf(aA.z*disn+d2*xsA.z+gbA.z,0.f)+mA.z;
    hA.w+=fmaxf(aA.w*disn+d2*xsA.w+gbA.w,0.f)+mA.w;
    hB.x+=fmaxf(aB.x*disn+d2*xsB.x+gbB.x,0.f)+mB.x;
    hB.y+=fmaxf(aB.y*disn+d2*xsB.y+gbB.y,0.f)+mB.y;
    hB.z+=fmaxf(aB.z*disn+d2*xsB.z+gbB.z,0.f)+mB.z;
    hB.w+=fmaxf(aB.w*disn+d2*xsB.w+gbB.w,0.f)+mB.w;
    *(float4*)&h[(long)n*128+d0]=hA;
    *(float4*)&h[(long)n*128+d0+4]=hB;
  }
}

// bb aggregation + fused output heads (layer 1 only)
__global__ void k_agg_bbh(const int* __restrict__ rp, const int2* __restrict__ se,
                          const float* __restrict__ disb,
                          const unsigned short* __restrict__ xw,
                          const unsigned short* __restrict__ mbuf,
                          const float* __restrict__ w, float* __restrict__ h,
                          const float* __restrict__ hat_h,
                          const void* old_chi, const void* old_phi, const void* old_psi,
                          const void* old_cb, const void* old_ca,
                          const int* flag, void* out){
  int wv=threadIdx.x>>6, lane=threadIdx.x&63;
  int n=blockIdx.x*4+wv;
  int g=lane>>4, l=lane&15, d0=l*8;
  float4 aA, aB; float disn;
  agg_bb_core(n, g, d0, rp, se, disb, xw, aA, aB, disn);

  // compute updated h row on all 4 groups (registers), write from g==0
  float d2=disn*disn;
  float4 xsA,xsB,mA,mB;
  bf8ld(&xw[(long)n*128+d0], xsA, xsB);
  bf8ld(&mbuf[(long)n*128+d0], mA, mB);
  float4 gbA=*(const float4*)&w[OW_BGB+d0];
  float4 gbB=*(const float4*)&w[OW_BGB+d0+4];
  float4 hA=*(const float4*)&h[(long)n*128+d0];
  float4 hB=*(const float4*)&h[(long)n*128+d0+4];
  hA.x+=fmaxf(aA.x*disn+d2*xsA.x+gbA.x,0.f)+mA.x;
  hA.y+=fmaxf(aA.y*disn+d2*xsA.y+gbA.y,0.f)+mA.y;
  hA.z+=fmaxf(aA.z*disn+d2*xsA.z+gbA.z,0.f)+mA.z;
  hA.w+=fmaxf(aA.w*disn+d2*xsA.w+gbA.w,0.f)+mA.w;
  hB.x+=fmaxf(aB.x*disn+d2*xsB.x+gbB.x,0.f)+mB.x;
  hB.y+=fmaxf(aB.y*disn+d2*xsB.y+gbB.y,0.f)+mB.y;
  hB.z+=fmaxf(aB.z*disn+d2*xsB.z+gbB.z,0.f)+mB.z;
  hB.w+=fmaxf(aB.w*disn+d2*xsB.w+gbB.w,0.f)+mB.w;
  if(g==0){
    *(float4*)&h[(long)n*128+d0]=hA;
    *(float4*)&h[(long)n*128+d0+4]=hB;
  }

  // heads: every lane (all 4 groups hold identical hA/hB after the full reduce)
  // lanes l=0..15 own dims d0..d0+7; reduce over 16 lanes within group 0 only.
  if(g==0){
    int f32=*flag;
    float4 shA=*(const float4*)&hat_h[(long)n*128+d0];
    float4 shB=*(const float4*)&hat_h[(long)n*128+d0+4];
    float sv[8]={fmaxf(shA.x,0.f),fmaxf(shA.y,0.f),fmaxf(shA.z,0.f),fmaxf(shA.w,0.f),
                 fmaxf(shB.x,0.f),fmaxf(shB.y,0.f),fmaxf(shB.z,0.f),fmaxf(shB.w,0.f)};
    float bv[8]={fmaxf(hA.x,0.f),fmaxf(hA.y,0.f),fmaxf(hA.z,0.f),fmaxf(hA.w,0.f),
                 fmaxf(hB.x,0.f),fmaxf(hB.y,0.f),fmaxf(hB.z,0.f),fmaxf(hB.w,0.f)};
    float r[8]={0,0,0,0,0,0,0,0};
    #pragma unroll
    for(int i=0;i<8;i++){
      int col=d0+i;
      r[0]+=sv[i]*w[OW_AW+col];
      r[1]+=sv[i]*w[OW_CW+col*3+0];
      r[2]+=sv[i]*w[OW_CW+col*3+1];
      r[3]+=sv[i]*w[OW_CW+col*3+2];
      r[4]+=bv[i]*w[OW_BAW+col];
      r[5]+=bv[i]*w[OW_XW+col*3+0];
      r[6]+=bv[i]*w[OW_XW+col*3+1];
      r[7]+=bv[i]*w[OW_XW+col*3+2];
    }
    #pragma unroll
    for(int m=1;m<16;m<<=1){
      #pragma unroll
      for(int t=0;t<8;t++) r[t]+=__shfl_xor(r[t],m,64);
    }
    if(l==0){
      float dchi=r[0]+w[OW_AB];
      for(int k=0;k<4;k++)
        stout(out,(long)k*N_+n, wrapf(ldin(old_chi,(long)k*N_+n,f32)+dchi), f32);
      float dphi=r[4]+w[OW_BAB];
      stout(out,(long)4*N_+n, wrapf(ldin(old_phi,n,f32)+dphi), f32);
      stout(out,(long)5*N_+n, wrapf(ldin(old_psi,n,f32)+dphi), f32);
      for(int t=0;t<3;t++){
        stout(out,(long)6*N_+(long)n*3+t, ldin(old_cb,(long)n*3+t,f32)+r[1+t]+w[OW_CB+t], f32);
        stout(out,(long)9*N_+(long)n*3+t, ldin(old_ca,(long)n*3+t,f32)+r[5+t]+w[OW_XB+t], f32);
      }
    }
  }
}

// ---------- host ----------
extern "C" void kernel_launch(void* const* d_in, const int* in_sizes, int n_in,
                              void* d_out, int out_size, void* d_ws, size_t ws_size,
                              hipStream_t stream) {
  (void)in_sizes; (void)n_in; (void)out_size; (void)ws_size;

  char* p=(char*)d_ws;
  auto alloc=[&](size_t bytes)->void*{ void* r=(void*)p; p+=((bytes+255)&~(size_t)255); return r; };
  int*   flag   =(int*)  alloc(16);
  float* warena =(float*)alloc((size_t)OW_TOT*4);
  float* dv     =(float*)alloc(1024*4);
  float* dvf    =(float*)alloc(1024*4);
  float* P      =(float*)alloc((size_t)441*128*4);
  float* sp     =(float*)alloc(441*4);
  float* qp     =(float*)alloc(441*4);
  float* hat_h  =(float*)alloc((size_t)N_*128*4);
  float* hbuf   =(float*)alloc((size_t)N_*128*4);
  float* bufX   =(float*)alloc((size_t)N_*128*4);
  unsigned short* bufXb=(unsigned short*)alloc((size_t)N_*128*2);
  unsigned short* bufMb=(unsigned short*)alloc((size_t)N_*128*2);
  float* xn_sc  =(float*)alloc((size_t)N_*32*4);
  float* xn_bb  =(float*)alloc((size_t)N_*64*4);
  float* we     =(float*)alloc((size_t)ESC*4);
  float* we_csr =(float*)alloc((size_t)ESC*4);
  float* an     =(float*)alloc((size_t)N_*4);
  float* bn     =(float*)alloc((size_t)N_*4);
  float* dis    =(float*)alloc((size_t)N_*4);
  float* disb   =(float*)alloc((size_t)N_*4);
  int* rp_sc    =(int*)  alloc((size_t)(N_+1)*4);
  int* rp_bb    =(int*)  alloc((size_t)(N_+1)*4);
  int*  key1_sc =(int*)  alloc((size_t)ESC*4);
  int2* pay1_sc =(int2*) alloc((size_t)ESC*8);
  int*  dstS_sc =(int*)  alloc((size_t)ESC*4);
  int2* csr_se_sc=(int2*)alloc((size_t)ESC*8);
  int*  key1_bb =(int*)  alloc((size_t)EBB*4);
  int2* pay1_bb =(int2*) alloc((size_t)EBB*8);
  int*  dstS_bb =(int*)  alloc((size_t)EBB*4);
  int2* csr_se_bb=(int2*)alloc((size_t)EBB*8);
  int*  hist    =(int*)  alloc((size_t)(RBS+RBB)*256*4);
  int*  tot     =(int*)  alloc(512*4);
  int*  dbase   =(int*)  alloc(512*4);
  unsigned short* wfg_hi =(unsigned short*)alloc(2048*8*2);
  unsigned short* wfg_lo =(unsigned short*)alloc(2048*8*2);
  unsigned short* wfbg_hi=(unsigned short*)alloc(2048*8*2);
  unsigned short* wfi2_hi=(unsigned short*)alloc(2048*8*2);
  unsigned short* wfi1_hi=(unsigned short*)alloc(4096*8*2);
  unsigned short* wfsc_hi=(unsigned short*)alloc(512*8*2);
  unsigned short* wfsc_lo=(unsigned short*)alloc(512*8*2);
  unsigned short* wfbb_hi=(unsigned short*)alloc(1024*8*2);
  unsigned short* wfbb_lo=(unsigned short*)alloc(1024*8*2);

  const int* src_sc=(const int*)d_in[48];
  const int* dst_sc=src_sc+ESC;
  const int* src_bb=(const int*)d_in[49];
  const int* dst_bb=src_bb+EBB;

  k_detect<<<1,1,0,stream>>>(d_in[0], flag);

  CvtArgs ca;
  {
    int map[29]={14,15,16,17,18,19,20,21,22,23,24,25,30,31,32,33,34,35,36,37,
                 38,39,40,41,42,43,44,45,13};
    for(int i=0;i<29;i++) ca.src[i]=d_in[map[i]];
  }
  k_cvtw<<<(OW_TOT+255)/256,256,0,stream>>>(ca, flag, warena);

  // mega prep: wprep | prevec | preP | LN
  k_prep<<<PB_LN,256,0,stream>>>(warena, flag,
      wfg_hi,wfg_lo, wfbg_hi, wfi2_hi, wfi1_hi,
      wfsc_hi,wfsc_lo, wfbb_hi,wfbb_lo,
      d_in[26], d_in[27], d_in[28], d_in[29], dv, dvf, P, sp, qp,
      d_in[0], d_in[1], d_in[2], d_in[3], d_in[4], d_in[5], xn_sc, xn_bb);

  // stable radix CSR build (parallel scan)
  k_rhist<<<RBS+RBB,256,0,stream>>>(dst_sc, dst_bb, 0, hist);
  k_rscanA<<<512,256,0,stream>>>(hist, tot);
  k_rscanB<<<1,256,0,stream>>>(tot, dbase);
  k_rscat<<<RBS+RBB,256,0,stream>>>(0, 1, dst_sc, src_sc, (const int2*)nullptr,
                                    dst_bb, src_bb, (const int2*)nullptr, hist, dbase,
                                    key1_sc, pay1_sc, key1_bb, pay1_bb);
  k_rhist<<<RBS+RBB,256,0,stream>>>(key1_sc, key1_bb, 8, hist);
  k_rscanA<<<512,256,0,stream>>>(hist, tot);
  k_rscanB<<<1,256,0,stream>>>(tot, dbase);
  k_rscat<<<RBS+RBB,256,0,stream>>>(8, 0, key1_sc, (const int*)nullptr, pay1_sc,
                                    key1_bb, (const int*)nullptr, pay1_bb, hist, dbase,
                                    dstS_sc, csr_se_sc, dstS_bb, csr_se_bb);
  k_bounds<<<(int)(((long)ESC+1+EBB+1+255)/256),256,0,stream>>>(dstS_sc, dstS_bb, rp_sc, rp_bb);
  k_degb<<<(N_+255)/256,256,0,stream>>>(rp_bb, disb);

  // featurizer GEMMs (merged)
  const int GB = (N_+63)/64;
  k_mfeat<<<2*GB,256,0,stream>>>(xn_sc, xn_bb, wfsc_hi, wfsc_lo, wfbb_hi, wfbb_lo,
                                 warena, hat_h, hbuf, N_);

  // edge MLP (16-lane groups, 4 edges/group, coalesced P)
  k_w0<<<WBG,256,0,stream>>>(d_in[6],d_in[7],(const int*)d_in[46],(const int*)d_in[47],
                             flag,dvf,P,sp,qp,we);

  // sidechain layers (GEMM || degree merged; dis[src] inlined in agg)
  const int DB = (N_+255)/256;
  for(int l=0;l<3;l++){
    k_gemmdeg<<<GB+DB,256,0,stream>>>(hat_h, wfg_hi, wfg_lo, bufX, N_,
                                      rp_sc, csr_se_sc, we, an, bn, dv, we_csr, dis, l);
    k_agg_sc<<<N_/4,256,0,stream>>>(rp_sc,csr_se_sc,we_csr,dis,bufX,warena,hat_h,dv,an,bn,(l<2)?1:0);
  }

  // backbone layers (fused GEMM trio + agg; heads fused into last agg only)
  k_mbb<<<GB,256,0,stream>>>(hbuf, hat_h, wfi1_hi, wfbg_hi, wfi2_hi,
                             warena+OW_IB1, warena+OW_IB2, bufXb, bufMb, N_);
  k_agg_bb<<<N_/4,256,0,stream>>>(rp_bb,csr_se_bb,disb,bufXb,bufMb,warena,hbuf);
  k_mbb<<<GB,256,0,stream>>>(hbuf, hat_h, wfi1_hi, wfbg_hi, wfi2_hi,
                             warena+OW_IB1, warena+OW_IB2, bufXb, bufMb, N_);
  k_agg_bbh<<<N_/4,256,0,stream>>>(rp_bb,csr_se_bb,disb,bufXb,bufMb,warena,hbuf,
                                   hat_h, d_in[8],d_in[9],d_in[10],d_in[11],d_in[12],
                                   flag, d_out);
}

// Round 19
// 547.580 us; speedup vs baseline: 1.2630x; 1.0141x over previous
//
#include <hip/hip_runtime.h>
#include <stdint.h>

#define DEVI __device__ __forceinline__

constexpr int N_   = 50000;
constexpr int ESC  = 600000;
constexpr int EBB  = 100000;
constexpr int NRES = 21;
constexpr float PI_F = 3.14159f;

// radix geometry
constexpr int RCH = 2048;
constexpr int RBS = (ESC + RCH - 1)/RCH;  // 293
constexpr int RBB = (EBB + RCH - 1)/RCH;  // 49

typedef __attribute__((ext_vector_type(8))) short short8v;
typedef __attribute__((ext_vector_type(4))) float f32x4;

// ---------- dtype helpers ----------
DEVI float bf2f(unsigned short u){ return __uint_as_float(((unsigned)u)<<16); }
DEVI unsigned short f2bf(float f){
  unsigned x = __float_as_uint(f);
  unsigned r = (x + 0x7FFFu + ((x>>16)&1u))>>16;
  return (unsigned short)r;
}
DEVI float ldin(const void* p, long i, int f32){
  return f32 ? ((const float*)p)[i] : bf2f(((const unsigned short*)p)[i]);
}
DEVI void stout(void* p, long i, float v, int f32){
  if(f32) ((float*)p)[i]=v; else ((unsigned short*)p)[i]=f2bf(v);
}
DEVI float wrapf(float a){
  float t = a + PI_F;
  const float TP = 2.f*PI_F;
  t -= floorf(t/TP)*TP;
  return t - PI_F;
}

// ---------- weight arena offsets ----------
constexpr int OW_SC_LN_G=0;
constexpr int OW_SC_LN_B=OW_SC_LN_G+19;
constexpr int OW_SC_W  = OW_SC_LN_B+19;
constexpr int OW_SC_B  = OW_SC_W+19*128;
constexpr int OW_BB_LN_G=OW_SC_B+128;
constexpr int OW_BB_LN_B=OW_BB_LN_G+38;
constexpr int OW_BB_W = OW_BB_LN_B+38;
constexpr int OW_BB_B = OW_BB_W+38*128;
constexpr int OW_E_LN_G=OW_BB_B+128;
constexpr int OW_E_LN_B=OW_E_LN_G+66;
constexpr int OW_EW1 = OW_E_LN_B+66;
constexpr int OW_EB1 = OW_EW1+66*128;
constexpr int OW_GW  = OW_EB1+128;
constexpr int OW_GB  = OW_GW+128*128;
constexpr int OW_BGW = OW_GB+128;
constexpr int OW_BGB = OW_BGW+128*128;
constexpr int OW_IW1 = OW_BGB+128;
constexpr int OW_IB1 = OW_IW1+256*128;
constexpr int OW_IW2 = OW_IB1+128;
constexpr int OW_IB2 = OW_IW2+128*128;
constexpr int OW_AW  = OW_IB2+128;
constexpr int OW_AB  = OW_AW+128;
constexpr int OW_BAW = OW_AB+1;
constexpr int OW_BAB = OW_BAW+128;
constexpr int OW_CW  = OW_BAB+1;
constexpr int OW_CB  = OW_CW+128*3;
constexpr int OW_XW  = OW_CB+3;
constexpr int OW_XB  = OW_XW+128*3;
constexpr int OW_RES = OW_XB+3;
constexpr int OW_TOT = OW_RES+21*32;

// ---------- basic kernels ----------
__global__ void k_detect(const void* vcom, int* flag){
  const unsigned short* u = (const unsigned short*)vcom;
  int insane=0;
  for(int i=0;i<64;i+=2){
    float f = bf2f(u[i]);
    float a = fabsf(f);
    if(!(a<1e5f) || (a!=0.0f && a<1e-5f)) insane++;
  }
  *flag = (insane>=8)?1:0;
}

struct CvtArgs { const void* src[29]; };

__global__ void k_cvtw(CvtArgs a, const int* flag, float* w){
  static constexpr int offs[30] = {
    OW_SC_LN_G,OW_SC_LN_B,OW_SC_W,OW_SC_B,OW_BB_LN_G,OW_BB_LN_B,OW_BB_W,OW_BB_B,
    OW_E_LN_G,OW_E_LN_B,OW_EW1,OW_EB1,OW_GW,OW_GB,OW_BGW,OW_BGB,OW_IW1,OW_IB1,
    OW_IW2,OW_IB2,OW_AW,OW_AB,OW_BAW,OW_BAB,OW_CW,OW_CB,OW_XW,OW_XB,OW_RES,OW_TOT};
  int f32=*flag;
  for(int t=blockIdx.x*blockDim.x+threadIdx.x; t<OW_TOT; t+=gridDim.x*blockDim.x){
    int s=0;
    while(t>=offs[s+1]) s++;
    w[t]=ldin(a.src[s], t-offs[s], f32);
  }
}

// W[K x 128] -> MFMA fragment order (zero-padded past Kreal), split hi/lo bf16.
DEVI void wprep_pad(const float* W, int Kreal, unsigned short* hi, unsigned short* lo, int idx){
  int lane=idx&63, nt=(idx>>6)&7, kt=idx>>9;
  int n = nt*16 + (lane&15);
  int kbase = kt*32 + (lane>>4)*8;
  #pragma unroll
  for(int i=0;i<8;i++){
    int k=kbase+i;
    float v = (k<Kreal) ? W[(long)k*128 + n] : 0.f;
    unsigned short h = f2bf(v);
    hi[(long)idx*8+i]=h;
    if(lo){ float r = v - bf2f(h); lo[(long)idx*8+i]=f2bf(r); }
  }
}

// ---------- mega prep kernel: wprep | prevec | preP | LN ----------
constexpr int PB_WP = 46;
constexpr int PB_PV = PB_WP+1;
constexpr int PB_PP = PB_PV+441;
constexpr int PB_LN = PB_PP + (2*N_+3)/4;

__global__ void k_prep(const float* w, const int* flag,
    unsigned short* g_hi, unsigned short* g_lo,
    unsigned short* bg_hi,
    unsigned short* i2_hi,
    unsigned short* i1_hi,
    unsigned short* sc_hi, unsigned short* sc_lo,
    unsigned short* bb_hi, unsigned short* bb_lo,
    const void* eW2, const void* eb2, const void* euW, const void* eub,
    float* dv, float* dvf, float* P, float* sp, float* qp,
    const void* vcom, const void* sbfchi,
    const void* xca, const void* vcb, const void* sphi, const void* spsi,
    float* xn_sc, float* xn_bb){
  __shared__ float pv[64];
  int b=blockIdx.x;
  if(b<PB_WP){
    int idx=b*256+threadIdx.x;
    if(idx<2048)       wprep_pad(w+OW_GW,  128, g_hi,  g_lo,  idx);
    else if(idx<4096)  wprep_pad(w+OW_BGW, 128, bg_hi, nullptr, idx-2048);
    else if(idx<6144)  wprep_pad(w+OW_IW2, 128, i2_hi, nullptr, idx-4096);
    else if(idx<10240) wprep_pad(w+OW_IW1, 256, i1_hi, nullptr, idx-6144);
    else if(idx<10752) wprep_pad(w+OW_SC_W, 19, sc_hi, sc_lo, idx-10240);
    else if(idx<11776) wprep_pad(w+OW_BB_W, 38, bb_hi, bb_lo, idx-10752);
  } else if(b<PB_PV){
    int j=threadIdx.x; int f32=*flag;
    if(j<128){
      const float* g=w+OW_E_LN_G; const float* bb=w+OW_E_LN_B; const float* W1=w+OW_EW1;
      float A=g[0]*W1[j], C=g[1]*W1[128+j];
      float G=0,B=0;
      for(int i=0;i<66;i++){ float wij=W1[i*128+j]; G+=g[i]*wij; B+=bb[i]*wij; }
      B += w[OW_EB1+j];
      float v2=0; for(int k=0;k<128;k++) v2+=ldin(eW2,(long)j*128+k,f32);
      float us=0,ud=0;
      for(int k=0;k<128;k++){ us+=ldin(euW,(long)j*128+k,f32); ud+=ldin(euW,(long)(128+j)*128+k,f32); }
      dv[640+j]=us*(1.f/128.f); dv[768+j]=ud*(1.f/128.f);
      dvf[j]=A; dvf[128+j]=C; dvf[256+j]=G; dvf[384+j]=B; dvf[512+j]=v2*(1.f/128.f);
      if(j==0){
        float s=0,t=0;
        for(int k=0;k<128;k++){ s+=ldin(eb2,k,f32); t+=ldin(eub,k,f32); }
        dv[896]=s*(1.f/128.f); dv[897]=t*(1.f/128.f);
        dvf[640]=s*(1.f/128.f);
      }
    }
  } else if(b<PB_PP){
    int c=b-PB_PV, j=threadIdx.x;
    const float* res=w+OW_RES;
    if(j<32) pv[j]=res[(c/NRES)*32+j];
    else if(j<64) pv[j]=res[(c%NRES)*32+(j-32)];
    __syncthreads();
    if(j<128){
      const float* g=w+OW_E_LN_G; const float* W1=w+OW_EW1;
      float s=0;
      for(int i=0;i<64;i++) s += pv[i]*g[2+i]*W1[(2+i)*128+j];
      P[c*128+j]=s;
      if(j==0){ float a=0,q=0; for(int i=0;i<64;i++){a+=pv[i]; q+=pv[i]*pv[i];} sp[c]=a; qp[c]=q; }
    }
  } else {
    int wv=threadIdx.x>>6, lane=threadIdx.x&63;
    long gw=(long)(b-PB_PP)*4+wv;
    int f32=*flag;
    if(gw<N_){
      int n=(int)gw;
      float x=0.f;
      if(lane<3) x=ldin(vcom,(long)n*3+lane,f32);
      else if(lane<19) x=ldin(sbfchi,(long)n*16+(lane-3),f32);
      float s=x, q=x*x;
      for(int m=1;m<64;m<<=1){ s+=__shfl_xor(s,m,64); q+=__shfl_xor(q,m,64); }
      float mean=s*(1.f/19.f);
      float istd=rsqrtf(fmaxf(q*(1.f/19.f)-mean*mean,0.f)+1e-5f);
      if(lane<32){
        float xn=(lane<19)? (x-mean)*istd*w[OW_SC_LN_G+lane]+w[OW_SC_LN_B+lane] : 0.f;
        xn_sc[(long)n*32+lane]=xn;
      }
    } else if(gw<2L*N_){
      int n=(int)(gw-N_);
      float x=0.f;
      if(lane<3) x=ldin(xca,(long)n*3+lane,f32);
      else if(lane<6) x=ldin(vcb,(long)n*3+(lane-3),f32);
      else if(lane<22) x=ldin(sphi,(long)n*16+(lane-6),f32);
      else if(lane<38) x=ldin(spsi,(long)n*16+(lane-22),f32);
      float s=x, q=x*x;
      for(int m=1;m<64;m<<=1){ s+=__shfl_xor(s,m,64); q+=__shfl_xor(q,m,64); }
      float mean=s*(1.f/38.f);
      float istd=rsqrtf(fmaxf(q*(1.f/38.f)-mean*mean,0.f)+1e-5f);
      float xn=(lane<38)? (x-mean)*istd*w[OW_BB_LN_G+lane]+w[OW_BB_LN_B+lane] : 0.f;
      xn_bb[(long)n*64+lane]=xn;
    }
  }
}

// ---------- stable 2-pass radix CSR build (RCH=2048, parallel scan) ----------
__global__ void k_rhist(const int* key_sc, const int* key_bb, int shift, int* hist){
  __shared__ int h[256];
  h[threadIdx.x]=0; __syncthreads();
  int g = blockIdx.x>=RBS;
  const int* key = g? key_bb : key_sc;
  int E = g? EBB : ESC;
  int b = g? blockIdx.x-RBS : blockIdx.x;
  int base=b*RCH;
  for(int r=0;r<RCH/256;r++){
    int idx=base+r*256+threadIdx.x;
    if(idx<E) atomicAdd(&h[(key[idx]>>shift)&255],1);
  }
  __syncthreads();
  hist[(long)blockIdx.x*256+threadIdx.x]=h[threadIdx.x];
}
__global__ void k_rscanA(int* hist, int* tot){
  __shared__ int sA[512], sB[512];
  int g = blockIdx.x>=256;
  int d = blockIdx.x&255;
  int NB = g? RBB : RBS;
  int* H = hist + (g? (long)RBS*256 : 0);
  int t=threadIdx.x;
  int i0=t, i1=t+256;
  int o0 = (i0<NB)? H[(long)i0*256+d] : 0;
  int o1 = (i1<NB)? H[(long)i1*256+d] : 0;
  sA[i0]=o0; sA[i1]=o1;
  __syncthreads();
  int* a=sA; int* b=sB;
  for(int off=1; off<512; off<<=1){
    b[i0] = a[i0] + ((i0>=off)? a[i0-off]:0);
    b[i1] = a[i1] + ((i1>=off)? a[i1-off]:0);
    __syncthreads();
    int* tmp=a; a=b; b=tmp;
  }
  if(i0<NB) H[(long)i0*256+d] = a[i0]-o0;
  if(i1<NB) H[(long)i1*256+d] = a[i1]-o1;
  if(t==255) tot[(g?256:0)+d] = a[511];
}
__global__ void k_rscanB(const int* tot, int* base){
  __shared__ int sA[256], sB[256];
  int t=threadIdx.x;
  for(int g=0;g<2;g++){
    int o=tot[g*256+t];
    sA[t]=o; __syncthreads();
    int* a=sA; int* b=sB;
    for(int off=1; off<256; off<<=1){
      b[t] = a[t] + ((t>=off)? a[t-off]:0);
      __syncthreads();
      int* tmp=a; a=b; b=tmp;
    }
    base[g*256+t] = a[t]-o;
    __syncthreads();
  }
}
__global__ void k_rscat(int shift, int first,
    const int* kin_sc, const int* srcv_sc, const int2* pin_sc,
    const int* kin_bb, const int* srcv_bb, const int2* pin_bb,
    const int* hist, const int* dbase,
    int* kout_sc, int2* pout_sc, int* kout_bb, int2* pout_bb){
  __shared__ int running[256];
  __shared__ int Hb[256];
  __shared__ int whist[4][256];
  __shared__ int pw[4][256];
  int tid=threadIdx.x, lane=tid&63, w=tid>>6;
  int g = blockIdx.x>=RBS;
  const int* kin  = g? kin_bb : kin_sc;
  const int* srcv = g? srcv_bb: srcv_sc;
  const int2* pin = g? pin_bb : pin_sc;
  int* kout  = g? kout_bb : kout_sc;
  int2* pout = g? pout_bb : pout_sc;
  int E = g? EBB : ESC;
  int b = g? blockIdx.x-RBS : blockIdx.x;
  running[tid]=0;
  Hb[tid]=hist[(long)blockIdx.x*256+tid] + dbase[(g?256:0)+tid];
  int base=b*RCH;
  for(int r=0;r<RCH/256;r++){
    __syncthreads();
    whist[0][tid]=0; whist[1][tid]=0; whist[2][tid]=0; whist[3][tid]=0;
    __syncthreads();
    int idx=base+r*256+tid;
    bool valid = idx<E;
    int key=0, digit=0; int2 pay; pay.x=0; pay.y=0;
    if(valid){
      key=kin[idx];
      digit=(key>>shift)&255;
      if(first){ pay.x=srcv[idx]; pay.y=idx; }
      else pay=pin[idx];
    }
    unsigned long long act=__ballot(valid);
    unsigned long long same=act;
    #pragma unroll
    for(int k=0;k<8;k++){
      unsigned long long m=__ballot(valid && ((digit>>k)&1));
      same &= ((digit>>k)&1)? m : ~m;
    }
    same &= act;
    unsigned long long below=(1ULL<<lane)-1ULL;
    int wrank=__popcll(same & below);
    if(valid && wrank==0) whist[w][digit]=__popcll(same);
    __syncthreads();
    int c0=whist[0][tid], c1=whist[1][tid], c2=whist[2][tid], c3=whist[3][tid];
    pw[0][tid]=0; pw[1][tid]=c0; pw[2][tid]=c0+c1; pw[3][tid]=c0+c1+c2;
    __syncthreads();
    if(valid){
      int pos=Hb[digit]+running[digit]+pw[w][digit]+wrank;
      kout[pos]=key; pout[pos]=pay;
    }
    __syncthreads();
    running[tid]+=c0+c1+c2+c3;
  }
}
__global__ void k_bounds(const int* dstS_sc, const int* dstS_bb, int* rp_sc, int* rp_bb){
  long i=(long)blockIdx.x*blockDim.x+threadIdx.x;
  if(i<=ESC){
    int cur = (i<ESC)? dstS_sc[i] : N_;
    int prev= (i>0)? dstS_sc[i-1] : -1;
    for(int d=prev+1; d<=cur; d++) rp_sc[d]=(int)i;
  } else if(i <= (long)ESC+1+EBB){
    long j=i-(ESC+1);
    int cur = (j<EBB)? dstS_bb[j] : N_;
    int prev= (j>0)? dstS_bb[j-1] : -1;
    for(int d=prev+1; d<=cur; d++) rp_bb[d]=(int)j;
  }
}
__global__ void k_degb(const int* rp, float* disb){
  int n=blockIdx.x*blockDim.x+threadIdx.x;
  if(n<N_) disb[n]=rsqrtf(1.f+(float)(rp[n+1]-rp[n]));
}

// ---------- edge MLP: 16-lane groups, 4 edges/group, dvf cached in registers ----------
constexpr int WBG = (ESC + 63)/64;  // 9375
__global__ __launch_bounds__(256,4) void k_w0(const void* dsc, const void* dmin,
    const int* ri_, const int* rj_, const int* flag, const float* dvf,
    const float* P, const float* sp, const float* qp, float* we){
  int wv=threadIdx.x>>6, lane=threadIdx.x&63;
  int g=lane>>4, l=lane&15;
  long ebase=(long)blockIdx.x*64 + wv*16 + g*4;
  int f32=*flag;
  int j0=l*8;
  float4 A0=*(const float4*)&dvf[j0],     A1=*(const float4*)&dvf[j0+4];
  float4 C0=*(const float4*)&dvf[128+j0], C1=*(const float4*)&dvf[128+j0+4];
  float4 G0=*(const float4*)&dvf[256+j0], G1=*(const float4*)&dvf[256+j0+4];
  float4 B0=*(const float4*)&dvf[384+j0], B1=*(const float4*)&dvf[384+j0+4];
  float4 V0=*(const float4*)&dvf[512+j0], V1=*(const float4*)&dvf[512+j0+4];
  float eb2=dvf[640];
  #pragma unroll
  for(int k=0;k<4;k++){
    long e=ebase+k;
    bool val = e<ESC;
    long ee = val? e : 0;
    float d1=ldin(dsc,ee,f32), d2=ldin(dmin,ee,f32);
    int c=ri_[ee]*NRES+rj_[ee];
    float m=(d1+d2+sp[c])*(1.f/66.f);
    float ms=(d1*d1+d2*d2+qp[c])*(1.f/66.f);
    float istd=rsqrtf(fmaxf(ms-m*m,0.f)+1e-5f);
    float nmi=-m*istd;
    float4 P0=*(const float4*)&P[(long)c*128+j0];
    float4 P1=*(const float4*)&P[(long)c*128+j0+4];
    float acc=0.f, t, hid;
    t=fmaf(d1,A0.x,fmaf(d2,C0.x,P0.x)); hid=fmaf(istd,t,fmaf(nmi,G0.x,B0.x)); acc=fmaf(fmaxf(hid,0.f),V0.x,acc);
    t=fmaf(d1,A0.y,fmaf(d2,C0.y,P0.y)); hid=fmaf(istd,t,fmaf(nmi,G0.y,B0.y)); acc=fmaf(fmaxf(hid,0.f),V0.y,acc);
    t=fmaf(d1,A0.z,fmaf(d2,C0.z,P0.z)); hid=fmaf(istd,t,fmaf(nmi,G0.z,B0.z)); acc=fmaf(fmaxf(hid,0.f),V0.z,acc);
    t=fmaf(d1,A0.w,fmaf(d2,C0.w,P0.w)); hid=fmaf(istd,t,fmaf(nmi,G0.w,B0.w)); acc=fmaf(fmaxf(hid,0.f),V0.w,acc);
    t=fmaf(d1,A1.x,fmaf(d2,C1.x,P1.x)); hid=fmaf(istd,t,fmaf(nmi,G1.x,B1.x)); acc=fmaf(fmaxf(hid,0.f),V1.x,acc);
    t=fmaf(d1,A1.y,fmaf(d2,C1.y,P1.y)); hid=fmaf(istd,t,fmaf(nmi,G1.y,B1.y)); acc=fmaf(fmaxf(hid,0.f),V1.y,acc);
    t=fmaf(d1,A1.z,fmaf(d2,C1.z,P1.z)); hid=fmaf(istd,t,fmaf(nmi,G1.z,B1.z)); acc=fmaf(fmaxf(hid,0.f),V1.z,acc);
    t=fmaf(d1,A1.w,fmaf(d2,C1.w,P1.w)); hid=fmaf(istd,t,fmaf(nmi,G1.w,B1.w)); acc=fmaf(fmaxf(hid,0.f),V1.w,acc);
    #pragma unroll
    for(int msk=1;msk<16;msk<<=1) acc+=__shfl_xor(acc,msk,64);
    if(l==0 && val) we[e]=acc+eb2;
  }
}

// ---------- split-bf16 MFMA GEMM core ----------
DEVI f32x4 MFMA(short8v a, short8v b, f32x4 c){
  return __builtin_amdgcn_mfma_f32_16x16x32_bf16(a,b,c,0,0,0);
}
DEVI void cvt8(float4 a0, float4 a1, short8v& hi, short8v& lo){
  float av[8]={a0.x,a0.y,a0.z,a0.w,a1.x,a1.y,a1.z,a1.w};
  union{short8v v; unsigned short u[8];} H,L;
  #pragma unroll
  for(int i=0;i<8;i++){
    unsigned short h=f2bf(av[i]);
    float r=av[i]-bf2f(h);
    H.u[i]=h; L.u[i]=f2bf(r);
  }
  hi=H.v; lo=L.v;
}
DEVI short8v cvt8hi(float4 a0, float4 a1){
  union{short8v v; unsigned short u[8];} H;
  H.u[0]=f2bf(a0.x); H.u[1]=f2bf(a0.y); H.u[2]=f2bf(a0.z); H.u[3]=f2bf(a0.w);
  H.u[4]=f2bf(a1.x); H.u[5]=f2bf(a1.y); H.u[6]=f2bf(a1.z); H.u[7]=f2bf(a1.w);
  return H.v;
}

template<int KT, int LDA>
DEVI void mgemm_body(int bid, const float* A1, const float* A2,
    const unsigned short* Whi, const unsigned short* Wlo,
    const float* bias, float* C, int relu, int accum, int M){
  const int lane = threadIdx.x & 63;
  const int wid  = threadIdx.x >> 6;
  const int r0   = bid*64 + wid*16;
  const int mrow = lane & 15;
  const int kg   = lane >> 4;
  long arow = (long)min(r0 + mrow, M-1);
  f32x4 acc[8];
  #pragma unroll
  for(int t=0;t<8;t++) acc[t]=(f32x4){0.f,0.f,0.f,0.f};

  #pragma unroll
  for(int kt=0; kt<KT; kt++){
    const float* A = (KT==8 && kt>=4) ? A2 : A1;
    int kb = (kt&3)*32 + kg*8;
    float4 a0 = *(const float4*)&A[arow*LDA + kb];
    float4 a1 = *(const float4*)&A[arow*LDA + kb + 4];
    short8v ah, al; cvt8(a0,a1,ah,al);
    #pragma unroll
    for(int nt=0;nt<8;nt++){
      long off = (((long)kt*8+nt)*64 + lane)*8;
      short8v wh = *(const short8v*)&Whi[off];
      short8v wl = *(const short8v*)&Wlo[off];
      acc[nt] = MFMA(ah, wh, acc[nt]);
      acc[nt] = MFMA(al, wh, acc[nt]);
      acc[nt] = MFMA(ah, wl, acc[nt]);
      acc[nt] = MFMA(al, wl, acc[nt]);
    }
  }

  #pragma unroll
  for(int nt=0;nt<8;nt++){
    int col = nt*16 + mrow;
    float bj = bias ? bias[col] : 0.f;
    #pragma unroll
    for(int r=0;r<4;r++){
      int row = r0 + kg*4 + r;
      if(row >= M) continue;
      long idx = (long)row*128 + col;
      float v = acc[nt][r] + bj;
      if(relu) v = fmaxf(v,0.f);
      if(accum) v += C[idx];
      C[idx] = v;
    }
  }
}

// sc layer: gW GEMM overlapped with degree pass
__global__ __launch_bounds__(256,4) void k_gemmdeg(const float* hat_h,
    const unsigned short* Whi, const unsigned short* Wlo, float* C, int M,
    const int* rp, const int2* se, const float* we_edge,
    const float* an, const float* bn, const float* dv,
    float* we_csr, float* dis, int layer){
  int GBl=(M+63)/64;
  if((int)blockIdx.x < GBl){
    mgemm_body<4,128>(blockIdx.x, hat_h, nullptr, Whi, Wlo, nullptr, C, 0, 0, M);
  } else {
    int n=(blockIdx.x-GBl)*256+threadIdx.x;
    if(n>=N_) return;
    int e0=rp[n], e1=rp[n+1];
    float s=1.f;
    if(layer==0){
      for(int p=e0;p<e1;p++){ float ww=we_edge[se[p].y]; we_csr[p]=ww; s+=ww; }
    } else {
      float add_n = bn[n] + dv[897];
      for(int p=e0;p<e1;p++){
        float ww=we_csr[p] + an[se[p].x] + add_n;
        we_csr[p]=ww; s+=ww;
      }
    }
    dis[n]=rsqrtf(fmaxf(s,1e-6f));
  }
}

// featurizer: both small GEMMs in one launch
__global__ __launch_bounds__(256,4) void k_mfeat(const float* xn_sc, const float* xn_bb,
    const unsigned short* schi, const unsigned short* sclo,
    const unsigned short* bbhi, const unsigned short* bblo,
    const float* w, float* hat_h, float* hbuf, int M){
  int GBl=(M+63)/64;
  if((int)blockIdx.x < GBl)
    mgemm_body<1,32>(blockIdx.x, xn_sc, nullptr, schi, sclo, w+OW_SC_B, hat_h, 0,0,M);
  else
    mgemm_body<2,64>(blockIdx.x-GBl, xn_bb, nullptr, bbhi, bblo, w+OW_BB_B, hbuf, 0,0,M);
}

// fused bb layer (backbone branch is NOT chaotic -> plain bf16 suffices)
__global__ __launch_bounds__(256,4) void k_mbb(const float* h, const float* hh,
    const unsigned short* W1hi,
    const unsigned short* W2hi,
    const unsigned short* W3hi,
    const float* b1, const float* b2,
    unsigned short* xwout, unsigned short* mout, int M){
  __shared__ unsigned short hids[64*136];
  const int lane = threadIdx.x & 63;
  const int wid  = threadIdx.x >> 6;
  const int r0   = blockIdx.x*64 + wid*16;
  const int mrow = lane & 15;
  const int kg   = lane >> 4;
  long arow = (long)min(r0 + mrow, M-1);
  f32x4 acc1[8], acc2[8];
  #pragma unroll
  for(int t=0;t<8;t++){ acc1[t]=(f32x4){0,0,0,0}; acc2[t]=(f32x4){0,0,0,0}; }

  #pragma unroll
  for(int kt=0; kt<8; kt++){
    const float* A = (kt>=4) ? hh : h;
    int kb = (kt&3)*32 + kg*8;
    float4 a0 = *(const float4*)&A[arow*128 + kb];
    float4 a1 = *(const float4*)&A[arow*128 + kb + 4];
    short8v ah = cvt8hi(a0,a1);
    #pragma unroll
    for(int nt=0;nt<8;nt++){
      long off = (((long)kt*8+nt)*64 + lane)*8;
      acc1[nt] = MFMA(ah, *(const short8v*)&W1hi[off], acc1[nt]);
    }
    if(kt<4){
      #pragma unroll
      for(int nt=0;nt<8;nt++){
        long off = (((long)kt*8+nt)*64 + lane)*8;
        acc2[nt] = MFMA(ah, *(const short8v*)&W2hi[off], acc2[nt]);
      }
    }
  }

  #pragma unroll
  for(int nt=0;nt<8;nt++){
    int col = nt*16 + mrow;
    float bj = b1[col];
    #pragma unroll
    for(int r=0;r<4;r++){
      int rloc = wid*16 + kg*4 + r;
      int row = r0 + kg*4 + r;
      hids[rloc*136 + col] = f2bf(fmaxf(acc1[nt][r] + bj, 0.f));
      if(row < M) xwout[(long)row*128 + col] = f2bf(acc2[nt][r]);
    }
  }
  __syncthreads();

  f32x4 acc3[8];
  #pragma unroll
  for(int t=0;t<8;t++) acc3[t]=(f32x4){0,0,0,0};
  int rloc = wid*16 + mrow;
  #pragma unroll
  for(int kt=0; kt<4; kt++){
    int kb = kt*32 + kg*8;
    short8v ah = *(const short8v*)&hids[rloc*136 + kb];
    #pragma unroll
    for(int nt=0;nt<8;nt++){
      long off = (((long)kt*8+nt)*64 + lane)*8;
      acc3[nt] = MFMA(ah, *(const short8v*)&W3hi[off], acc3[nt]);
    }
  }
  #pragma unroll
  for(int nt=0;nt<8;nt++){
    int col = nt*16 + mrow;
    float bj = b2[col];
    #pragma unroll
    for(int r=0;r<4;r++){
      int row = r0 + kg*4 + r;
      if(row < M) mout[(long)row*128 + col] = f2bf(acc3[nt][r] + bj);
    }
  }
}

// ---------- aggregation: 16 lanes/edge, 2-edge unroll, inline dis[src] ----------
__global__ void k_agg_sc(const int* __restrict__ rp, const int2* __restrict__ se,
                         const float* __restrict__ wc, const float* __restrict__ dis,
                         const float* __restrict__ xw, const float* __restrict__ w,
                         float* __restrict__ hat_h, const float* __restrict__ dv,
                         float* __restrict__ an, float* __restrict__ bn, int withdot){
  int wv=threadIdx.x>>6, lane=threadIdx.x&63;
  int n=blockIdx.x*4+wv;
  int g=lane>>4, l=lane&15, d0=l*8;
  float disn=dis[n];
  float4 aA={0,0,0,0}, aB={0,0,0,0}, cA={0,0,0,0}, cB={0,0,0,0};
  int e0=rp[n], e1=rp[n+1];
  int p=e0+g;
  for(; p+4<e1; p+=8){
    int s0=se[p].x, s1=se[p+4].x;
    float nw0=dis[s0]*wc[p], nw1=dis[s1]*wc[p+4];
    float4 xa0=*(const float4*)&xw[(long)s0*128+d0];
    float4 xb0=*(const float4*)&xw[(long)s0*128+d0+4];
    float4 xa1=*(const float4*)&xw[(long)s1*128+d0];
    float4 xb1=*(const float4*)&xw[(long)s1*128+d0+4];
    aA.x+=nw0*xa0.x; aA.y+=nw0*xa0.y; aA.z+=nw0*xa0.z; aA.w+=nw0*xa0.w;
    aB.x+=nw0*xb0.x; aB.y+=nw0*xb0.y; aB.z+=nw0*xb0.z; aB.w+=nw0*xb0.w;
    cA.x+=nw1*xa1.x; cA.y+=nw1*xa1.y; cA.z+=nw1*xa1.z; cA.w+=nw1*xa1.w;
    cB.x+=nw1*xb1.x; cB.y+=nw1*xb1.y; cB.z+=nw1*xb1.z; cB.w+=nw1*xb1.w;
  }
  if(p<e1){
    int s0=se[p].x;
    float nw0=dis[s0]*wc[p];
    float4 xa0=*(const float4*)&xw[(long)s0*128+d0];
    float4 xb0=*(const float4*)&xw[(long)s0*128+d0+4];
    aA.x+=nw0*xa0.x; aA.y+=nw0*xa0.y; aA.z+=nw0*xa0.z; aA.w+=nw0*xa0.w;
    aB.x+=nw0*xb0.x; aB.y+=nw0*xb0.y; aB.z+=nw0*xb0.z; aB.w+=nw0*xb0.w;
  }
  aA.x+=cA.x; aA.y+=cA.y; aA.z+=cA.z; aA.w+=cA.w;
  aB.x+=cB.x; aB.y+=cB.y; aB.z+=cB.z; aB.w+=cB.w;
  #pragma unroll
  for(int m=16;m<64;m<<=1){
    aA.x+=__shfl_xor(aA.x,m,64); aA.y+=__shfl_xor(aA.y,m,64);
    aA.z+=__shfl_xor(aA.z,m,64); aA.w+=__shfl_xor(aA.w,m,64);
    aB.x+=__shfl_xor(aB.x,m,64); aB.y+=__shfl_xor(aB.y,m,64);
    aB.z+=__shfl_xor(aB.z,m,64); aB.w+=__shfl_xor(aB.w,m,64);
  }
  float d2=disn*disn;
  float4 xsA=*(const float4*)&xw[(long)n*128+d0];
  float4 xsB=*(const float4*)&xw[(long)n*128+d0+4];
  float4 gbA=*(const float4*)&w[OW_GB+d0];
  float4 gbB=*(const float4*)&w[OW_GB+d0+4];
  float4 hoA=*(const float4*)&hat_h[(long)n*128+d0];
  float4 hoB=*(const float4*)&hat_h[(long)n*128+d0+4];
  float4 hA, hB;
  hA.x=hoA.x+fmaxf(aA.x*disn+d2*xsA.x+gbA.x,0.f);
  hA.y=hoA.y+fmaxf(aA.y*disn+d2*xsA.y+gbA.y,0.f);
  hA.z=hoA.z+fmaxf(aA.z*disn+d2*xsA.z+gbA.z,0.f);
  hA.w=hoA.w+fmaxf(aA.w*disn+d2*xsA.w+gbA.w,0.f);
  hB.x=hoB.x+fmaxf(aB.x*disn+d2*xsB.x+gbB.x,0.f);
  hB.y=hoB.y+fmaxf(aB.y*disn+d2*xsB.y+gbB.y,0.f);
  hB.z=hoB.z+fmaxf(aB.z*disn+d2*xsB.z+gbB.z,0.f);
  hB.w=hoB.w+fmaxf(aB.w*disn+d2*xsB.w+gbB.w,0.f);
  if(g==0){
    *(float4*)&hat_h[(long)n*128+d0]=hA;
    *(float4*)&hat_h[(long)n*128+d0+4]=hB;
  }
  if(withdot){
    float4 usA=*(const float4*)&dv[640+d0], usB=*(const float4*)&dv[640+d0+4];
    float4 udA=*(const float4*)&dv[768+d0], udB=*(const float4*)&dv[768+d0+4];
    float a = hA.x*usA.x+hA.y*usA.y+hA.z*usA.z+hA.w*usA.w
            + hB.x*usB.x+hB.y*usB.y+hB.z*usB.z+hB.w*usB.w;
    float b = hA.x*udA.x+hA.y*udA.y+hA.z*udA.z+hA.w*udA.w
            + hB.x*udB.x+hB.y*udB.y+hB.z*udB.z+hB.w*udB.w;
    #pragma unroll
    for(int m=1;m<16;m<<=1){ a+=__shfl_xor(a,m,64); b+=__shfl_xor(b,m,64); }
    if(lane==0){ an[n]=a; bn[n]=b; }
  }
}

DEVI void bf8ld(const unsigned short* p, float4& lo, float4& hi){
  union{short8v v; unsigned short u[8];} t;
  t.v = *(const short8v*)p;
  lo.x=bf2f(t.u[0]); lo.y=bf2f(t.u[1]); lo.z=bf2f(t.u[2]); lo.w=bf2f(t.u[3]);
  hi.x=bf2f(t.u[4]); hi.y=bf2f(t.u[5]); hi.z=bf2f(t.u[6]); hi.w=bf2f(t.u[7]);
}

// plain bb aggregation (both layers) — lean signature
__global__ void k_agg_bb(const int* __restrict__ rp, const int2* __restrict__ se,
                         const float* __restrict__ disb,
                         const unsigned short* __restrict__ xw,
                         const unsigned short* __restrict__ mbuf,
                         const float* __restrict__ w, float* __restrict__ h){
  int wv=threadIdx.x>>6, lane=threadIdx.x&63;
  int n=blockIdx.x*4+wv;
  int g=lane>>4, l=lane&15, d0=l*8;
  int e0=rp[n], e1=rp[n+1];
  float disn=disb[n];
  float4 aA={0,0,0,0}, aB={0,0,0,0}, cA={0,0,0,0}, cB={0,0,0,0};
  int p=e0+g;
  for(; p+4<e1; p+=8){
    int s0=se[p].x, s1=se[p+4].x;
    float nw0=disb[s0], nw1=disb[s1];
    float4 xa0,xb0,xa1,xb1;
    bf8ld(&xw[(long)s0*128+d0], xa0, xb0);
    bf8ld(&xw[(long)s1*128+d0], xa1, xb1);
    aA.x+=nw0*xa0.x; aA.y+=nw0*xa0.y; aA.z+=nw0*xa0.z; aA.w+=nw0*xa0.w;
    aB.x+=nw0*xb0.x; aB.y+=nw0*xb0.y; aB.z+=nw0*xb0.z; aB.w+=nw0*xb0.w;
    cA.x+=nw1*xa1.x; cA.y+=nw1*xa1.y; cA.z+=nw1*xa1.z; cA.w+=nw1*xa1.w;
    cB.x+=nw1*xb1.x; cB.y+=nw1*xb1.y; cB.z+=nw1*xb1.z; cB.w+=nw1*xb1.w;
  }
  if(p<e1){
    int s0=se[p].x;
    float nw0=disb[s0];
    float4 xa0,xb0;
    bf8ld(&xw[(long)s0*128+d0], xa0, xb0);
    aA.x+=nw0*xa0.x; aA.y+=nw0*xa0.y; aA.z+=nw0*xa0.z; aA.w+=nw0*xa0.w;
    aB.x+=nw0*xb0.x; aB.y+=nw0*xb0.y; aB.z+=nw0*xb0.z; aB.w+=nw0*xb0.w;
  }
  aA.x+=cA.x; aA.y+=cA.y; aA.z+=cA.z; aA.w+=cA.w;
  aB.x+=cB.x; aB.y+=cB.y; aB.z+=cB.z; aB.w+=cB.w;
  #pragma unroll
  for(int m=16;m<64;m<<=1){
    aA.x+=__shfl_xor(aA.x,m,64); aA.y+=__shfl_xor(aA.y,m,64);
    aA.z+=__shfl_xor(aA.z,m,64); aA.w+=__shfl_xor(aA.w,m,64);
    aB.x+=__shfl_xor(aB.x,m,64); aB.y+=__shfl_xor(aB.y,m,64);
    aB.z+=__shfl_xor(aB.z,m,64); aB.w+=__shfl_xor(aB.w,m,64);
  }
  if(g==0){
    float d2=disn*disn;
    float4 xsA,xsB,mA,mB;
    bf8ld(&xw[(long)n*128+d0], xsA, xsB);
    bf8ld(&mbuf[(long)n*128+d0], mA, mB);
    float4 gbA=*(const float4*)&w[OW_BGB+d0];
    float4 gbB=*(const float4*)&w[OW_BGB+d0+4];
    float4 hA=*(float4*)&h[(long)n*128+d0];
    float4 hB=*(float4*)&h[(long)n*128+d0+4];
    hA.x+=fmaxf(aA.x*disn+d2*xsA.x+gbA.x,0.f)+mA.x;
    hA.y+=fmaxf(aA.y*disn+d2*xsA.y+gbA.y,0.f)+mA.y;
    hA.z+=fmaxf(aA.z*disn+d2*xsA.z+gbA.z,0.f)+mA.z;
    hA.w+=fmaxf(aA.w*disn+d2*xsA.w+gbA.w,0.f)+mA.w;
    hB.x+=fmaxf(aB.x*disn+d2*xsB.x+gbB.x,0.f)+mB.x;
    hB.y+=fmaxf(aB.y*disn+d2*xsB.y+gbB.y,0.f)+mB.y;
    hB.z+=fmaxf(aB.z*disn+d2*xsB.z+gbB.z,0.f)+mB.z;
    hB.w+=fmaxf(aB.w*disn+d2*xsB.w+gbB.w,0.f)+mB.w;
    *(float4*)&h[(long)n*128+d0]=hA;
    *(float4*)&h[(long)n*128+d0+4]=hB;
  }
}

// standalone output heads (round-16 proven)
__global__ void k_heads(const float* hat_h, const float* h, const float* w,
                        const void* old_chi, const void* old_phi, const void* old_psi,
                        const void* old_cb, const void* old_ca, const int* flag, void* out){
  int wv=threadIdx.x>>6, lane=threadIdx.x&63;
  int n=blockIdx.x*4+wv;
  int f32=*flag;
  float s0=fmaxf(hat_h[(long)n*128+lane],0.f), s1=fmaxf(hat_h[(long)n*128+64+lane],0.f);
  float b0=fmaxf(h[(long)n*128+lane],0.f),    b1=fmaxf(h[(long)n*128+64+lane],0.f);
  float r[8];
  r[0]=s0*w[OW_AW+lane]+s1*w[OW_AW+64+lane];
  r[1]=s0*w[OW_CW+lane*3+0]+s1*w[OW_CW+(64+lane)*3+0];
  r[2]=s0*w[OW_CW+lane*3+1]+s1*w[OW_CW+(64+lane)*3+1];
  r[3]=s0*w[OW_CW+lane*3+2]+s1*w[OW_CW+(64+lane)*3+2];
  r[4]=b0*w[OW_BAW+lane]+b1*w[OW_BAW+64+lane];
  r[5]=b0*w[OW_XW+lane*3+0]+b1*w[OW_XW+(64+lane)*3+0];
  r[6]=b0*w[OW_XW+lane*3+1]+b1*w[OW_XW+(64+lane)*3+1];
  r[7]=b0*w[OW_XW+lane*3+2]+b1*w[OW_XW+(64+lane)*3+2];
  for(int m=1;m<64;m<<=1){
    #pragma unroll
    for(int t=0;t<8;t++) r[t]+=__shfl_xor(r[t],m,64);
  }
  if(lane==0){
    float dchi=r[0]+w[OW_AB];
    for(int k=0;k<4;k++)
      stout(out,(long)k*N_+n, wrapf(ldin(old_chi,(long)k*N_+n,f32)+dchi), f32);
    float dphi=r[4]+w[OW_BAB];
    stout(out,(long)4*N_+n, wrapf(ldin(old_phi,n,f32)+dphi), f32);
    stout(out,(long)5*N_+n, wrapf(ldin(old_psi,n,f32)+dphi), f32);
    for(int t=0;t<3;t++){
      stout(out,(long)6*N_+(long)n*3+t, ldin(old_cb,(long)n*3+t,f32)+r[1+t]+w[OW_CB+t], f32);
      stout(out,(long)9*N_+(long)n*3+t, ldin(old_ca,(long)n*3+t,f32)+r[5+t]+w[OW_XB+t], f32);
    }
  }
}

// ---------- host ----------
extern "C" void kernel_launch(void* const* d_in, const int* in_sizes, int n_in,
                              void* d_out, int out_size, void* d_ws, size_t ws_size,
                              hipStream_t stream) {
  (void)in_sizes; (void)n_in; (void)out_size; (void)ws_size;

  char* p=(char*)d_ws;
  auto alloc=[&](size_t bytes)->void*{ void* r=(void*)p; p+=((bytes+255)&~(size_t)255); return r; };
  int*   flag   =(int*)  alloc(16);
  float* warena =(float*)alloc((size_t)OW_TOT*4);
  float* dv     =(float*)alloc(1024*4);
  float* dvf    =(float*)alloc(1024*4);
  float* P      =(float*)alloc((size_t)441*128*4);
  float* sp     =(float*)alloc(441*4);
  float* qp     =(float*)alloc(441*4);
  float* hat_h  =(float*)alloc((size_t)N_*128*4);
  float* hbuf   =(float*)alloc((size_t)N_*128*4);
  float* bufX   =(float*)alloc((size_t)N_*128*4);
  unsigned short* bufXb=(unsigned short*)alloc((size_t)N_*128*2);
  unsigned short* bufMb=(unsigned short*)alloc((size_t)N_*128*2);
  float* xn_sc  =(float*)alloc((size_t)N_*32*4);
  float* xn_bb  =(float*)alloc((size_t)N_*64*4);
  float* we     =(float*)alloc((size_t)ESC*4);
  float* we_csr =(float*)alloc((size_t)ESC*4);
  float* an     =(float*)alloc((size_t)N_*4);
  float* bn     =(float*)alloc((size_t)N_*4);
  float* dis    =(float*)alloc((size_t)N_*4);
  float* disb   =(float*)alloc((size_t)N_*4);
  int* rp_sc    =(int*)  alloc((size_t)(N_+1)*4);
  int* rp_bb    =(int*)  alloc((size_t)(N_+1)*4);
  int*  key1_sc =(int*)  alloc((size_t)ESC*4);
  int2* pay1_sc =(int2*) alloc((size_t)ESC*8);
  int*  dstS_sc =(int*)  alloc((size_t)ESC*4);
  int2* csr_se_sc=(int2*)alloc((size_t)ESC*8);
  int*  key1_bb =(int*)  alloc((size_t)EBB*4);
  int2* pay1_bb =(int2*) alloc((size_t)EBB*8);
  int*  dstS_bb =(int*)  alloc((size_t)EBB*4);
  int2* csr_se_bb=(int2*)alloc((size_t)EBB*8);
  int*  hist    =(int*)  alloc((size_t)(RBS+RBB)*256*4);
  int*  tot     =(int*)  alloc(512*4);
  int*  dbase   =(int*)  alloc(512*4);
  unsigned short* wfg_hi =(unsigned short*)alloc(2048*8*2);
  unsigned short* wfg_lo =(unsigned short*)alloc(2048*8*2);
  unsigned short* wfbg_hi=(unsigned short*)alloc(2048*8*2);
  unsigned short* wfi2_hi=(unsigned short*)alloc(2048*8*2);
  unsigned short* wfi1_hi=(unsigned short*)alloc(4096*8*2);
  unsigned short* wfsc_hi=(unsigned short*)alloc(512*8*2);
  unsigned short* wfsc_lo=(unsigned short*)alloc(512*8*2);
  unsigned short* wfbb_hi=(unsigned short*)alloc(1024*8*2);
  unsigned short* wfbb_lo=(unsigned short*)alloc(1024*8*2);

  const int* src_sc=(const int*)d_in[48];
  const int* dst_sc=src_sc+ESC;
  const int* src_bb=(const int*)d_in[49];
  const int* dst_bb=src_bb+EBB;

  k_detect<<<1,1,0,stream>>>(d_in[0], flag);

  CvtArgs ca;
  {
    int map[29]={14,15,16,17,18,19,20,21,22,23,24,25,30,31,32,33,34,35,36,37,
                 38,39,40,41,42,43,44,45,13};
    for(int i=0;i<29;i++) ca.src[i]=d_in[map[i]];
  }
  k_cvtw<<<(OW_TOT+255)/256,256,0,stream>>>(ca, flag, warena);

  // mega prep: wprep | prevec | preP | LN
  k_prep<<<PB_LN,256,0,stream>>>(warena, flag,
      wfg_hi,wfg_lo, wfbg_hi, wfi2_hi, wfi1_hi,
      wfsc_hi,wfsc_lo, wfbb_hi,wfbb_lo,
      d_in[26], d_in[27], d_in[28], d_in[29], dv, dvf, P, sp, qp,
      d_in[0], d_in[1], d_in[2], d_in[3], d_in[4], d_in[5], xn_sc, xn_bb);

  // stable radix CSR build (parallel scan)
  k_rhist<<<RBS+RBB,256,0,stream>>>(dst_sc, dst_bb, 0, hist);
  k_rscanA<<<512,256,0,stream>>>(hist, tot);
  k_rscanB<<<1,256,0,stream>>>(tot, dbase);
  k_rscat<<<RBS+RBB,256,0,stream>>>(0, 1, dst_sc, src_sc, (const int2*)nullptr,
                                    dst_bb, src_bb, (const int2*)nullptr, hist, dbase,
                                    key1_sc, pay1_sc, key1_bb, pay1_bb);
  k_rhist<<<RBS+RBB,256,0,stream>>>(key1_sc, key1_bb, 8, hist);
  k_rscanA<<<512,256,0,stream>>>(hist, tot);
  k_rscanB<<<1,256,0,stream>>>(tot, dbase);
  k_rscat<<<RBS+RBB,256,0,stream>>>(8, 0, key1_sc, (const int*)nullptr, pay1_sc,
                                    key1_bb, (const int*)nullptr, pay1_bb, hist, dbase,
                                    dstS_sc, csr_se_sc, dstS_bb, csr_se_bb);
  k_bounds<<<(int)(((long)ESC+1+EBB+1+255)/256),256,0,stream>>>(dstS_sc, dstS_bb, rp_sc, rp_bb);
  k_degb<<<(N_+255)/256,256,0,stream>>>(rp_bb, disb);

  // featurizer GEMMs (merged)
  const int GB = (N_+63)/64;
  k_mfeat<<<2*GB,256,0,stream>>>(xn_sc, xn_bb, wfsc_hi, wfsc_lo, wfbb_hi, wfbb_lo,
                                 warena, hat_h, hbuf, N_);

  // edge MLP (16-lane groups, 4 edges/group, coalesced P)
  k_w0<<<WBG,256,0,stream>>>(d_in[6],d_in[7],(const int*)d_in[46],(const int*)d_in[47],
                             flag,dvf,P,sp,qp,we);

  // sidechain layers (GEMM || degree merged; dis[src] inlined in agg)
  const int DB = (N_+255)/256;
  for(int l=0;l<3;l++){
    k_gemmdeg<<<GB+DB,256,0,stream>>>(hat_h, wfg_hi, wfg_lo, bufX, N_,
                                      rp_sc, csr_se_sc, we, an, bn, dv, we_csr, dis, l);
    k_agg_sc<<<N_/4,256,0,stream>>>(rp_sc,csr_se_sc,we_csr,dis,bufX,warena,hat_h,dv,an,bn,(l<2)?1:0);
  }

  // backbone layers (fused GEMM trio + plain agg)
  for(int l=0;l<2;l++){
    k_mbb<<<GB,256,0,stream>>>(hbuf, hat_h, wfi1_hi, wfbg_hi, wfi2_hi,
                               warena+OW_IB1, warena+OW_IB2, bufXb, bufMb, N_);
    k_agg_bb<<<N_/4,256,0,stream>>>(rp_bb,csr_se_bb,disb,bufXb,bufMb,warena,hbuf);
  }

  // output heads (standalone — fusion measured net-negative in r17/r18)
  k_heads<<<N_/4,256,0,stream>>>(hat_h,hbuf,warena,
                                 d_in[8],d_in[9],d_in[10],d_in[11],d_in[12],flag,d_out);
}